// Round 7
// baseline (1385.382 us; speedup 1.0000x reference)
//
#include <hip/hip_runtime.h>
#include <hip/hip_bf16.h>

typedef unsigned int u32;
typedef unsigned short u16;
typedef __attribute__((ext_vector_type(8))) __bf16 bf16x8;
typedef __attribute__((ext_vector_type(8))) unsigned short u16x8;
typedef __attribute__((ext_vector_type(4))) float f32x4;

#define SEQ 2048

__device__ __forceinline__ float b2f(u16 u) {
  union { u32 i; float f; } x; x.i = ((u32)u) << 16; return x.f;
}
__device__ __forceinline__ u16 f2b(float f) {
  u32 u = __float_as_uint(f);
  u = (u + 0x7fffu + ((u >> 16) & 1u)) >> 16;
  return (u16)u;
}
__device__ __forceinline__ void gload_lds16(const void* g, void* l) {
  __builtin_amdgcn_global_load_lds((const __attribute__((address_space(1))) u32*)g,
                                   (__attribute__((address_space(3))) u32*)l, 16, 0, 0);
}

// ---------------------------------------------------------------------------
// Fused fp32 -> bf16 bulk convert over up to 7 tensors (one launch).
// ---------------------------------------------------------------------------
struct CvtArgs {
  const float* src[7];
  u16* dst[7];
  u32 beg[8];
  u32 total;
};

__global__ __launch_bounds__(256) void cvt_all(CvtArgs a)
{
  for (u32 i = blockIdx.x * 256 + threadIdx.x; i < a.total; i += gridDim.x * 256) {
    int s = 0;
#pragma unroll
    for (int k = 1; k < 7; ++k) s += (i >= a.beg[k]);
    const u32 li = i - a.beg[s];
    const float* in = a.src[s];
    const float4 f0 = ((const float4*)in)[(size_t)li * 2];
    const float4 f1 = ((const float4*)in)[(size_t)li * 2 + 1];
    union { bf16x8 b; u16x8 u; } r;
    r.b[0] = (__bf16)f0.x; r.b[1] = (__bf16)f0.y;
    r.b[2] = (__bf16)f0.z; r.b[3] = (__bf16)f0.w;
    r.b[4] = (__bf16)f1.x; r.b[5] = (__bf16)f1.y;
    r.b[6] = (__bf16)f1.z; r.b[7] = (__bf16)f1.w;
    *(u16x8*)(a.dst[s] + (size_t)li * 8) = r.u;
  }
}

// ---------------------------------------------------------------------------
// 256x256 8-phase pipelined GEMM (logits): C = A[2048][K] * Bt[N][K]^T, fp32 C.
// 8 waves (512 thr), BK=64, dbuf LDS 128 KB, XOR-swizzled (slot = gr ^ row&7).
// Per K-step: 4 phases {ds_read afrag (+bfrag p0) | stage 2 gload_lds of t+1 |
// barrier | setprio+16 MFMA+setprio | [p3: vmcnt(0)] barrier}.
// vmcnt(0) only once per K-step, before buffer swap; loads issue 1-4 phases
// ahead of their drain (structural counted-vmcnt).
// ---------------------------------------------------------------------------
__global__ __launch_bounds__(512, 2) void gemm256(
    const u16* __restrict__ A, const u16* __restrict__ Bt,
    float* __restrict__ C, int N, int K)
{
  __shared__ u16 As[2][256 * 64];
  __shared__ u16 Bs[2][256 * 64];
  const int tid = threadIdx.x;
  const int lane = tid & 63;
  const int wid = tid >> 6;
  const int wr = wid >> 2;     // 0..1  (M half)
  const int wc = wid & 3;      // 0..3  (N quarter)

  // chunked-bijective XCD swizzle, M-fast decode (8 M-blocks share B-panel)
  const int T = (int)gridDim.x;
  const int bid = (int)blockIdx.x;
  const int q8 = T >> 3, r8 = T & 7;
  const int xcd = bid & 7, base = bid >> 3;
  const int swz = (xcd < r8 ? xcd * (q8 + 1) : r8 * (q8 + 1) + (xcd - r8) * q8) + base;
  const int m0 = (swz & 7) * 256;
  const int n0 = (swz >> 3) * 256;

  f32x4 acc[8][4] = {};

  // staging: call c covers 64 rows; thread -> row=c*64+(tid>>3), slot=tid&7,
  // pre-swizzled source granule = slot ^ (row&7). Dest base wave-uniform.
  const int srow = tid >> 3;
  const int sgr = (tid & 7) ^ (srow & 7);
  const u16* gA = A + (size_t)(m0 + srow) * K + sgr * 8;
  const u16* gB = Bt + (size_t)(n0 + srow) * K + sgr * 8;
  const int dwave = wid * 512;          // u16 units within a 64-row call block

  // frag read offsets (u16 units)
  const int co0 = (((lane >> 4)) ^ (lane & 7)) * 8;
  const int co1 = (((lane >> 4) + 4) ^ (lane & 7)) * 8;
  const int raA = (wr * 128 + (lane & 15)) * 64;
  const int raB = (wc * 64 + (lane & 15)) * 64;

  // prologue: stage K-step 0 into buffer 0
#pragma unroll
  for (int c = 0; c < 4; ++c) {
    gload_lds16(gA + (size_t)(c * 64) * K, &As[0][c * 4096 + dwave]);
    gload_lds16(gB + (size_t)(c * 64) * K, &Bs[0][c * 4096 + dwave]);
  }
  asm volatile("s_waitcnt vmcnt(0)" ::: "memory");
  __syncthreads();

  const int nk = K >> 6;                 // 16 K-steps
#pragma unroll 2
  for (int t = 0; t < nk; ++t) {
    const int cb = t & 1;
    const int sb = cb ^ 1;
    const u16* Acur = &As[cb][0];
    const u16* Bcur = &Bs[cb][0];
    u16* Anxt = &As[sb][0];
    u16* Bnxt = &Bs[sb][0];
    const size_t ktn = (size_t)(t + 1) * 64;
    const bool stg = (t + 1 < nk);
    bf16x8 bf[4][2];
#pragma unroll
    for (int p = 0; p < 4; ++p) {
      // --- ds-load register subtile ---
      bf16x8 af[2][2];
#pragma unroll
      for (int mm = 0; mm < 2; ++mm) {
        const int ro = raA + (p * 32 + mm * 16) * 64;
        af[mm][0] = *(const bf16x8*)&Acur[ro + co0];
        af[mm][1] = *(const bf16x8*)&Acur[ro + co1];
      }
      if (p == 0) {
#pragma unroll
        for (int n = 0; n < 4; ++n) {
          const int ro = raB + n * 16 * 64;
          bf[n][0] = *(const bf16x8*)&Bcur[ro + co0];
          bf[n][1] = *(const bf16x8*)&Bcur[ro + co1];
        }
      }
      // --- stage 1 half-tile of K-step t+1 (2 calls) ---
      if (stg) {
        if (p < 2) {
          gload_lds16(gA + (size_t)((p * 2 + 0) * 64) * K + ktn, Anxt + (p * 2 + 0) * 4096 + dwave);
          gload_lds16(gA + (size_t)((p * 2 + 1) * 64) * K + ktn, Anxt + (p * 2 + 1) * 4096 + dwave);
        } else {
          gload_lds16(gB + (size_t)(((p - 2) * 2 + 0) * 64) * K + ktn, Bnxt + ((p - 2) * 2 + 0) * 4096 + dwave);
          gload_lds16(gB + (size_t)(((p - 2) * 2 + 1) * 64) * K + ktn, Bnxt + ((p - 2) * 2 + 1) * 4096 + dwave);
        }
      }
      __syncthreads();
      // --- MFMA cluster (compiler inserts lgkmcnt for the ds_reads) ---
      __builtin_amdgcn_s_setprio(1);
#pragma unroll
      for (int mm = 0; mm < 2; ++mm)
#pragma unroll
        for (int n = 0; n < 4; ++n) {
          acc[p * 2 + mm][n] = __builtin_amdgcn_mfma_f32_16x16x32_bf16(af[mm][0], bf[n][0], acc[p * 2 + mm][n], 0, 0, 0);
          acc[p * 2 + mm][n] = __builtin_amdgcn_mfma_f32_16x16x32_bf16(af[mm][1], bf[n][1], acc[p * 2 + mm][n], 0, 0, 0);
        }
      __builtin_amdgcn_s_setprio(0);
      if (p == 3) asm volatile("s_waitcnt vmcnt(0)" ::: "memory");  // drain own t+1 stages
      __syncthreads();   // buffer swap point at p==3
    }
  }

  // epilogue: fp32 C store
  const int crow = m0 + wr * 128 + ((lane >> 4) << 2);
  const int ccol = n0 + wc * 64 + (lane & 15);
#pragma unroll
  for (int m = 0; m < 8; ++m)
#pragma unroll
    for (int n = 0; n < 4; ++n)
#pragma unroll
      for (int j = 0; j < 4; ++j)
        C[(size_t)(crow + m * 16 + j) * N + ccol + n * 16] = acc[m][n][j];
}

// ---------------------------------------------------------------------------
// 64x128 / BK=64 GEMM for layer GEMMs (R6-proven). XOR-swizzled staging.
// EPI 1: QKV head-major bf16 (which = swz>>8, needs T=768)
// EPI 2: bf16 gelu(acc + bias)
// EPI 3: atomicAdd fp32 (+bias on z==0), split-K via gridDim.z
// ---------------------------------------------------------------------------
template <int EPI>
__global__ __launch_bounds__(256) void gemm64(
    const u16* __restrict__ A, const u16* __restrict__ B0,
    const u16* __restrict__ B1, const u16* __restrict__ B2,
    void* __restrict__ C0, void* __restrict__ C1, void* __restrict__ C2,
    const float* __restrict__ bias, int N, int K)
{
  __shared__ u16 As[64 * 64];
  __shared__ u16 Bs[128 * 64];
  const int tid = threadIdx.x;
  const int lane = tid & 63;
  const int w = tid >> 6;
  const int wr = w >> 1;
  const int wc = w & 1;

  const int T = (int)gridDim.x;
  const int bid = (int)blockIdx.x;
  const int q8 = T >> 3, r8 = T & 7;
  const int xcd = bid & 7, base = bid >> 3;
  int swz = (xcd < r8 ? xcd * (q8 + 1) : r8 * (q8 + 1) + (xcd - r8) * q8) + base;
  int which = 0;
  if (EPI == 1) which = swz >> 8;
  const u16* Bt = (which == 0) ? B0 : (which == 1) ? B1 : B2;
  const int m0 = (swz & 31) * 64;
  const int n0 = (EPI == 1 ? ((swz >> 5) & 7) : (swz >> 5)) * 128;

  const int kchunk = K / (int)gridDim.z;
  const int kbeg = (int)blockIdx.z * kchunk;
  const int kend = kbeg + kchunk;

  f32x4 acc[2][4] = {};

  const int rs = lane >> 3;
  const int gs = (lane & 7) ^ rs;
  const u16* ga0 = A + (size_t)(m0 + w * 16 + rs) * K + gs * 8;
  const u16* gb0 = Bt + (size_t)(n0 + w * 32 + rs) * K + gs * 8;
  u16* la = &As[(w * 16) * 64];
  u16* lb = &Bs[(w * 32) * 64];

  const int xg = lane & 7;
  int coff[2];
#pragma unroll
  for (int ks = 0; ks < 2; ++ks)
    coff[ks] = ((ks * 4 + (lane >> 4)) ^ xg) * 8;
  const int ra = (wr * 32 + (lane & 15)) * 64;
  const int rb = (wc * 64 + (lane & 15)) * 64;

  for (int kt = kbeg; kt < kend; kt += 64) {
    __syncthreads();
#pragma unroll
    for (int c = 0; c < 2; ++c)
      gload_lds16(ga0 + (size_t)c * 8 * K + kt, la + c * 8 * 64);
#pragma unroll
    for (int c = 0; c < 4; ++c)
      gload_lds16(gb0 + (size_t)c * 8 * K + kt, lb + c * 8 * 64);
    asm volatile("s_waitcnt vmcnt(0)" ::: "memory");
    __syncthreads();
#pragma unroll
    for (int ks = 0; ks < 2; ++ks) {
      bf16x8 af[2], bfr[4];
#pragma unroll
      for (int m = 0; m < 2; ++m)
        af[m] = *(const bf16x8*)&As[ra + m * 16 * 64 + coff[ks]];
#pragma unroll
      for (int n = 0; n < 4; ++n)
        bfr[n] = *(const bf16x8*)&Bs[rb + n * 16 * 64 + coff[ks]];
#pragma unroll
      for (int m = 0; m < 2; ++m)
#pragma unroll
        for (int n = 0; n < 4; ++n)
          acc[m][n] = __builtin_amdgcn_mfma_f32_16x16x32_bf16(af[m], bfr[n], acc[m][n], 0, 0, 0);
    }
  }

#pragma unroll
  for (int m = 0; m < 2; ++m) {
    const int rowb = m0 + wr * 32 + m * 16 + ((lane >> 4) << 2);
#pragma unroll
    for (int n = 0; n < 4; ++n) {
      const int col = n0 + wc * 64 + n * 16 + (lane & 15);
#pragma unroll
      for (int j = 0; j < 4; ++j) {
        const int r = rowb + j;
        float v = acc[m][n][j];
        if (EPI == 1) {
          u16* outp = (u16*)((which == 0) ? C0 : (which == 1) ? C1 : C2);
          outp[((size_t)(col >> 6) * SEQ + r) * 64 + (col & 63)] = f2b(v);
        } else if (EPI == 2) {
          float xx = v + bias[col];
          float ge = 0.5f * xx * (1.0f + erff(xx * 0.70710678118654752f));
          ((u16*)C0)[(size_t)r * N + col] = f2b(ge);
        } else {
          float xx = v;
          if (bias != nullptr && blockIdx.z == 0) xx += bias[col];
          atomicAdd(&((float*)C0)[(size_t)r * N + col], xx);
        }
      }
    }
  }
}

// ---------------------------------------------------------------------------
// Fallback logits GEMM (fp32 B, BK=32, R2-proven) if emb_bf16 doesn't fit ws.
// ---------------------------------------------------------------------------
__global__ __launch_bounds__(256) void gemm_f32b(
    const u16* __restrict__ A, const float* __restrict__ Bt,
    float* __restrict__ C0, int N, int K)
{
  __shared__ u16 As[128 * 32];
  __shared__ u16 Bs[128 * 32];
  const int tid = threadIdx.x;
  const int lane = tid & 63;
  const int w = tid >> 6;
  const int wr = w >> 1;
  const int wc = w & 1;

  const int T = (int)gridDim.x;
  const int bid = (int)blockIdx.x;
  const int q8 = T >> 3, r8 = T & 7;
  const int xcd = bid & 7, base = bid >> 3;
  int swz = (xcd < r8 ? xcd * (q8 + 1) : r8 * (q8 + 1) + (xcd - r8) * q8) + base;
  const int m0 = (swz & 15) * 128;
  const int n0 = (swz >> 4) * 128;

  f32x4 acc[4][4] = {};
  const u16* ga0 = A + (size_t)(m0 + w * 32 + (lane >> 2)) * K + (lane & 3) * 8;
  u16* la = &As[(w * 32) * 32];
  const float* gb32 = Bt + (size_t)(n0 + (tid >> 1)) * K + (tid & 1) * 16;
  u16* lbw = &Bs[(tid >> 1) * 32 + (tid & 1) * 16];

  for (int kt = 0; kt < K; kt += 32) {
    __syncthreads();
    gload_lds16(ga0 + kt, la);
    gload_lds16(ga0 + kt + 16 * K, la + 16 * 32);
    {
      const float4 f0 = *(const float4*)(gb32 + kt);
      const float4 f1 = *(const float4*)(gb32 + kt + 4);
      const float4 f2 = *(const float4*)(gb32 + kt + 8);
      const float4 f3 = *(const float4*)(gb32 + kt + 12);
      union { bf16x8 b; u16x8 u; } lo, hi;
      lo.b[0] = (__bf16)f0.x; lo.b[1] = (__bf16)f0.y;
      lo.b[2] = (__bf16)f0.z; lo.b[3] = (__bf16)f0.w;
      lo.b[4] = (__bf16)f1.x; lo.b[5] = (__bf16)f1.y;
      lo.b[6] = (__bf16)f1.z; lo.b[7] = (__bf16)f1.w;
      hi.b[0] = (__bf16)f2.x; hi.b[1] = (__bf16)f2.y;
      hi.b[2] = (__bf16)f2.z; hi.b[3] = (__bf16)f2.w;
      hi.b[4] = (__bf16)f3.x; hi.b[5] = (__bf16)f3.y;
      hi.b[6] = (__bf16)f3.z; hi.b[7] = (__bf16)f3.w;
      *(u16x8*)lbw = lo.u;
      *(u16x8*)(lbw + 8) = hi.u;
    }
    asm volatile("s_waitcnt vmcnt(0)" ::: "memory");
    __syncthreads();
    bf16x8 af[4], bfr[4];
#pragma unroll
    for (int m = 0; m < 4; ++m)
      af[m] = *(const bf16x8*)&As[(wr * 64 + m * 16 + (lane & 15)) * 32 + (lane >> 4) * 8];
#pragma unroll
    for (int n = 0; n < 4; ++n)
      bfr[n] = *(const bf16x8*)&Bs[(wc * 64 + n * 16 + (lane & 15)) * 32 + (lane >> 4) * 8];
#pragma unroll
    for (int m = 0; m < 4; ++m)
#pragma unroll
      for (int n = 0; n < 4; ++n)
        acc[m][n] = __builtin_amdgcn_mfma_f32_16x16x32_bf16(af[m], bfr[n], acc[m][n], 0, 0, 0);
  }

#pragma unroll
  for (int m = 0; m < 4; ++m) {
    const int rowb = m0 + wr * 64 + m * 16 + ((lane >> 4) << 2);
#pragma unroll
    for (int n = 0; n < 4; ++n) {
      const int col = n0 + wc * 64 + n * 16 + (lane & 15);
#pragma unroll
      for (int j = 0; j < 4; ++j)
        C0[(size_t)(rowb + j) * N + col] = acc[m][n][j];
    }
  }
}

// ---------------------------------------------------------------------------
// LayerNorm: fp32 x[row][1024] -> bf16 out; g/b fp32
// ---------------------------------------------------------------------------
__global__ __launch_bounds__(256) void ln_kernel(const float* __restrict__ x,
    const float* __restrict__ g, const float* __restrict__ b, u16* __restrict__ out)
{
  const int row = blockIdx.x;
  const int tid = threadIdx.x;
  const float4 v = ((const float4*)(x + (size_t)row * 1024))[tid];
  float s = v.x + v.y + v.z + v.w;
  float sq = v.x * v.x + v.y * v.y + v.z * v.z + v.w * v.w;
#pragma unroll
  for (int o = 1; o < 64; o <<= 1) { s += __shfl_xor(s, o); sq += __shfl_xor(sq, o); }
  __shared__ float ss[4], ssq[4];
  if ((tid & 63) == 0) { ss[tid >> 6] = s; ssq[tid >> 6] = sq; }
  __syncthreads();
  s = ss[0] + ss[1] + ss[2] + ss[3];
  sq = ssq[0] + ssq[1] + ssq[2] + ssq[3];
  const float mean = s * (1.0f / 1024.0f);
  const float var = sq * (1.0f / 1024.0f) - mean * mean;
  const float rstd = rsqrtf(var + 1e-5f);
  const int c = tid * 4;
  u16* o4 = out + (size_t)row * 1024 + c;
  const float4 gg = ((const float4*)g)[tid];
  const float4 bb = ((const float4*)b)[tid];
  o4[0] = f2b((v.x - mean) * rstd * gg.x + bb.x);
  o4[1] = f2b((v.y - mean) * rstd * gg.y + bb.y);
  o4[2] = f2b((v.z - mean) * rstd * gg.z + bb.z);
  o4[3] = f2b((v.w - mean) * rstd * gg.w + bb.w);
}

// ---------------------------------------------------------------------------
// Embedding gather: x[s][d] = emb_fp32[ids[s]][d]
// ---------------------------------------------------------------------------
__global__ __launch_bounds__(256) void gather_kernel(const int* __restrict__ ids,
    const float* __restrict__ emb, float* __restrict__ x)
{
  const int srow = blockIdx.x;
  const int tid = threadIdx.x;
  const int id = ids[srow];
  ((float4*)(x + (size_t)srow * 1024))[tid] =
      ((const float4*)(emb + (size_t)id * 1024))[tid];
}

// ---------------------------------------------------------------------------
// Flash attention w/ ALiBi + causal (R6 config, head-major XCD grid).
// ---------------------------------------------------------------------------
__global__ __launch_bounds__(256) void attn_kernel(
    const u16* __restrict__ q, const u16* __restrict__ k, const u16* __restrict__ v,
    const float* __restrict__ slopes, u16* __restrict__ out)
{
  const int bid = (int)blockIdx.x;
  const int swz = (bid & 7) * 32 + (bid >> 3);
  const int h = swz >> 4;
  const int q0 = (swz & 15) * 128;
  const int tid = threadIdx.x;
  const int lane = tid & 63;
  const int w = tid >> 6;
  const float slope = slopes[h];

  __shared__ u16 Ks[2][64 * 32];
  __shared__ u16 Vt[64][72];
  __shared__ u16 Pl[4][32][72];

  const u16* qb = q + ((size_t)h * SEQ + q0 + w * 32) * 64;
  bf16x8 qf[2][2];
#pragma unroll
  for (int m = 0; m < 2; ++m)
#pragma unroll
    for (int kk = 0; kk < 2; ++kk)
      qf[m][kk] = *(const bf16x8*)(qb + (m * 16 + (lane & 15)) * 64 + kk * 32 + (lane >> 4) * 8);

  f32x4 o_acc[2][4] = {};
  float mrun[2][4], lrun[2][4];
#pragma unroll
  for (int m = 0; m < 2; ++m)
#pragma unroll
    for (int j = 0; j < 4; ++j) { mrun[m][j] = -1e30f; lrun[m][j] = 0.0f; }

  const int ntiles = (q0 >> 6) + 2;
  const int wmaxrow = q0 + w * 32 + 31;

  const int kkp = w >> 1, halfp = w & 1;
  const u16* gk0 = k + ((size_t)h * SEQ + halfp * 32 + (lane >> 2)) * 64 + kkp * 32 + (lane & 3) * 8;
  u16* lk = &Ks[kkp][(halfp * 32) * 32];
  const u16* gv0 = v + ((size_t)h * SEQ + lane) * 64 + w * 16;

  for (int t = 0; t < ntiles; ++t) {
    const int j0 = t << 6;
    __syncthreads();
    gload_lds16(gk0 + (size_t)j0 * 64, lk);
    gload_lds16(gk0 + (size_t)(j0 + 16) * 64, lk + 16 * 32);
    {
      const u16* gvp = gv0 + (size_t)j0 * 64;
      u16x8 v0 = *(const u16x8*)gvp;
      u16x8 v1 = *(const u16x8*)(gvp + 8);
      const int d0 = w * 16;
#pragma unroll
      for (int i = 0; i < 8; ++i) Vt[d0 + i][lane] = v0[i];
#pragma unroll
      for (int i = 0; i < 8; ++i) Vt[d0 + 8 + i][lane] = v1[i];
    }
    asm volatile("s_waitcnt vmcnt(0)" ::: "memory");
    __syncthreads();

    if (wmaxrow >= j0) {
      f32x4 s[2][4] = {};
      __builtin_amdgcn_s_setprio(1);
#pragma unroll
      for (int kk = 0; kk < 2; ++kk) {
        bf16x8 kf[4];
#pragma unroll
        for (int n = 0; n < 4; ++n)
          kf[n] = *(const bf16x8*)&Ks[kk][(n * 16 + (lane & 15)) * 32 + (lane >> 4) * 8];
#pragma unroll
        for (int m = 0; m < 2; ++m)
#pragma unroll
          for (int n = 0; n < 4; ++n)
            s[m][n] = __builtin_amdgcn_mfma_f32_16x16x32_bf16(qf[m][kk], kf[n], s[m][n], 0, 0, 0);
      }
      __builtin_amdgcn_s_setprio(0);
      const int rq = q0 + w * 32 + ((lane >> 4) << 2);
      const int ck = j0 + (lane & 15);
#pragma unroll
      for (int m = 0; m < 2; ++m) {
#pragma unroll
        for (int j = 0; j < 4; ++j) {
          const int qi = rq + m * 16 + j;
          float mx = -1e30f;
#pragma unroll
          for (int n = 0; n < 4; ++n) {
            const int kj = ck + n * 16;
            float val = s[m][n][j] * 0.125f - slope * (float)(kj - qi);
            val = (kj <= qi) ? val : -1e30f;
            s[m][n][j] = val;
            mx = fmaxf(mx, val);
          }
#pragma unroll
          for (int o = 1; o < 16; o <<= 1) mx = fmaxf(mx, __shfl_xor(mx, o));
          const float mnew = fmaxf(mrun[m][j], mx);
          const float alpha = __expf(mrun[m][j] - mnew);
          mrun[m][j] = mnew;
          float rs = 0.0f;
          const int prow = m * 16 + ((lane >> 4) << 2) + j;
#pragma unroll
          for (int n = 0; n < 4; ++n) {
            const float p = __expf(s[m][n][j] - mnew);
            rs += p;
            Pl[w][prow][n * 16 + (lane & 15)] = f2b(p);
          }
#pragma unroll
          for (int o = 1; o < 16; o <<= 1) rs += __shfl_xor(rs, o);
          lrun[m][j] = lrun[m][j] * alpha + rs;
#pragma unroll
          for (int n = 0; n < 4; ++n) o_acc[m][n][j] *= alpha;
        }
      }
      __builtin_amdgcn_s_setprio(1);
#pragma unroll
      for (int kk = 0; kk < 2; ++kk) {
        bf16x8 pf[2], vf[4];
#pragma unroll
        for (int m = 0; m < 2; ++m)
          pf[m] = *(const bf16x8*)&Pl[w][m * 16 + (lane & 15)][kk * 32 + (lane >> 4) * 8];
#pragma unroll
        for (int n = 0; n < 4; ++n)
          vf[n] = *(const bf16x8*)&Vt[n * 16 + (lane & 15)][kk * 32 + (lane >> 4) * 8];
#pragma unroll
        for (int m = 0; m < 2; ++m)
#pragma unroll
          for (int n = 0; n < 4; ++n)
            o_acc[m][n] = __builtin_amdgcn_mfma_f32_16x16x32_bf16(pf[m], vf[n], o_acc[m][n], 0, 0, 0);
      }
      __builtin_amdgcn_s_setprio(0);
    }
  }

#pragma unroll
  for (int m = 0; m < 2; ++m) {
    const int sbase = q0 + w * 32 + m * 16 + ((lane >> 4) << 2);
#pragma unroll
    for (int n = 0; n < 4; ++n) {
      const int d = h * 64 + n * 16 + (lane & 15);
#pragma unroll
      for (int j = 0; j < 4; ++j)
        out[(size_t)(sbase + j) * 1024 + d] = f2b(o_acc[m][n][j] / lrun[m][j]);
    }
  }
}

// ---------------------------------------------------------------------------
extern "C" void kernel_launch(void* const* d_in, const int* in_sizes, int n_in,
                              void* d_out, int out_size, void* d_ws, size_t ws_size,
                              hipStream_t stream)
{
  (void)in_sizes; (void)n_in; (void)out_size;
  const int* ids = (const int*)d_in[0];
  const float* emb = (const float*)d_in[1];
  const float* slopes = (const float*)d_in[2];
  const float* Wq = (const float*)d_in[3];
  const float* Wk = (const float*)d_in[4];
  const float* Wv = (const float*)d_in[5];
  const float* Wo = (const float*)d_in[6];
  const float* W1 = (const float*)d_in[7];
  const float* b1 = (const float*)d_in[8];
  const float* W2 = (const float*)d_in[9];
  const float* b2 = (const float*)d_in[10];
  const float* g1 = (const float*)d_in[11];
  const float* be1 = (const float*)d_in[12];
  const float* g2 = (const float*)d_in[13];
  const float* be2 = (const float*)d_in[14];
  const float* gf = (const float*)d_in[15];
  const float* bfin = (const float*)d_in[16];

  char* ob = (char*)d_out;
  float* x   = (float*)ob;                         // 8 MB fp32 residual
  u16* qb    = (u16*)(ob + (size_t)( 8u << 20));   // 4 MB
  u16* kb    = (u16*)(ob + (size_t)(12u << 20));   // 4 MB
  u16* vb    = (u16*)(ob + (size_t)(16u << 20));   // 4 MB
  u16* attn  = (u16*)(ob + (size_t)(20u << 20));   // 4 MB
  u16* ff    = (u16*)(ob + (size_t)(24u << 20));   // 16 MB
  u16* Wq_b  = (u16*)(ob + (size_t)( 40u << 20));  // 8 MB
  u16* Wk_b  = (u16*)(ob + (size_t)( 48u << 20));  // 8 MB
  u16* Wv_b  = (u16*)(ob + (size_t)( 56u << 20));  // 8 MB
  u16* Wo_b  = (u16*)(ob + (size_t)( 64u << 20));  // 8 MB
  u16* W1_b  = (u16*)(ob + (size_t)( 72u << 20));  // 32 MB
  u16* W2_b  = (u16*)(ob + (size_t)(104u << 20));  // 32 MB
  u16* h     = (u16*)d_ws;                         // 4 MB
  const size_t emb_b_need = (size_t)(4u << 20) + (size_t)32000 * 1024 * 2;
  const bool emb_fits = ws_size >= emb_b_need;
  u16* emb_b = (u16*)((char*)d_ws + (4u << 20));
  float* logits = (float*)d_out;

  {
    CvtArgs a;
    const u32 wsz = 4 * 1024 * 1024 / 8;
    const u32 fsz = 16 * 1024 * 1024 / 8;
    const u32 esz = 32000 * 1024 / 8;
    a.src[0] = Wq; a.dst[0] = Wq_b;
    a.src[1] = Wk; a.dst[1] = Wk_b;
    a.src[2] = Wv; a.dst[2] = Wv_b;
    a.src[3] = Wo; a.dst[3] = Wo_b;
    a.src[4] = W1; a.dst[4] = W1_b;
    a.src[5] = W2; a.dst[5] = W2_b;
    a.src[6] = emb; a.dst[6] = emb_b;
    a.beg[0] = 0;
    a.beg[1] = wsz;      a.beg[2] = 2 * wsz;  a.beg[3] = 3 * wsz;
    a.beg[4] = 4 * wsz;  a.beg[5] = 4 * wsz + fsz;  a.beg[6] = 4 * wsz + 2 * fsz;
    a.beg[7] = a.beg[6] + esz;
    a.total = emb_fits ? a.beg[7] : a.beg[6];
    cvt_all<<<2048, 256, 0, stream>>>(a);
  }

  gather_kernel<<<2048, 256, 0, stream>>>(ids, emb, x);

  for (int l = 0; l < 4; ++l) {
    const size_t wo = (size_t)l * 1024 * 1024;
    const size_t wf = (size_t)l * 4096 * 1024;
    ln_kernel<<<2048, 256, 0, stream>>>(x, g1 + l * 1024, be1 + l * 1024, h);
    gemm64<1><<<dim3(768, 1, 1), 256, 0, stream>>>(h, Wq_b + wo, Wk_b + wo, Wv_b + wo,
        qb, kb, vb, nullptr, 1024, 1024);
    attn_kernel<<<dim3(256, 1, 1), 256, 0, stream>>>(qb, kb, vb, slopes, attn);
    gemm64<3><<<dim3(256, 1, 2), 256, 0, stream>>>(attn, Wo_b + wo, nullptr, nullptr,
        x, nullptr, nullptr, nullptr, 1024, 1024);
    ln_kernel<<<2048, 256, 0, stream>>>(x, g2 + l * 1024, be2 + l * 1024, h);
    gemm64<2><<<dim3(1024, 1, 1), 256, 0, stream>>>(h, W1_b + wf, nullptr, nullptr,
        ff, nullptr, nullptr, b1 + l * 4096, 4096, 1024);
    gemm64<3><<<dim3(256, 1, 2), 256, 0, stream>>>(ff, W2_b + wf, nullptr, nullptr,
        x, nullptr, nullptr, b2 + l * 1024, 1024, 4096);
  }
  ln_kernel<<<2048, 256, 0, stream>>>(x, gf, bfin, h);
  if (emb_fits) {
    gemm256<<<dim3(1000, 1, 1), 512, 0, stream>>>(h, emb_b, logits, 32000, 1024);
  } else {
    gemm_f32b<<<dim3(4000, 1, 1), 256, 0, stream>>>(h, emb, logits, 32000, 1024);
  }
}

// Round 8
// 1318.885 us; speedup vs baseline: 1.0504x; 1.0504x over previous
//
#include <hip/hip_runtime.h>
#include <hip/hip_bf16.h>

typedef unsigned int u32;
typedef unsigned short u16;
typedef __attribute__((ext_vector_type(8))) __bf16 bf16x8;
typedef __attribute__((ext_vector_type(8))) unsigned short u16x8;
typedef __attribute__((ext_vector_type(4))) float f32x4;

#define SEQ 2048

__device__ __forceinline__ float b2f(u16 u) {
  union { u32 i; float f; } x; x.i = ((u32)u) << 16; return x.f;
}
__device__ __forceinline__ u16 f2b(float f) {
  u32 u = __float_as_uint(f);
  u = (u + 0x7fffu + ((u >> 16) & 1u)) >> 16;
  return (u16)u;
}
__device__ __forceinline__ void gload_lds16(const void* g, void* l) {
  __builtin_amdgcn_global_load_lds((const __attribute__((address_space(1))) u32*)g,
                                   (__attribute__((address_space(3))) u32*)l, 16, 0, 0);
}

// ---------------------------------------------------------------------------
// Fused fp32 -> bf16 bulk convert over up to 7 tensors (one launch).
// ---------------------------------------------------------------------------
struct CvtArgs {
  const float* src[7];
  u16* dst[7];
  u32 beg[8];
  u32 total;
};

__global__ __launch_bounds__(256) void cvt_all(CvtArgs a)
{
  for (u32 i = blockIdx.x * 256 + threadIdx.x; i < a.total; i += gridDim.x * 256) {
    int s = 0;
#pragma unroll
    for (int k = 1; k < 7; ++k) s += (i >= a.beg[k]);
    const u32 li = i - a.beg[s];
    const float* in = a.src[s];
    const float4 f0 = ((const float4*)in)[(size_t)li * 2];
    const float4 f1 = ((const float4*)in)[(size_t)li * 2 + 1];
    union { bf16x8 b; u16x8 u; } r;
    r.b[0] = (__bf16)f0.x; r.b[1] = (__bf16)f0.y;
    r.b[2] = (__bf16)f0.z; r.b[3] = (__bf16)f0.w;
    r.b[4] = (__bf16)f1.x; r.b[5] = (__bf16)f1.y;
    r.b[6] = (__bf16)f1.z; r.b[7] = (__bf16)f1.w;
    *(u16x8*)(a.dst[s] + (size_t)li * 8) = r.u;
  }
}

// ---------------------------------------------------------------------------
// 256x256 pipelined GEMM (logits), corrected sync (m201-style):
// raw s_barrier + counted vmcnt. 8 waves, BK=64, dbuf 128 KB LDS,
// XOR-swizzle (slot = granule ^ row&7) via pre-swizzled global source.
// Per K-step t: {4 phases: ds_read A-frags + 16 MFMA each, B-frags once;
//   s_barrier; issue 8 loads of tile t+2 into freed buffer;
//   s_waitcnt vmcnt(8)  [drains tile t+1's loads, issued one step ago];
//   s_barrier; sched_barrier(0)}.
// ---------------------------------------------------------------------------
__global__ __launch_bounds__(512, 2) void gemm256(
    const u16* __restrict__ A, const u16* __restrict__ Bt,
    float* __restrict__ C, int N, int K)
{
  __shared__ u16 As[2][256 * 64];
  __shared__ u16 Bs[2][256 * 64];
  const int tid = threadIdx.x;
  const int lane = tid & 63;
  const int wid = tid >> 6;
  const int wr = wid >> 2;     // 0..1  (M half)
  const int wc = wid & 3;      // 0..3  (N quarter)

  // chunked-bijective XCD swizzle, M-fast decode (8 M-blocks share B-panel)
  const int T = (int)gridDim.x;
  const int bid = (int)blockIdx.x;
  const int q8 = T >> 3, r8 = T & 7;
  const int xcd = bid & 7, base = bid >> 3;
  const int swz = (xcd < r8 ? xcd * (q8 + 1) : r8 * (q8 + 1) + (xcd - r8) * q8) + base;
  const int m0 = (swz & 7) * 256;
  const int n0 = (swz >> 3) * 256;

  f32x4 acc[8][4] = {};

  // staging: call c covers rows c*64..c*64+63; thread -> row=c*64+(tid>>3),
  // slot=tid&7, pre-swizzled source granule = slot ^ (row&7).
  const int srow = tid >> 3;
  const int sgr = (tid & 7) ^ (srow & 7);
  const u16* gA = A + (size_t)(m0 + srow) * K + sgr * 8;
  const u16* gB = Bt + (size_t)(n0 + srow) * K + sgr * 8;
  const int dwave = wid * 512;          // u16 units within a 64-row call block

  // frag read offsets (u16 units)
  const int co0 = (((lane >> 4)) ^ (lane & 7)) * 8;
  const int co1 = (((lane >> 4) + 4) ^ (lane & 7)) * 8;
  const int raA = (wr * 128 + (lane & 15)) * 64;
  const int raB = (wc * 64 + (lane & 15)) * 64;

  const int nk = K >> 6;                 // 16 K-steps

  // prologue: stage tile0 -> buf0 (8 loads), tile1 -> buf1 (8 loads)
#pragma unroll
  for (int c = 0; c < 4; ++c) {
    gload_lds16(gA + (size_t)(c * 64) * K, &As[0][c * 4096 + dwave]);
    gload_lds16(gB + (size_t)(c * 64) * K, &Bs[0][c * 4096 + dwave]);
  }
#pragma unroll
  for (int c = 0; c < 4; ++c) {
    gload_lds16(gA + (size_t)(c * 64) * K + 64, &As[1][c * 4096 + dwave]);
    gload_lds16(gB + (size_t)(c * 64) * K + 64, &Bs[1][c * 4096 + dwave]);
  }
  asm volatile("s_waitcnt vmcnt(8)" ::: "memory");   // tile0 landed; tile1 in flight
  __builtin_amdgcn_s_barrier();
  __builtin_amdgcn_sched_barrier(0);

#pragma unroll 2
  for (int t = 0; t < nk; ++t) {
    const int cb = t & 1;
    const u16* Acur = &As[cb][0];
    const u16* Bcur = &Bs[cb][0];

    // B frags for this wave's 64-col slice, once per K-step
    bf16x8 bf[4][2];
#pragma unroll
    for (int n = 0; n < 4; ++n) {
      const int ro = raB + n * 16 * 64;
      bf[n][0] = *(const bf16x8*)&Bcur[ro + co0];
      bf[n][1] = *(const bf16x8*)&Bcur[ro + co1];
    }
    // 4 phases: A-frag ds_reads + MFMA cluster (compiler inserts lgkmcnt)
#pragma unroll
    for (int p = 0; p < 4; ++p) {
      bf16x8 af[2][2];
#pragma unroll
      for (int mm = 0; mm < 2; ++mm) {
        const int ro = raA + (p * 32 + mm * 16) * 64;
        af[mm][0] = *(const bf16x8*)&Acur[ro + co0];
        af[mm][1] = *(const bf16x8*)&Acur[ro + co1];
      }
      __builtin_amdgcn_s_setprio(1);
#pragma unroll
      for (int mm = 0; mm < 2; ++mm)
#pragma unroll
        for (int n = 0; n < 4; ++n) {
          acc[p * 2 + mm][n] = __builtin_amdgcn_mfma_f32_16x16x32_bf16(af[mm][0], bf[n][0], acc[p * 2 + mm][n], 0, 0, 0);
          acc[p * 2 + mm][n] = __builtin_amdgcn_mfma_f32_16x16x32_bf16(af[mm][1], bf[n][1], acc[p * 2 + mm][n], 0, 0, 0);
        }
      __builtin_amdgcn_s_setprio(0);
    }

    __builtin_amdgcn_s_barrier();        // all waves done READING buf cb
    // refill freed buffer with tile t+2
    if (t + 2 < nk) {
      const size_t kto = (size_t)(t + 2) * 64;
      u16* Anx = &As[cb][0];
      u16* Bnx = &Bs[cb][0];
#pragma unroll
      for (int c = 0; c < 4; ++c) {
        gload_lds16(gA + (size_t)(c * 64) * K + kto, Anx + c * 4096 + dwave);
        gload_lds16(gB + (size_t)(c * 64) * K + kto, Bnx + c * 4096 + dwave);
      }
      asm volatile("s_waitcnt vmcnt(8)" ::: "memory");  // drain tile t+1 loads
    } else if (t + 1 < nk) {
      asm volatile("s_waitcnt vmcnt(0)" ::: "memory");  // final drain
    }
    __builtin_amdgcn_s_barrier();        // publish buf cb^1 (tile t+1)
    __builtin_amdgcn_sched_barrier(0);   // keep next-step ds_reads below
  }

  // epilogue: fp32 C store
  const int crow = m0 + wr * 128 + ((lane >> 4) << 2);
  const int ccol = n0 + wc * 64 + (lane & 15);
#pragma unroll
  for (int m = 0; m < 8; ++m)
#pragma unroll
    for (int n = 0; n < 4; ++n)
#pragma unroll
      for (int j = 0; j < 4; ++j)
        C[(size_t)(crow + m * 16 + j) * N + ccol + n * 16] = acc[m][n][j];
}

// ---------------------------------------------------------------------------
// 64x128 / BK=64 GEMM for layer GEMMs (R6-proven). XOR-swizzled staging.
// EPI 1: QKV head-major bf16 (which = swz>>8, needs T=768)
// EPI 2: bf16 gelu(acc + bias)
// EPI 3: atomicAdd fp32 (+bias on z==0), split-K via gridDim.z
// ---------------------------------------------------------------------------
template <int EPI>
__global__ __launch_bounds__(256) void gemm64(
    const u16* __restrict__ A, const u16* __restrict__ B0,
    const u16* __restrict__ B1, const u16* __restrict__ B2,
    void* __restrict__ C0, void* __restrict__ C1, void* __restrict__ C2,
    const float* __restrict__ bias, int N, int K)
{
  __shared__ u16 As[64 * 64];
  __shared__ u16 Bs[128 * 64];
  const int tid = threadIdx.x;
  const int lane = tid & 63;
  const int w = tid >> 6;
  const int wr = w >> 1;
  const int wc = w & 1;

  const int T = (int)gridDim.x;
  const int bid = (int)blockIdx.x;
  const int q8 = T >> 3, r8 = T & 7;
  const int xcd = bid & 7, base = bid >> 3;
  int swz = (xcd < r8 ? xcd * (q8 + 1) : r8 * (q8 + 1) + (xcd - r8) * q8) + base;
  int which = 0;
  if (EPI == 1) which = swz >> 8;
  const u16* Bt = (which == 0) ? B0 : (which == 1) ? B1 : B2;
  const int m0 = (swz & 31) * 64;
  const int n0 = (EPI == 1 ? ((swz >> 5) & 7) : (swz >> 5)) * 128;

  const int kchunk = K / (int)gridDim.z;
  const int kbeg = (int)blockIdx.z * kchunk;
  const int kend = kbeg + kchunk;

  f32x4 acc[2][4] = {};

  const int rs = lane >> 3;
  const int gs = (lane & 7) ^ rs;
  const u16* ga0 = A + (size_t)(m0 + w * 16 + rs) * K + gs * 8;
  const u16* gb0 = Bt + (size_t)(n0 + w * 32 + rs) * K + gs * 8;
  u16* la = &As[(w * 16) * 64];
  u16* lb = &Bs[(w * 32) * 64];

  const int xg = lane & 7;
  int coff[2];
#pragma unroll
  for (int ks = 0; ks < 2; ++ks)
    coff[ks] = ((ks * 4 + (lane >> 4)) ^ xg) * 8;
  const int ra = (wr * 32 + (lane & 15)) * 64;
  const int rb = (wc * 64 + (lane & 15)) * 64;

  for (int kt = kbeg; kt < kend; kt += 64) {
    __syncthreads();
#pragma unroll
    for (int c = 0; c < 2; ++c)
      gload_lds16(ga0 + (size_t)c * 8 * K + kt, la + c * 8 * 64);
#pragma unroll
    for (int c = 0; c < 4; ++c)
      gload_lds16(gb0 + (size_t)c * 8 * K + kt, lb + c * 8 * 64);
    asm volatile("s_waitcnt vmcnt(0)" ::: "memory");
    __syncthreads();
#pragma unroll
    for (int ks = 0; ks < 2; ++ks) {
      bf16x8 af[2], bfr[4];
#pragma unroll
      for (int m = 0; m < 2; ++m)
        af[m] = *(const bf16x8*)&As[ra + m * 16 * 64 + coff[ks]];
#pragma unroll
      for (int n = 0; n < 4; ++n)
        bfr[n] = *(const bf16x8*)&Bs[rb + n * 16 * 64 + coff[ks]];
#pragma unroll
      for (int m = 0; m < 2; ++m)
#pragma unroll
        for (int n = 0; n < 4; ++n)
          acc[m][n] = __builtin_amdgcn_mfma_f32_16x16x32_bf16(af[m], bfr[n], acc[m][n], 0, 0, 0);
    }
  }

#pragma unroll
  for (int m = 0; m < 2; ++m) {
    const int rowb = m0 + wr * 32 + m * 16 + ((lane >> 4) << 2);
#pragma unroll
    for (int n = 0; n < 4; ++n) {
      const int col = n0 + wc * 64 + n * 16 + (lane & 15);
#pragma unroll
      for (int j = 0; j < 4; ++j) {
        const int r = rowb + j;
        float v = acc[m][n][j];
        if (EPI == 1) {
          u16* outp = (u16*)((which == 0) ? C0 : (which == 1) ? C1 : C2);
          outp[((size_t)(col >> 6) * SEQ + r) * 64 + (col & 63)] = f2b(v);
        } else if (EPI == 2) {
          float xx = v + bias[col];
          float ge = 0.5f * xx * (1.0f + erff(xx * 0.70710678118654752f));
          ((u16*)C0)[(size_t)r * N + col] = f2b(ge);
        } else {
          float xx = v;
          if (bias != nullptr && blockIdx.z == 0) xx += bias[col];
          atomicAdd(&((float*)C0)[(size_t)r * N + col], xx);
        }
      }
    }
  }
}

// ---------------------------------------------------------------------------
// Fallback logits GEMM (fp32 B, BK=32, R2-proven) if emb_bf16 doesn't fit ws.
// ---------------------------------------------------------------------------
__global__ __launch_bounds__(256) void gemm_f32b(
    const u16* __restrict__ A, const float* __restrict__ Bt,
    float* __restrict__ C0, int N, int K)
{
  __shared__ u16 As[128 * 32];
  __shared__ u16 Bs[128 * 32];
  const int tid = threadIdx.x;
  const int lane = tid & 63;
  const int w = tid >> 6;
  const int wr = w >> 1;
  const int wc = w & 1;

  const int T = (int)gridDim.x;
  const int bid = (int)blockIdx.x;
  const int q8 = T >> 3, r8 = T & 7;
  const int xcd = bid & 7, base = bid >> 3;
  int swz = (xcd < r8 ? xcd * (q8 + 1) : r8 * (q8 + 1) + (xcd - r8) * q8) + base;
  const int m0 = (swz & 15) * 128;
  const int n0 = (swz >> 4) * 128;

  f32x4 acc[4][4] = {};
  const u16* ga0 = A + (size_t)(m0 + w * 32 + (lane >> 2)) * K + (lane & 3) * 8;
  u16* la = &As[(w * 32) * 32];
  const float* gb32 = Bt + (size_t)(n0 + (tid >> 1)) * K + (tid & 1) * 16;
  u16* lbw = &Bs[(tid >> 1) * 32 + (tid & 1) * 16];

  for (int kt = 0; kt < K; kt += 32) {
    __syncthreads();
    gload_lds16(ga0 + kt, la);
    gload_lds16(ga0 + kt + 16 * K, la + 16 * 32);
    {
      const float4 f0 = *(const float4*)(gb32 + kt);
      const float4 f1 = *(const float4*)(gb32 + kt + 4);
      const float4 f2 = *(const float4*)(gb32 + kt + 8);
      const float4 f3 = *(const float4*)(gb32 + kt + 12);
      union { bf16x8 b; u16x8 u; } lo, hi;
      lo.b[0] = (__bf16)f0.x; lo.b[1] = (__bf16)f0.y;
      lo.b[2] = (__bf16)f0.z; lo.b[3] = (__bf16)f0.w;
      lo.b[4] = (__bf16)f1.x; lo.b[5] = (__bf16)f1.y;
      lo.b[6] = (__bf16)f1.z; lo.b[7] = (__bf16)f1.w;
      hi.b[0] = (__bf16)f2.x; hi.b[1] = (__bf16)f2.y;
      hi.b[2] = (__bf16)f2.z; hi.b[3] = (__bf16)f2.w;
      hi.b[4] = (__bf16)f3.x; hi.b[5] = (__bf16)f3.y;
      hi.b[6] = (__bf16)f3.z; hi.b[7] = (__bf16)f3.w;
      *(u16x8*)lbw = lo.u;
      *(u16x8*)(lbw + 8) = hi.u;
    }
    asm volatile("s_waitcnt vmcnt(0)" ::: "memory");
    __syncthreads();
    bf16x8 af[4], bfr[4];
#pragma unroll
    for (int m = 0; m < 4; ++m)
      af[m] = *(const bf16x8*)&As[(wr * 64 + m * 16 + (lane & 15)) * 32 + (lane >> 4) * 8];
#pragma unroll
    for (int n = 0; n < 4; ++n)
      bfr[n] = *(const bf16x8*)&Bs[(wc * 64 + n * 16 + (lane & 15)) * 32 + (lane >> 4) * 8];
#pragma unroll
    for (int m = 0; m < 4; ++m)
#pragma unroll
      for (int n = 0; n < 4; ++n)
        acc[m][n] = __builtin_amdgcn_mfma_f32_16x16x32_bf16(af[m], bfr[n], acc[m][n], 0, 0, 0);
  }

#pragma unroll
  for (int m = 0; m < 4; ++m) {
    const int rowb = m0 + wr * 64 + m * 16 + ((lane >> 4) << 2);
#pragma unroll
    for (int n = 0; n < 4; ++n) {
      const int col = n0 + wc * 64 + n * 16 + (lane & 15);
#pragma unroll
      for (int j = 0; j < 4; ++j)
        C0[(size_t)(rowb + j) * N + col] = acc[m][n][j];
    }
  }
}

// ---------------------------------------------------------------------------
// LayerNorm: fp32 x[row][1024] -> bf16 out; g/b fp32
// ---------------------------------------------------------------------------
__global__ __launch_bounds__(256) void ln_kernel(const float* __restrict__ x,
    const float* __restrict__ g, const float* __restrict__ b, u16* __restrict__ out)
{
  const int row = blockIdx.x;
  const int tid = threadIdx.x;
  const float4 v = ((const float4*)(x + (size_t)row * 1024))[tid];
  float s = v.x + v.y + v.z + v.w;
  float sq = v.x * v.x + v.y * v.y + v.z * v.z + v.w * v.w;
#pragma unroll
  for (int o = 1; o < 64; o <<= 1) { s += __shfl_xor(s, o); sq += __shfl_xor(sq, o); }
  __shared__ float ss[4], ssq[4];
  if ((tid & 63) == 0) { ss[tid >> 6] = s; ssq[tid >> 6] = sq; }
  __syncthreads();
  s = ss[0] + ss[1] + ss[2] + ss[3];
  sq = ssq[0] + ssq[1] + ssq[2] + ssq[3];
  const float mean = s * (1.0f / 1024.0f);
  const float var = sq * (1.0f / 1024.0f) - mean * mean;
  const float rstd = rsqrtf(var + 1e-5f);
  const int c = tid * 4;
  u16* o4 = out + (size_t)row * 1024 + c;
  const float4 gg = ((const float4*)g)[tid];
  const float4 bb = ((const float4*)b)[tid];
  o4[0] = f2b((v.x - mean) * rstd * gg.x + bb.x);
  o4[1] = f2b((v.y - mean) * rstd * gg.y + bb.y);
  o4[2] = f2b((v.z - mean) * rstd * gg.z + bb.z);
  o4[3] = f2b((v.w - mean) * rstd * gg.w + bb.w);
}

// ---------------------------------------------------------------------------
// Embedding gather: x[s][d] = emb_fp32[ids[s]][d]
// ---------------------------------------------------------------------------
__global__ __launch_bounds__(256) void gather_kernel(const int* __restrict__ ids,
    const float* __restrict__ emb, float* __restrict__ x)
{
  const int srow = blockIdx.x;
  const int tid = threadIdx.x;
  const int id = ids[srow];
  ((float4*)(x + (size_t)srow * 1024))[tid] =
      ((const float4*)(emb + (size_t)id * 1024))[tid];
}

// ---------------------------------------------------------------------------
// Flash attention w/ ALiBi + causal (R6 config, head-major XCD grid).
// ---------------------------------------------------------------------------
__global__ __launch_bounds__(256) void attn_kernel(
    const u16* __restrict__ q, const u16* __restrict__ k, const u16* __restrict__ v,
    const float* __restrict__ slopes, u16* __restrict__ out)
{
  const int bid = (int)blockIdx.x;
  const int swz = (bid & 7) * 32 + (bid >> 3);
  const int h = swz >> 4;
  const int q0 = (swz & 15) * 128;
  const int tid = threadIdx.x;
  const int lane = tid & 63;
  const int w = tid >> 6;
  const float slope = slopes[h];

  __shared__ u16 Ks[2][64 * 32];
  __shared__ u16 Vt[64][72];
  __shared__ u16 Pl[4][32][72];

  const u16* qb = q + ((size_t)h * SEQ + q0 + w * 32) * 64;
  bf16x8 qf[2][2];
#pragma unroll
  for (int m = 0; m < 2; ++m)
#pragma unroll
    for (int kk = 0; kk < 2; ++kk)
      qf[m][kk] = *(const bf16x8*)(qb + (m * 16 + (lane & 15)) * 64 + kk * 32 + (lane >> 4) * 8);

  f32x4 o_acc[2][4] = {};
  float mrun[2][4], lrun[2][4];
#pragma unroll
  for (int m = 0; m < 2; ++m)
#pragma unroll
    for (int j = 0; j < 4; ++j) { mrun[m][j] = -1e30f; lrun[m][j] = 0.0f; }

  const int ntiles = (q0 >> 6) + 2;
  const int wmaxrow = q0 + w * 32 + 31;

  const int kkp = w >> 1, halfp = w & 1;
  const u16* gk0 = k + ((size_t)h * SEQ + halfp * 32 + (lane >> 2)) * 64 + kkp * 32 + (lane & 3) * 8;
  u16* lk = &Ks[kkp][(halfp * 32) * 32];
  const u16* gv0 = v + ((size_t)h * SEQ + lane) * 64 + w * 16;

  for (int t = 0; t < ntiles; ++t) {
    const int j0 = t << 6;
    __syncthreads();
    gload_lds16(gk0 + (size_t)j0 * 64, lk);
    gload_lds16(gk0 + (size_t)(j0 + 16) * 64, lk + 16 * 32);
    {
      const u16* gvp = gv0 + (size_t)j0 * 64;
      u16x8 v0 = *(const u16x8*)gvp;
      u16x8 v1 = *(const u16x8*)(gvp + 8);
      const int d0 = w * 16;
#pragma unroll
      for (int i = 0; i < 8; ++i) Vt[d0 + i][lane] = v0[i];
#pragma unroll
      for (int i = 0; i < 8; ++i) Vt[d0 + 8 + i][lane] = v1[i];
    }
    asm volatile("s_waitcnt vmcnt(0)" ::: "memory");
    __syncthreads();

    if (wmaxrow >= j0) {
      f32x4 s[2][4] = {};
      __builtin_amdgcn_s_setprio(1);
#pragma unroll
      for (int kk = 0; kk < 2; ++kk) {
        bf16x8 kf[4];
#pragma unroll
        for (int n = 0; n < 4; ++n)
          kf[n] = *(const bf16x8*)&Ks[kk][(n * 16 + (lane & 15)) * 32 + (lane >> 4) * 8];
#pragma unroll
        for (int m = 0; m < 2; ++m)
#pragma unroll
          for (int n = 0; n < 4; ++n)
            s[m][n] = __builtin_amdgcn_mfma_f32_16x16x32_bf16(qf[m][kk], kf[n], s[m][n], 0, 0, 0);
      }
      __builtin_amdgcn_s_setprio(0);
      const int rq = q0 + w * 32 + ((lane >> 4) << 2);
      const int ck = j0 + (lane & 15);
#pragma unroll
      for (int m = 0; m < 2; ++m) {
#pragma unroll
        for (int j = 0; j < 4; ++j) {
          const int qi = rq + m * 16 + j;
          float mx = -1e30f;
#pragma unroll
          for (int n = 0; n < 4; ++n) {
            const int kj = ck + n * 16;
            float val = s[m][n][j] * 0.125f - slope * (float)(kj - qi);
            val = (kj <= qi) ? val : -1e30f;
            s[m][n][j] = val;
            mx = fmaxf(mx, val);
          }
#pragma unroll
          for (int o = 1; o < 16; o <<= 1) mx = fmaxf(mx, __shfl_xor(mx, o));
          const float mnew = fmaxf(mrun[m][j], mx);
          const float alpha = __expf(mrun[m][j] - mnew);
          mrun[m][j] = mnew;
          float rs = 0.0f;
          const int prow = m * 16 + ((lane >> 4) << 2) + j;
#pragma unroll
          for (int n = 0; n < 4; ++n) {
            const float p = __expf(s[m][n][j] - mnew);
            rs += p;
            Pl[w][prow][n * 16 + (lane & 15)] = f2b(p);
          }
#pragma unroll
          for (int o = 1; o < 16; o <<= 1) rs += __shfl_xor(rs, o);
          lrun[m][j] = lrun[m][j] * alpha + rs;
#pragma unroll
          for (int n = 0; n < 4; ++n) o_acc[m][n][j] *= alpha;
        }
      }
      __builtin_amdgcn_s_setprio(1);
#pragma unroll
      for (int kk = 0; kk < 2; ++kk) {
        bf16x8 pf[2], vf[4];
#pragma unroll
        for (int m = 0; m < 2; ++m)
          pf[m] = *(const bf16x8*)&Pl[w][m * 16 + (lane & 15)][kk * 32 + (lane >> 4) * 8];
#pragma unroll
        for (int n = 0; n < 4; ++n)
          vf[n] = *(const bf16x8*)&Vt[n * 16 + (lane & 15)][kk * 32 + (lane >> 4) * 8];
#pragma unroll
        for (int m = 0; m < 2; ++m)
#pragma unroll
          for (int n = 0; n < 4; ++n)
            o_acc[m][n] = __builtin_amdgcn_mfma_f32_16x16x32_bf16(pf[m], vf[n], o_acc[m][n], 0, 0, 0);
      }
      __builtin_amdgcn_s_setprio(0);
    }
  }

#pragma unroll
  for (int m = 0; m < 2; ++m) {
    const int sbase = q0 + w * 32 + m * 16 + ((lane >> 4) << 2);
#pragma unroll
    for (int n = 0; n < 4; ++n) {
      const int d = h * 64 + n * 16 + (lane & 15);
#pragma unroll
      for (int j = 0; j < 4; ++j)
        out[(size_t)(sbase + j) * 1024 + d] = f2b(o_acc[m][n][j] / lrun[m][j]);
    }
  }
}

// ---------------------------------------------------------------------------
extern "C" void kernel_launch(void* const* d_in, const int* in_sizes, int n_in,
                              void* d_out, int out_size, void* d_ws, size_t ws_size,
                              hipStream_t stream)
{
  (void)in_sizes; (void)n_in; (void)out_size;
  const int* ids = (const int*)d_in[0];
  const float* emb = (const float*)d_in[1];
  const float* slopes = (const float*)d_in[2];
  const float* Wq = (const float*)d_in[3];
  const float* Wk = (const float*)d_in[4];
  const float* Wv = (const float*)d_in[5];
  const float* Wo = (const float*)d_in[6];
  const float* W1 = (const float*)d_in[7];
  const float* b1 = (const float*)d_in[8];
  const float* W2 = (const float*)d_in[9];
  const float* b2 = (const float*)d_in[10];
  const float* g1 = (const float*)d_in[11];
  const float* be1 = (const float*)d_in[12];
  const float* g2 = (const float*)d_in[13];
  const float* be2 = (const float*)d_in[14];
  const float* gf = (const float*)d_in[15];
  const float* bfin = (const float*)d_in[16];

  char* ob = (char*)d_out;
  float* x   = (float*)ob;                         // 8 MB fp32 residual
  u16* qb    = (u16*)(ob + (size_t)( 8u << 20));   // 4 MB
  u16* kb    = (u16*)(ob + (size_t)(12u << 20));   // 4 MB
  u16* vb    = (u16*)(ob + (size_t)(16u << 20));   // 4 MB
  u16* attn  = (u16*)(ob + (size_t)(20u << 20));   // 4 MB
  u16* ff    = (u16*)(ob + (size_t)(24u << 20));   // 16 MB
  u16* Wq_b  = (u16*)(ob + (size_t)( 40u << 20));  // 8 MB
  u16* Wk_b  = (u16*)(ob + (size_t)( 48u << 20));  // 8 MB
  u16* Wv_b  = (u16*)(ob + (size_t)( 56u << 20));  // 8 MB
  u16* Wo_b  = (u16*)(ob + (size_t)( 64u << 20));  // 8 MB
  u16* W1_b  = (u16*)(ob + (size_t)( 72u << 20));  // 32 MB
  u16* W2_b  = (u16*)(ob + (size_t)(104u << 20));  // 32 MB
  u16* h     = (u16*)d_ws;                         // 4 MB
  const size_t emb_b_need = (size_t)(4u << 20) + (size_t)32000 * 1024 * 2;
  const bool emb_fits = ws_size >= emb_b_need;
  u16* emb_b = (u16*)((char*)d_ws + (4u << 20));
  float* logits = (float*)d_out;

  {
    CvtArgs a;
    const u32 wsz = 4 * 1024 * 1024 / 8;
    const u32 fsz = 16 * 1024 * 1024 / 8;
    const u32 esz = 32000 * 1024 / 8;
    a.src[0] = Wq; a.dst[0] = Wq_b;
    a.src[1] = Wk; a.dst[1] = Wk_b;
    a.src[2] = Wv; a.dst[2] = Wv_b;
    a.src[3] = Wo; a.dst[3] = Wo_b;
    a.src[4] = W1; a.dst[4] = W1_b;
    a.src[5] = W2; a.dst[5] = W2_b;
    a.src[6] = emb; a.dst[6] = emb_b;
    a.beg[0] = 0;
    a.beg[1] = wsz;      a.beg[2] = 2 * wsz;  a.beg[3] = 3 * wsz;
    a.beg[4] = 4 * wsz;  a.beg[5] = 4 * wsz + fsz;  a.beg[6] = 4 * wsz + 2 * fsz;
    a.beg[7] = a.beg[6] + esz;
    a.total = emb_fits ? a.beg[7] : a.beg[6];
    cvt_all<<<2048, 256, 0, stream>>>(a);
  }

  gather_kernel<<<2048, 256, 0, stream>>>(ids, emb, x);

  for (int l = 0; l < 4; ++l) {
    const size_t wo = (size_t)l * 1024 * 1024;
    const size_t wf = (size_t)l * 4096 * 1024;
    ln_kernel<<<2048, 256, 0, stream>>>(x, g1 + l * 1024, be1 + l * 1024, h);
    gemm64<1><<<dim3(768, 1, 1), 256, 0, stream>>>(h, Wq_b + wo, Wk_b + wo, Wv_b + wo,
        qb, kb, vb, nullptr, 1024, 1024);
    attn_kernel<<<dim3(256, 1, 1), 256, 0, stream>>>(qb, kb, vb, slopes, attn);
    gemm64<3><<<dim3(256, 1, 2), 256, 0, stream>>>(attn, Wo_b + wo, nullptr, nullptr,
        x, nullptr, nullptr, nullptr, 1024, 1024);
    ln_kernel<<<2048, 256, 0, stream>>>(x, g2 + l * 1024, be2 + l * 1024, h);
    gemm64<2><<<dim3(1024, 1, 1), 256, 0, stream>>>(h, W1_b + wf, nullptr, nullptr,
        ff, nullptr, nullptr, b1 + l * 4096, 4096, 1024);
    gemm64<3><<<dim3(256, 1, 2), 256, 0, stream>>>(ff, W2_b + wf, nullptr, nullptr,
        x, nullptr, nullptr, b2 + l * 1024, 1024, 4096);
  }
  ln_kernel<<<2048, 256, 0, stream>>>(x, gf, bfin, h);
  if (emb_fits) {
    gemm256<<<dim3(1000, 1, 1), 512, 0, stream>>>(h, emb_b, logits, 32000, 1024);
  } else {
    gemm_f32b<<<dim3(4000, 1, 1), 256, 0, stream>>>(h, emb, logits, 32000, 1024);
  }
}

// Round 9
// 1287.432 us; speedup vs baseline: 1.0761x; 1.0244x over previous
//
#include <hip/hip_runtime.h>
#include <hip/hip_bf16.h>

typedef unsigned int u32;
typedef unsigned short u16;
typedef __attribute__((ext_vector_type(8))) __bf16 bf16x8;
typedef __attribute__((ext_vector_type(8))) unsigned short u16x8;
typedef __attribute__((ext_vector_type(4))) float f32x4;

#define SEQ 2048

__device__ __forceinline__ float b2f(u16 u) {
  union { u32 i; float f; } x; x.i = ((u32)u) << 16; return x.f;
}
__device__ __forceinline__ u16 f2b(float f) {
  u32 u = __float_as_uint(f);
  u = (u + 0x7fffu + ((u >> 16) & 1u)) >> 16;
  return (u16)u;
}
__device__ __forceinline__ void gload_lds16(const void* g, void* l) {
  __builtin_amdgcn_global_load_lds((const __attribute__((address_space(1))) u32*)g,
                                   (__attribute__((address_space(3))) u32*)l, 16, 0, 0);
}

// ---------------------------------------------------------------------------
// Fused fp32 -> bf16 bulk convert. Segments 0-2 (Wq/Wk/Wv) are remapped into
// a concatenated [L][3072][1024] layout: dst[s] points at row-block s*1024;
// layer stride is 3072*1024 elems (393216 granules).
// ---------------------------------------------------------------------------
struct CvtArgs {
  const float* src[7];
  u16* dst[7];
  u32 beg[8];
  u32 total;
};

__global__ __launch_bounds__(256) void cvt_all(CvtArgs a)
{
  for (u32 i = blockIdx.x * 256 + threadIdx.x; i < a.total; i += gridDim.x * 256) {
    int s = 0;
#pragma unroll
    for (int k = 1; k < 7; ++k) s += (i >= a.beg[k]);
    const u32 li = i - a.beg[s];
    const float* in = a.src[s];
    const float4 f0 = ((const float4*)in)[(size_t)li * 2];
    const float4 f1 = ((const float4*)in)[(size_t)li * 2 + 1];
    union { bf16x8 b; u16x8 u; } r;
    r.b[0] = (__bf16)f0.x; r.b[1] = (__bf16)f0.y;
    r.b[2] = (__bf16)f0.z; r.b[3] = (__bf16)f0.w;
    r.b[4] = (__bf16)f1.x; r.b[5] = (__bf16)f1.y;
    r.b[6] = (__bf16)f1.z; r.b[7] = (__bf16)f1.w;
    u16* d;
    if (s < 3) {
      const u32 layer = li >> 17;              // 131072 granules per layer-matrix
      const u32 rem = li & 131071u;
      d = a.dst[s] + ((size_t)layer * 393216u + rem) * 8;
    } else {
      d = a.dst[s] + (size_t)li * 8;
    }
    *(u16x8*)d = r.u;
  }
}

// ---------------------------------------------------------------------------
// 256x256 pipelined GEMM (logits) — R8-proven. raw s_barrier + counted vmcnt,
// 8 waves, BK=64, dbuf 128 KB, XOR swizzle via pre-swizzled global source.
// ---------------------------------------------------------------------------
__global__ __launch_bounds__(512, 2) void gemm256(
    const u16* __restrict__ A, const u16* __restrict__ Bt,
    float* __restrict__ C, int N, int K)
{
  __shared__ u16 As[2][256 * 64];
  __shared__ u16 Bs[2][256 * 64];
  const int tid = threadIdx.x;
  const int lane = tid & 63;
  const int wid = tid >> 6;
  const int wr = wid >> 2;
  const int wc = wid & 3;

  const int T = (int)gridDim.x;
  const int bid = (int)blockIdx.x;
  const int q8 = T >> 3, r8 = T & 7;
  const int xcd = bid & 7, base = bid >> 3;
  const int swz = (xcd < r8 ? xcd * (q8 + 1) : r8 * (q8 + 1) + (xcd - r8) * q8) + base;
  const int m0 = (swz & 7) * 256;
  const int n0 = (swz >> 3) * 256;

  f32x4 acc[8][4] = {};

  const int srow = tid >> 3;
  const int sgr = (tid & 7) ^ (srow & 7);
  const u16* gA = A + (size_t)(m0 + srow) * K + sgr * 8;
  const u16* gB = Bt + (size_t)(n0 + srow) * K + sgr * 8;
  const int dwave = wid * 512;

  const int co0 = (((lane >> 4)) ^ (lane & 7)) * 8;
  const int co1 = (((lane >> 4) + 4) ^ (lane & 7)) * 8;
  const int raA = (wr * 128 + (lane & 15)) * 64;
  const int raB = (wc * 64 + (lane & 15)) * 64;

  const int nk = K >> 6;

#pragma unroll
  for (int c = 0; c < 4; ++c) {
    gload_lds16(gA + (size_t)(c * 64) * K, &As[0][c * 4096 + dwave]);
    gload_lds16(gB + (size_t)(c * 64) * K, &Bs[0][c * 4096 + dwave]);
  }
#pragma unroll
  for (int c = 0; c < 4; ++c) {
    gload_lds16(gA + (size_t)(c * 64) * K + 64, &As[1][c * 4096 + dwave]);
    gload_lds16(gB + (size_t)(c * 64) * K + 64, &Bs[1][c * 4096 + dwave]);
  }
  asm volatile("s_waitcnt vmcnt(8)" ::: "memory");
  __builtin_amdgcn_s_barrier();
  __builtin_amdgcn_sched_barrier(0);

#pragma unroll 2
  for (int t = 0; t < nk; ++t) {
    const int cb = t & 1;
    const u16* Acur = &As[cb][0];
    const u16* Bcur = &Bs[cb][0];

    bf16x8 bf[4][2];
#pragma unroll
    for (int n = 0; n < 4; ++n) {
      const int ro = raB + n * 16 * 64;
      bf[n][0] = *(const bf16x8*)&Bcur[ro + co0];
      bf[n][1] = *(const bf16x8*)&Bcur[ro + co1];
    }
#pragma unroll
    for (int p = 0; p < 4; ++p) {
      bf16x8 af[2][2];
#pragma unroll
      for (int mm = 0; mm < 2; ++mm) {
        const int ro = raA + (p * 32 + mm * 16) * 64;
        af[mm][0] = *(const bf16x8*)&Acur[ro + co0];
        af[mm][1] = *(const bf16x8*)&Acur[ro + co1];
      }
      __builtin_amdgcn_s_setprio(1);
#pragma unroll
      for (int mm = 0; mm < 2; ++mm)
#pragma unroll
        for (int n = 0; n < 4; ++n) {
          acc[p * 2 + mm][n] = __builtin_amdgcn_mfma_f32_16x16x32_bf16(af[mm][0], bf[n][0], acc[p * 2 + mm][n], 0, 0, 0);
          acc[p * 2 + mm][n] = __builtin_amdgcn_mfma_f32_16x16x32_bf16(af[mm][1], bf[n][1], acc[p * 2 + mm][n], 0, 0, 0);
        }
      __builtin_amdgcn_s_setprio(0);
    }

    __builtin_amdgcn_s_barrier();
    if (t + 2 < nk) {
      const size_t kto = (size_t)(t + 2) * 64;
      u16* Anx = &As[cb][0];
      u16* Bnx = &Bs[cb][0];
#pragma unroll
      for (int c = 0; c < 4; ++c) {
        gload_lds16(gA + (size_t)(c * 64) * K + kto, Anx + c * 4096 + dwave);
        gload_lds16(gB + (size_t)(c * 64) * K + kto, Bnx + c * 4096 + dwave);
      }
      asm volatile("s_waitcnt vmcnt(8)" ::: "memory");
    } else if (t + 1 < nk) {
      asm volatile("s_waitcnt vmcnt(0)" ::: "memory");
    }
    __builtin_amdgcn_s_barrier();
    __builtin_amdgcn_sched_barrier(0);
  }

  const int crow = m0 + wr * 128 + ((lane >> 4) << 2);
  const int ccol = n0 + wc * 64 + (lane & 15);
#pragma unroll
  for (int m = 0; m < 8; ++m)
#pragma unroll
    for (int n = 0; n < 4; ++n)
#pragma unroll
      for (int j = 0; j < 4; ++j)
        C[(size_t)(crow + m * 16 + j) * N + ccol + n * 16] = acc[m][n][j];
}

// ---------------------------------------------------------------------------
// 128x128 pipelined layer GEMM: same sync ledger as gemm256 (2 raw barriers +
// vmcnt(8)/step), 4 waves (2Mx2N, per-wave 64x64, 32 MFMA/step), BK=64,
// 64 KB dbuf LDS -> 2 blocks/CU. XOR swizzle via pre-swizzled source.
// EPI 0: fp32 store to C0/C1 (by blockIdx.z) [split-K partials, no bias]
// EPI 1: QKV head-major bf16 from concat [3072][1024] weights
// EPI 2: bf16 gelu(acc + bias[col])
// ---------------------------------------------------------------------------
template <int EPI>
__global__ __launch_bounds__(256, 2) void gemm128p(
    const u16* __restrict__ A, const u16* __restrict__ Bt,
    void* __restrict__ C0, void* __restrict__ C1, void* __restrict__ C2,
    const float* __restrict__ bias, int N, int K)
{
  __shared__ u16 As[2][128 * 64];
  __shared__ u16 Bs[2][128 * 64];
  const int tid = threadIdx.x;
  const int lane = tid & 63;
  const int wid = tid >> 6;
  const int wr = wid >> 1;
  const int wc = wid & 1;

  const int T = (int)gridDim.x;
  const int bid = (int)blockIdx.x;
  const int q8 = T >> 3, r8 = T & 7;
  const int xcd = bid & 7, base = bid >> 3;
  const int swz = (xcd < r8 ? xcd * (q8 + 1) : r8 * (q8 + 1) + (xcd - r8) * q8) + base;
  const int m0 = (swz & 15) * 128;
  const int n0 = (swz >> 4) * 128;

  const int kchunk = K / (int)gridDim.z;
  const int kbeg = (int)blockIdx.z * kchunk;
  const int nk = kchunk >> 6;

  f32x4 acc[4][4] = {};

  // staging: call c covers rows c*32..c*32+31; thread -> row=c*32+(tid>>3),
  // slot=tid&7, pre-swizzled source granule = slot ^ (row&7)
  const int srow = tid >> 3;
  const int sgr = (tid & 7) ^ (srow & 7);
  const u16* gA = A + (size_t)(m0 + srow) * K + kbeg + sgr * 8;
  const u16* gB = Bt + (size_t)(n0 + srow) * K + kbeg + sgr * 8;
  const int dwave = wid * 512;

  const int co0 = (((lane >> 4)) ^ (lane & 7)) * 8;
  const int co1 = (((lane >> 4) + 4) ^ (lane & 7)) * 8;
  const int raA = (wr * 64 + (lane & 15)) * 64;
  const int raB = (wc * 64 + (lane & 15)) * 64;

  // prologue: tile0 -> buf0, tile1 -> buf1 (4+4 calls each)
#pragma unroll
  for (int c = 0; c < 4; ++c) {
    gload_lds16(gA + (size_t)(c * 32) * K, &As[0][c * 2048 + dwave]);
    gload_lds16(gB + (size_t)(c * 32) * K, &Bs[0][c * 2048 + dwave]);
  }
#pragma unroll
  for (int c = 0; c < 4; ++c) {
    gload_lds16(gA + (size_t)(c * 32) * K + 64, &As[1][c * 2048 + dwave]);
    gload_lds16(gB + (size_t)(c * 32) * K + 64, &Bs[1][c * 2048 + dwave]);
  }
  asm volatile("s_waitcnt vmcnt(8)" ::: "memory");
  __builtin_amdgcn_s_barrier();
  __builtin_amdgcn_sched_barrier(0);

#pragma unroll 2
  for (int t = 0; t < nk; ++t) {
    const int cb = t & 1;
    const u16* Acur = &As[cb][0];
    const u16* Bcur = &Bs[cb][0];

    bf16x8 bf[4][2];
#pragma unroll
    for (int n = 0; n < 4; ++n) {
      const int ro = raB + n * 16 * 64;
      bf[n][0] = *(const bf16x8*)&Bcur[ro + co0];
      bf[n][1] = *(const bf16x8*)&Bcur[ro + co1];
    }
#pragma unroll
    for (int p = 0; p < 4; ++p) {
      bf16x8 af[2];
      {
        const int ro = raA + p * 16 * 64;
        af[0] = *(const bf16x8*)&Acur[ro + co0];
        af[1] = *(const bf16x8*)&Acur[ro + co1];
      }
      __builtin_amdgcn_s_setprio(1);
#pragma unroll
      for (int n = 0; n < 4; ++n) {
        acc[p][n] = __builtin_amdgcn_mfma_f32_16x16x32_bf16(af[0], bf[n][0], acc[p][n], 0, 0, 0);
        acc[p][n] = __builtin_amdgcn_mfma_f32_16x16x32_bf16(af[1], bf[n][1], acc[p][n], 0, 0, 0);
      }
      __builtin_amdgcn_s_setprio(0);
    }

    __builtin_amdgcn_s_barrier();
    if (t + 2 < nk) {
      const size_t kto = (size_t)(t + 2) * 64;
      u16* Anx = &As[cb][0];
      u16* Bnx = &Bs[cb][0];
#pragma unroll
      for (int c = 0; c < 4; ++c) {
        gload_lds16(gA + (size_t)(c * 32) * K + kto, Anx + c * 2048 + dwave);
        gload_lds16(gB + (size_t)(c * 32) * K + kto, Bnx + c * 2048 + dwave);
      }
      asm volatile("s_waitcnt vmcnt(8)" ::: "memory");
    } else if (t + 1 < nk) {
      asm volatile("s_waitcnt vmcnt(0)" ::: "memory");
    }
    __builtin_amdgcn_s_barrier();
    __builtin_amdgcn_sched_barrier(0);
  }

  // epilogue
  const int z = (int)blockIdx.z;
#pragma unroll
  for (int m = 0; m < 4; ++m) {
    const int rowb = m0 + wr * 64 + m * 16 + ((lane >> 4) << 2);
#pragma unroll
    for (int n = 0; n < 4; ++n) {
      const int col = n0 + wc * 64 + n * 16 + (lane & 15);
#pragma unroll
      for (int j = 0; j < 4; ++j) {
        const int r = rowb + j;
        float v = acc[m][n][j];
        if (EPI == 0) {
          float* outp = (float*)(z == 0 ? C0 : C1);
          outp[(size_t)r * N + col] = v;
        } else if (EPI == 1) {
          const int which = col >> 10;
          const int ci = col & 1023;
          u16* outp = (u16*)((which == 0) ? C0 : (which == 1) ? C1 : C2);
          outp[((size_t)(ci >> 6) * SEQ + r) * 64 + (ci & 63)] = f2b(v);
        } else {
          float xx = v + bias[col];
          float ge = 0.5f * xx * (1.0f + erff(xx * 0.70710678118654752f));
          ((u16*)C0)[(size_t)r * N + col] = f2b(ge);
        }
      }
    }
  }
}

// ---------------------------------------------------------------------------
// Fallback logits GEMM (fp32 B, BK=32) if emb_bf16 doesn't fit ws.
// ---------------------------------------------------------------------------
__global__ __launch_bounds__(256) void gemm_f32b(
    const u16* __restrict__ A, const float* __restrict__ Bt,
    float* __restrict__ C0, int N, int K)
{
  __shared__ u16 As[128 * 32];
  __shared__ u16 Bs[128 * 32];
  const int tid = threadIdx.x;
  const int lane = tid & 63;
  const int w = tid >> 6;
  const int wr = w >> 1;
  const int wc = w & 1;

  const int T = (int)gridDim.x;
  const int bid = (int)blockIdx.x;
  const int q8 = T >> 3, r8 = T & 7;
  const int xcd = bid & 7, base = bid >> 3;
  int swz = (xcd < r8 ? xcd * (q8 + 1) : r8 * (q8 + 1) + (xcd - r8) * q8) + base;
  const int m0 = (swz & 15) * 128;
  const int n0 = (swz >> 4) * 128;

  f32x4 acc[4][4] = {};
  const u16* ga0 = A + (size_t)(m0 + w * 32 + (lane >> 2)) * K + (lane & 3) * 8;
  u16* la = &As[(w * 32) * 32];
  const float* gb32 = Bt + (size_t)(n0 + (tid >> 1)) * K + (tid & 1) * 16;
  u16* lbw = &Bs[(tid >> 1) * 32 + (tid & 1) * 16];

  for (int kt = 0; kt < K; kt += 32) {
    __syncthreads();
    gload_lds16(ga0 + kt, la);
    gload_lds16(ga0 + kt + 16 * K, la + 16 * 32);
    {
      const float4 f0 = *(const float4*)(gb32 + kt);
      const float4 f1 = *(const float4*)(gb32 + kt + 4);
      const float4 f2 = *(const float4*)(gb32 + kt + 8);
      const float4 f3 = *(const float4*)(gb32 + kt + 12);
      union { bf16x8 b; u16x8 u; } lo, hi;
      lo.b[0] = (__bf16)f0.x; lo.b[1] = (__bf16)f0.y;
      lo.b[2] = (__bf16)f0.z; lo.b[3] = (__bf16)f0.w;
      lo.b[4] = (__bf16)f1.x; lo.b[5] = (__bf16)f1.y;
      lo.b[6] = (__bf16)f1.z; lo.b[7] = (__bf16)f1.w;
      hi.b[0] = (__bf16)f2.x; hi.b[1] = (__bf16)f2.y;
      hi.b[2] = (__bf16)f2.z; hi.b[3] = (__bf16)f2.w;
      hi.b[4] = (__bf16)f3.x; hi.b[5] = (__bf16)f3.y;
      hi.b[6] = (__bf16)f3.z; hi.b[7] = (__bf16)f3.w;
      *(u16x8*)lbw = lo.u;
      *(u16x8*)(lbw + 8) = hi.u;
    }
    asm volatile("s_waitcnt vmcnt(0)" ::: "memory");
    __syncthreads();
    bf16x8 af[4], bfr[4];
#pragma unroll
    for (int m = 0; m < 4; ++m)
      af[m] = *(const bf16x8*)&As[(wr * 64 + m * 16 + (lane & 15)) * 32 + (lane >> 4) * 8];
#pragma unroll
    for (int n = 0; n < 4; ++n)
      bfr[n] = *(const bf16x8*)&Bs[(wc * 64 + n * 16 + (lane & 15)) * 32 + (lane >> 4) * 8];
#pragma unroll
    for (int m = 0; m < 4; ++m)
#pragma unroll
      for (int n = 0; n < 4; ++n)
        acc[m][n] = __builtin_amdgcn_mfma_f32_16x16x32_bf16(af[m], bfr[n], acc[m][n], 0, 0, 0);
  }

#pragma unroll
  for (int m = 0; m < 4; ++m) {
    const int rowb = m0 + wr * 64 + m * 16 + ((lane >> 4) << 2);
#pragma unroll
    for (int n = 0; n < 4; ++n) {
      const int col = n0 + wc * 64 + n * 16 + (lane & 15);
#pragma unroll
      for (int j = 0; j < 4; ++j)
        C0[(size_t)(rowb + j) * N + col] = acc[m][n][j];
    }
  }
}

// ---------------------------------------------------------------------------
// LayerNorm (plain): fp32 x[row][1024] -> bf16 h
// ---------------------------------------------------------------------------
__global__ __launch_bounds__(256) void ln_kernel(const float* __restrict__ x,
    const float* __restrict__ g, const float* __restrict__ b, u16* __restrict__ out)
{
  const int row = blockIdx.x;
  const int tid = threadIdx.x;
  const float4 v = ((const float4*)(x + (size_t)row * 1024))[tid];
  float s = v.x + v.y + v.z + v.w;
  float sq = v.x * v.x + v.y * v.y + v.z * v.z + v.w * v.w;
#pragma unroll
  for (int o = 1; o < 64; o <<= 1) { s += __shfl_xor(s, o); sq += __shfl_xor(sq, o); }
  __shared__ float ss[4], ssq[4];
  if ((tid & 63) == 0) { ss[tid >> 6] = s; ssq[tid >> 6] = sq; }
  __syncthreads();
  s = ss[0] + ss[1] + ss[2] + ss[3];
  sq = ssq[0] + ssq[1] + ssq[2] + ssq[3];
  const float mean = s * (1.0f / 1024.0f);
  const float var = sq * (1.0f / 1024.0f) - mean * mean;
  const float rstd = rsqrtf(var + 1e-5f);
  const int c = tid * 4;
  u16* o4 = out + (size_t)row * 1024 + c;
  const float4 gg = ((const float4*)g)[tid];
  const float4 bb = ((const float4*)b)[tid];
  o4[0] = f2b((v.x - mean) * rstd * gg.x + bb.x);
  o4[1] = f2b((v.y - mean) * rstd * gg.y + bb.y);
  o4[2] = f2b((v.z - mean) * rstd * gg.z + bb.z);
  o4[3] = f2b((v.w - mean) * rstd * gg.w + bb.w);
}

// ---------------------------------------------------------------------------
// Fused residual + LayerNorm: x_new = x + p0 + p1 (+bias); writes x_new (fp32)
// and h = ln(x_new)*g + b (bf16).
// ---------------------------------------------------------------------------
__global__ __launch_bounds__(256) void ln_res(float* __restrict__ x,
    const float* __restrict__ p0, const float* __restrict__ p1,
    const float* __restrict__ bias,
    const float* __restrict__ g, const float* __restrict__ b,
    u16* __restrict__ out)
{
  const int row = blockIdx.x;
  const int tid = threadIdx.x;
  const size_t off = (size_t)row * 1024;
  float4 v = ((const float4*)(x + off))[tid];
  const float4 a0 = ((const float4*)(p0 + off))[tid];
  const float4 a1 = ((const float4*)(p1 + off))[tid];
  v.x += a0.x + a1.x; v.y += a0.y + a1.y;
  v.z += a0.z + a1.z; v.w += a0.w + a1.w;
  if (bias != nullptr) {
    const float4 bi = ((const float4*)bias)[tid];
    v.x += bi.x; v.y += bi.y; v.z += bi.z; v.w += bi.w;
  }
  ((float4*)(x + off))[tid] = v;
  float s = v.x + v.y + v.z + v.w;
  float sq = v.x * v.x + v.y * v.y + v.z * v.z + v.w * v.w;
#pragma unroll
  for (int o = 1; o < 64; o <<= 1) { s += __shfl_xor(s, o); sq += __shfl_xor(sq, o); }
  __shared__ float ss[4], ssq[4];
  if ((tid & 63) == 0) { ss[tid >> 6] = s; ssq[tid >> 6] = sq; }
  __syncthreads();
  s = ss[0] + ss[1] + ss[2] + ss[3];
  sq = ssq[0] + ssq[1] + ssq[2] + ssq[3];
  const float mean = s * (1.0f / 1024.0f);
  const float var = sq * (1.0f / 1024.0f) - mean * mean;
  const float rstd = rsqrtf(var + 1e-5f);
  const int c = tid * 4;
  u16* o4 = out + off + c;
  const float4 gg = ((const float4*)g)[tid];
  const float4 bb = ((const float4*)b)[tid];
  o4[0] = f2b((v.x - mean) * rstd * gg.x + bb.x);
  o4[1] = f2b((v.y - mean) * rstd * gg.y + bb.y);
  o4[2] = f2b((v.z - mean) * rstd * gg.z + bb.z);
  o4[3] = f2b((v.w - mean) * rstd * gg.w + bb.w);
}

// ---------------------------------------------------------------------------
// Embedding gather: x[s][d] = emb_fp32[ids[s]][d]
// ---------------------------------------------------------------------------
__global__ __launch_bounds__(256) void gather_kernel(const int* __restrict__ ids,
    const float* __restrict__ emb, float* __restrict__ x)
{
  const int srow = blockIdx.x;
  const int tid = threadIdx.x;
  const int id = ids[srow];
  ((float4*)(x + (size_t)srow * 1024))[tid] =
      ((const float4*)(emb + (size_t)id * 1024))[tid];
}

// ---------------------------------------------------------------------------
// Flash attention w/ ALiBi + causal (R6 config, head-major XCD grid).
// ---------------------------------------------------------------------------
__global__ __launch_bounds__(256) void attn_kernel(
    const u16* __restrict__ q, const u16* __restrict__ k, const u16* __restrict__ v,
    const float* __restrict__ slopes, u16* __restrict__ out)
{
  const int bid = (int)blockIdx.x;
  const int swz = (bid & 7) * 32 + (bid >> 3);
  const int h = swz >> 4;
  const int q0 = (swz & 15) * 128;
  const int tid = threadIdx.x;
  const int lane = tid & 63;
  const int w = tid >> 6;
  const float slope = slopes[h];

  __shared__ u16 Ks[2][64 * 32];
  __shared__ u16 Vt[64][72];
  __shared__ u16 Pl[4][32][72];

  const u16* qb = q + ((size_t)h * SEQ + q0 + w * 32) * 64;
  bf16x8 qf[2][2];
#pragma unroll
  for (int m = 0; m < 2; ++m)
#pragma unroll
    for (int kk = 0; kk < 2; ++kk)
      qf[m][kk] = *(const bf16x8*)(qb + (m * 16 + (lane & 15)) * 64 + kk * 32 + (lane >> 4) * 8);

  f32x4 o_acc[2][4] = {};
  float mrun[2][4], lrun[2][4];
#pragma unroll
  for (int m = 0; m < 2; ++m)
#pragma unroll
    for (int j = 0; j < 4; ++j) { mrun[m][j] = -1e30f; lrun[m][j] = 0.0f; }

  const int ntiles = (q0 >> 6) + 2;
  const int wmaxrow = q0 + w * 32 + 31;

  const int kkp = w >> 1, halfp = w & 1;
  const u16* gk0 = k + ((size_t)h * SEQ + halfp * 32 + (lane >> 2)) * 64 + kkp * 32 + (lane & 3) * 8;
  u16* lk = &Ks[kkp][(halfp * 32) * 32];
  const u16* gv0 = v + ((size_t)h * SEQ + lane) * 64 + w * 16;

  for (int t = 0; t < ntiles; ++t) {
    const int j0 = t << 6;
    __syncthreads();
    gload_lds16(gk0 + (size_t)j0 * 64, lk);
    gload_lds16(gk0 + (size_t)(j0 + 16) * 64, lk + 16 * 32);
    {
      const u16* gvp = gv0 + (size_t)j0 * 64;
      u16x8 v0 = *(const u16x8*)gvp;
      u16x8 v1 = *(const u16x8*)(gvp + 8);
      const int d0 = w * 16;
#pragma unroll
      for (int i = 0; i < 8; ++i) Vt[d0 + i][lane] = v0[i];
#pragma unroll
      for (int i = 0; i < 8; ++i) Vt[d0 + 8 + i][lane] = v1[i];
    }
    asm volatile("s_waitcnt vmcnt(0)" ::: "memory");
    __syncthreads();

    if (wmaxrow >= j0) {
      f32x4 s[2][4] = {};
      __builtin_amdgcn_s_setprio(1);
#pragma unroll
      for (int kk = 0; kk < 2; ++kk) {
        bf16x8 kf[4];
#pragma unroll
        for (int n = 0; n < 4; ++n)
          kf[n] = *(const bf16x8*)&Ks[kk][(n * 16 + (lane & 15)) * 32 + (lane >> 4) * 8];
#pragma unroll
        for (int m = 0; m < 2; ++m)
#pragma unroll
          for (int n = 0; n < 4; ++n)
            s[m][n] = __builtin_amdgcn_mfma_f32_16x16x32_bf16(qf[m][kk], kf[n], s[m][n], 0, 0, 0);
      }
      __builtin_amdgcn_s_setprio(0);
      const int rq = q0 + w * 32 + ((lane >> 4) << 2);
      const int ck = j0 + (lane & 15);
#pragma unroll
      for (int m = 0; m < 2; ++m) {
#pragma unroll
        for (int j = 0; j < 4; ++j) {
          const int qi = rq + m * 16 + j;
          float mx = -1e30f;
#pragma unroll
          for (int n = 0; n < 4; ++n) {
            const int kj = ck + n * 16;
            float val = s[m][n][j] * 0.125f - slope * (float)(kj - qi);
            val = (kj <= qi) ? val : -1e30f;
            s[m][n][j] = val;
            mx = fmaxf(mx, val);
          }
#pragma unroll
          for (int o = 1; o < 16; o <<= 1) mx = fmaxf(mx, __shfl_xor(mx, o));
          const float mnew = fmaxf(mrun[m][j], mx);
          const float alpha = __expf(mrun[m][j] - mnew);
          mrun[m][j] = mnew;
          float rs = 0.0f;
          const int prow = m * 16 + ((lane >> 4) << 2) + j;
#pragma unroll
          for (int n = 0; n < 4; ++n) {
            const float p = __expf(s[m][n][j] - mnew);
            rs += p;
            Pl[w][prow][n * 16 + (lane & 15)] = f2b(p);
          }
#pragma unroll
          for (int o = 1; o < 16; o <<= 1) rs += __shfl_xor(rs, o);
          lrun[m][j] = lrun[m][j] * alpha + rs;
#pragma unroll
          for (int n = 0; n < 4; ++n) o_acc[m][n][j] *= alpha;
        }
      }
      __builtin_amdgcn_s_setprio(1);
#pragma unroll
      for (int kk = 0; kk < 2; ++kk) {
        bf16x8 pf[2], vf[4];
#pragma unroll
        for (int m = 0; m < 2; ++m)
          pf[m] = *(const bf16x8*)&Pl[w][m * 16 + (lane & 15)][kk * 32 + (lane >> 4) * 8];
#pragma unroll
        for (int n = 0; n < 4; ++n)
          vf[n] = *(const bf16x8*)&Vt[n * 16 + (lane & 15)][kk * 32 + (lane >> 4) * 8];
#pragma unroll
        for (int m = 0; m < 2; ++m)
#pragma unroll
          for (int n = 0; n < 4; ++n)
            o_acc[m][n] = __builtin_amdgcn_mfma_f32_16x16x32_bf16(pf[m], vf[n], o_acc[m][n], 0, 0, 0);
      }
      __builtin_amdgcn_s_setprio(0);
    }
  }

#pragma unroll
  for (int m = 0; m < 2; ++m) {
    const int sbase = q0 + w * 32 + m * 16 + ((lane >> 4) << 2);
#pragma unroll
    for (int n = 0; n < 4; ++n) {
      const int d = h * 64 + n * 16 + (lane & 15);
#pragma unroll
      for (int j = 0; j < 4; ++j)
        out[(size_t)(sbase + j) * 1024 + d] = f2b(o_acc[m][n][j] / lrun[m][j]);
    }
  }
}

// ---------------------------------------------------------------------------
extern "C" void kernel_launch(void* const* d_in, const int* in_sizes, int n_in,
                              void* d_out, int out_size, void* d_ws, size_t ws_size,
                              hipStream_t stream)
{
  (void)in_sizes; (void)n_in; (void)out_size;
  const int* ids = (const int*)d_in[0];
  const float* emb = (const float*)d_in[1];
  const float* slopes = (const float*)d_in[2];
  const float* Wq = (const float*)d_in[3];
  const float* Wk = (const float*)d_in[4];
  const float* Wv = (const float*)d_in[5];
  const float* Wo = (const float*)d_in[6];
  const float* W1 = (const float*)d_in[7];
  const float* b1 = (const float*)d_in[8];
  const float* W2 = (const float*)d_in[9];
  const float* b2 = (const float*)d_in[10];
  const float* g1 = (const float*)d_in[11];
  const float* be1 = (const float*)d_in[12];
  const float* g2 = (const float*)d_in[13];
  const float* be2 = (const float*)d_in[14];
  const float* gf = (const float*)d_in[15];
  const float* bfin = (const float*)d_in[16];

  char* ob = (char*)d_out;
  float* x    = (float*)ob;                         // 8 MB fp32 residual
  u16* qb     = (u16*)(ob + (size_t)( 8u << 20));   // 4 MB
  u16* kb     = (u16*)(ob + (size_t)(12u << 20));   // 4 MB
  u16* vb     = (u16*)(ob + (size_t)(16u << 20));   // 4 MB
  u16* attn   = (u16*)(ob + (size_t)(20u << 20));   // 4 MB
  u16* ff     = (u16*)(ob + (size_t)(24u << 20));   // 16 MB
  u16* Wqkv_b = (u16*)(ob + (size_t)( 40u << 20));  // 24 MB  [4][3072][1024]
  u16* Wo_b   = (u16*)(ob + (size_t)( 64u << 20));  // 8 MB
  u16* W1_b   = (u16*)(ob + (size_t)( 72u << 20));  // 32 MB
  u16* W2_b   = (u16*)(ob + (size_t)(104u << 20));  // 32 MB
  float* p0   = (float*)(ob + (size_t)(136u << 20)); // 8 MB split-K partial
  float* p1   = (float*)(ob + (size_t)(144u << 20)); // 8 MB
  u16* h      = (u16*)d_ws;                          // 4 MB
  const size_t emb_b_need = (size_t)(4u << 20) + (size_t)32000 * 1024 * 2;
  const bool emb_fits = ws_size >= emb_b_need;
  u16* emb_b = (u16*)((char*)d_ws + (4u << 20));
  float* logits = (float*)d_out;

  {
    CvtArgs a;
    const u32 wsz = 4 * 1024 * 1024 / 8;            // all-4-layer [D][D] tensor
    const u32 fsz = 16 * 1024 * 1024 / 8;
    const u32 esz = 32000 * 1024 / 8;
    a.src[0] = Wq; a.dst[0] = Wqkv_b;                    // remapped (s<3)
    a.src[1] = Wk; a.dst[1] = Wqkv_b + 1024 * 1024;
    a.src[2] = Wv; a.dst[2] = Wqkv_b + 2 * 1024 * 1024;
    a.src[3] = Wo; a.dst[3] = Wo_b;
    a.src[4] = W1; a.dst[4] = W1_b;
    a.src[5] = W2; a.dst[5] = W2_b;
    a.src[6] = emb; a.dst[6] = emb_b;
    a.beg[0] = 0;
    a.beg[1] = wsz;      a.beg[2] = 2 * wsz;  a.beg[3] = 3 * wsz;
    a.beg[4] = 4 * wsz;  a.beg[5] = 4 * wsz + fsz;  a.beg[6] = 4 * wsz + 2 * fsz;
    a.beg[7] = a.beg[6] + esz;
    a.total = emb_fits ? a.beg[7] : a.beg[6];
    cvt_all<<<2048, 256, 0, stream>>>(a);
  }

  gather_kernel<<<2048, 256, 0, stream>>>(ids, emb, x);
  ln_kernel<<<2048, 256, 0, stream>>>(x, g1, be1, h);

  for (int l = 0; l < 4; ++l) {
    const size_t wqkv = (size_t)l * 3072 * 1024;
    const size_t wo = (size_t)l * 1024 * 1024;
    const size_t wf = (size_t)l * 4096 * 1024;
    // QKV (concat, N=3072): 16 M x 24 N = 384 blocks
    gemm128p<1><<<dim3(384, 1, 1), 256, 0, stream>>>(h, Wqkv_b + wqkv,
        qb, kb, vb, nullptr, 3072, 1024);
    attn_kernel<<<dim3(256, 1, 1), 256, 0, stream>>>(qb, kb, vb, slopes, attn);
    // O-proj: N=1024, split-K z=2 -> fp32 partials p0/p1
    gemm128p<0><<<dim3(128, 1, 2), 256, 0, stream>>>(attn, Wo_b + wo,
        p0, p1, nullptr, nullptr, 1024, 1024);
    ln_res<<<2048, 256, 0, stream>>>(x, p0, p1, nullptr,
        g2 + l * 1024, be2 + l * 1024, h);
    // FFN1: N=4096 -> 16 x 32 = 512 blocks, gelu+bias epilogue
    gemm128p<2><<<dim3(512, 1, 1), 256, 0, stream>>>(h, W1_b + wf,
        ff, nullptr, nullptr, b1 + l * 4096, 4096, 1024);
    // FFN2: N=1024, K=4096, split-K z=2 -> partials
    gemm128p<0><<<dim3(128, 1, 2), 256, 0, stream>>>(ff, W2_b + wf,
        p0, p1, nullptr, nullptr, 1024, 4096);
    if (l < 3) {
      ln_res<<<2048, 256, 0, stream>>>(x, p0, p1, b2 + l * 1024,
          g1 + (l + 1) * 1024, be1 + (l + 1) * 1024, h);
    } else {
      ln_res<<<2048, 256, 0, stream>>>(x, p0, p1, b2 + l * 1024, gf, bfin, h);
    }
  }

  if (emb_fits) {
    gemm256<<<dim3(1000, 1, 1), 512, 0, stream>>>(h, emb_b, logits, 32000, 1024);
  } else {
    gemm_f32b<<<dim3(4000, 1, 1), 256, 0, stream>>>(h, emb, logits, 32000, 1024);
  }
}

// Round 10
// 1234.602 us; speedup vs baseline: 1.1221x; 1.0428x over previous
//
#include <hip/hip_runtime.h>
#include <hip/hip_bf16.h>

typedef unsigned int u32;
typedef unsigned short u16;
typedef __attribute__((ext_vector_type(8))) __bf16 bf16x8;
typedef __attribute__((ext_vector_type(8))) unsigned short u16x8;
typedef __attribute__((ext_vector_type(4))) float f32x4;

#define SEQ 2048

__device__ __forceinline__ float b2f(u16 u) {
  union { u32 i; float f; } x; x.i = ((u32)u) << 16; return x.f;
}
__device__ __forceinline__ u16 f2b(float f) {
  u32 u = __float_as_uint(f);
  u = (u + 0x7fffu + ((u >> 16) & 1u)) >> 16;
  return (u16)u;
}
__device__ __forceinline__ void gload_lds16(const void* g, void* l) {
  __builtin_amdgcn_global_load_lds((const __attribute__((address_space(1))) u32*)g,
                                   (__attribute__((address_space(3))) u32*)l, 16, 0, 0);
}

// ---------------------------------------------------------------------------
// Fused fp32 -> bf16 bulk convert. Segments 0-2 (Wq/Wk/Wv) are remapped into
// a concatenated [L][3072][1024] layout.
// ---------------------------------------------------------------------------
struct CvtArgs {
  const float* src[7];
  u16* dst[7];
  u32 beg[8];
  u32 total;
};

__global__ __launch_bounds__(256) void cvt_all(CvtArgs a)
{
  for (u32 i = blockIdx.x * 256 + threadIdx.x; i < a.total; i += gridDim.x * 256) {
    int s = 0;
#pragma unroll
    for (int k = 1; k < 7; ++k) s += (i >= a.beg[k]);
    const u32 li = i - a.beg[s];
    const float* in = a.src[s];
    const float4 f0 = ((const float4*)in)[(size_t)li * 2];
    const float4 f1 = ((const float4*)in)[(size_t)li * 2 + 1];
    union { bf16x8 b; u16x8 u; } r;
    r.b[0] = (__bf16)f0.x; r.b[1] = (__bf16)f0.y;
    r.b[2] = (__bf16)f0.z; r.b[3] = (__bf16)f0.w;
    r.b[4] = (__bf16)f1.x; r.b[5] = (__bf16)f1.y;
    r.b[6] = (__bf16)f1.z; r.b[7] = (__bf16)f1.w;
    u16* d;
    if (s < 3) {
      const u32 layer = li >> 17;
      const u32 rem = li & 131071u;
      d = a.dst[s] + ((size_t)layer * 393216u + rem) * 8;
    } else {
      d = a.dst[s] + (size_t)li * 8;
    }
    *(u16x8*)d = r.u;
  }
}

// ---------------------------------------------------------------------------
// 256x256 pipelined GEMM (logits) — R8-proven. raw s_barrier + counted vmcnt.
// ---------------------------------------------------------------------------
__global__ __launch_bounds__(512, 2) void gemm256(
    const u16* __restrict__ A, const u16* __restrict__ Bt,
    float* __restrict__ C, int N, int K)
{
  __shared__ u16 As[2][256 * 64];
  __shared__ u16 Bs[2][256 * 64];
  const int tid = threadIdx.x;
  const int lane = tid & 63;
  const int wid = tid >> 6;
  const int wr = wid >> 2;
  const int wc = wid & 3;

  const int T = (int)gridDim.x;
  const int bid = (int)blockIdx.x;
  const int q8 = T >> 3, r8 = T & 7;
  const int xcd = bid & 7, base = bid >> 3;
  const int swz = (xcd < r8 ? xcd * (q8 + 1) : r8 * (q8 + 1) + (xcd - r8) * q8) + base;
  const int m0 = (swz & 7) * 256;
  const int n0 = (swz >> 3) * 256;

  f32x4 acc[8][4] = {};

  const int srow = tid >> 3;
  const int sgr = (tid & 7) ^ (srow & 7);
  const u16* gA = A + (size_t)(m0 + srow) * K + sgr * 8;
  const u16* gB = Bt + (size_t)(n0 + srow) * K + sgr * 8;
  const int dwave = wid * 512;

  const int co0 = (((lane >> 4)) ^ (lane & 7)) * 8;
  const int co1 = (((lane >> 4) + 4) ^ (lane & 7)) * 8;
  const int raA = (wr * 128 + (lane & 15)) * 64;
  const int raB = (wc * 64 + (lane & 15)) * 64;

  const int nk = K >> 6;

#pragma unroll
  for (int c = 0; c < 4; ++c) {
    gload_lds16(gA + (size_t)(c * 64) * K, &As[0][c * 4096 + dwave]);
    gload_lds16(gB + (size_t)(c * 64) * K, &Bs[0][c * 4096 + dwave]);
  }
#pragma unroll
  for (int c = 0; c < 4; ++c) {
    gload_lds16(gA + (size_t)(c * 64) * K + 64, &As[1][c * 4096 + dwave]);
    gload_lds16(gB + (size_t)(c * 64) * K + 64, &Bs[1][c * 4096 + dwave]);
  }
  asm volatile("s_waitcnt vmcnt(8)" ::: "memory");
  __builtin_amdgcn_s_barrier();
  __builtin_amdgcn_sched_barrier(0);

#pragma unroll 2
  for (int t = 0; t < nk; ++t) {
    const int cb = t & 1;
    const u16* Acur = &As[cb][0];
    const u16* Bcur = &Bs[cb][0];

    bf16x8 bf[4][2];
#pragma unroll
    for (int n = 0; n < 4; ++n) {
      const int ro = raB + n * 16 * 64;
      bf[n][0] = *(const bf16x8*)&Bcur[ro + co0];
      bf[n][1] = *(const bf16x8*)&Bcur[ro + co1];
    }
#pragma unroll
    for (int p = 0; p < 4; ++p) {
      bf16x8 af[2][2];
#pragma unroll
      for (int mm = 0; mm < 2; ++mm) {
        const int ro = raA + (p * 32 + mm * 16) * 64;
        af[mm][0] = *(const bf16x8*)&Acur[ro + co0];
        af[mm][1] = *(const bf16x8*)&Acur[ro + co1];
      }
      __builtin_amdgcn_s_setprio(1);
#pragma unroll
      for (int mm = 0; mm < 2; ++mm)
#pragma unroll
        for (int n = 0; n < 4; ++n) {
          acc[p * 2 + mm][n] = __builtin_amdgcn_mfma_f32_16x16x32_bf16(af[mm][0], bf[n][0], acc[p * 2 + mm][n], 0, 0, 0);
          acc[p * 2 + mm][n] = __builtin_amdgcn_mfma_f32_16x16x32_bf16(af[mm][1], bf[n][1], acc[p * 2 + mm][n], 0, 0, 0);
        }
      __builtin_amdgcn_s_setprio(0);
    }

    __builtin_amdgcn_s_barrier();
    if (t + 2 < nk) {
      const size_t kto = (size_t)(t + 2) * 64;
      u16* Anx = &As[cb][0];
      u16* Bnx = &Bs[cb][0];
#pragma unroll
      for (int c = 0; c < 4; ++c) {
        gload_lds16(gA + (size_t)(c * 64) * K + kto, Anx + c * 4096 + dwave);
        gload_lds16(gB + (size_t)(c * 64) * K + kto, Bnx + c * 4096 + dwave);
      }
      asm volatile("s_waitcnt vmcnt(8)" ::: "memory");
    } else if (t + 1 < nk) {
      asm volatile("s_waitcnt vmcnt(0)" ::: "memory");
    }
    __builtin_amdgcn_s_barrier();
    __builtin_amdgcn_sched_barrier(0);
  }

  const int crow = m0 + wr * 128 + ((lane >> 4) << 2);
  const int ccol = n0 + wc * 64 + (lane & 15);
#pragma unroll
  for (int m = 0; m < 8; ++m)
#pragma unroll
    for (int n = 0; n < 4; ++n)
#pragma unroll
      for (int j = 0; j < 4; ++j)
        C[(size_t)(crow + m * 16 + j) * N + ccol + n * 16] = acc[m][n][j];
}

// ---------------------------------------------------------------------------
// 128x128 pipelined layer GEMM (R9 structure, generalized split-K partials).
// EPI 0: fp32 partial store to P + blockIdx.z * (2048*1024)
// EPI 1: QKV head-major bf16 from concat [3072][1024] weights
// EPI 2: bf16 gelu(acc + bias[col])
// ---------------------------------------------------------------------------
template <int EPI>
__global__ __launch_bounds__(256, 2) void gemm128p(
    const u16* __restrict__ A, const u16* __restrict__ Bt,
    void* __restrict__ C0, void* __restrict__ C1, void* __restrict__ C2,
    const float* __restrict__ bias, int N, int K)
{
  __shared__ u16 As[2][128 * 64];
  __shared__ u16 Bs[2][128 * 64];
  const int tid = threadIdx.x;
  const int lane = tid & 63;
  const int wid = tid >> 6;
  const int wr = wid >> 1;
  const int wc = wid & 1;

  const int T = (int)gridDim.x;
  const int bid = (int)blockIdx.x;
  const int q8 = T >> 3, r8 = T & 7;
  const int xcd = bid & 7, base = bid >> 3;
  const int swz = (xcd < r8 ? xcd * (q8 + 1) : r8 * (q8 + 1) + (xcd - r8) * q8) + base;
  const int m0 = (swz & 15) * 128;
  const int n0 = (swz >> 4) * 128;

  const int kchunk = K / (int)gridDim.z;
  const int kbeg = (int)blockIdx.z * kchunk;
  const int nk = kchunk >> 6;

  f32x4 acc[4][4] = {};

  const int srow = tid >> 3;
  const int sgr = (tid & 7) ^ (srow & 7);
  const u16* gA = A + (size_t)(m0 + srow) * K + kbeg + sgr * 8;
  const u16* gB = Bt + (size_t)(n0 + srow) * K + kbeg + sgr * 8;
  const int dwave = wid * 512;

  const int co0 = (((lane >> 4)) ^ (lane & 7)) * 8;
  const int co1 = (((lane >> 4) + 4) ^ (lane & 7)) * 8;
  const int raA = (wr * 64 + (lane & 15)) * 64;
  const int raB = (wc * 64 + (lane & 15)) * 64;

#pragma unroll
  for (int c = 0; c < 4; ++c) {
    gload_lds16(gA + (size_t)(c * 32) * K, &As[0][c * 2048 + dwave]);
    gload_lds16(gB + (size_t)(c * 32) * K, &Bs[0][c * 2048 + dwave]);
  }
#pragma unroll
  for (int c = 0; c < 4; ++c) {
    gload_lds16(gA + (size_t)(c * 32) * K + 64, &As[1][c * 2048 + dwave]);
    gload_lds16(gB + (size_t)(c * 32) * K + 64, &Bs[1][c * 2048 + dwave]);
  }
  asm volatile("s_waitcnt vmcnt(8)" ::: "memory");
  __builtin_amdgcn_s_barrier();
  __builtin_amdgcn_sched_barrier(0);

#pragma unroll 2
  for (int t = 0; t < nk; ++t) {
    const int cb = t & 1;
    const u16* Acur = &As[cb][0];
    const u16* Bcur = &Bs[cb][0];

    bf16x8 bf[4][2];
#pragma unroll
    for (int n = 0; n < 4; ++n) {
      const int ro = raB + n * 16 * 64;
      bf[n][0] = *(const bf16x8*)&Bcur[ro + co0];
      bf[n][1] = *(const bf16x8*)&Bcur[ro + co1];
    }
#pragma unroll
    for (int p = 0; p < 4; ++p) {
      bf16x8 af[2];
      {
        const int ro = raA + p * 16 * 64;
        af[0] = *(const bf16x8*)&Acur[ro + co0];
        af[1] = *(const bf16x8*)&Acur[ro + co1];
      }
      __builtin_amdgcn_s_setprio(1);
#pragma unroll
      for (int n = 0; n < 4; ++n) {
        acc[p][n] = __builtin_amdgcn_mfma_f32_16x16x32_bf16(af[0], bf[n][0], acc[p][n], 0, 0, 0);
        acc[p][n] = __builtin_amdgcn_mfma_f32_16x16x32_bf16(af[1], bf[n][1], acc[p][n], 0, 0, 0);
      }
      __builtin_amdgcn_s_setprio(0);
    }

    __builtin_amdgcn_s_barrier();
    if (t + 2 < nk) {
      const size_t kto = (size_t)(t + 2) * 64;
      u16* Anx = &As[cb][0];
      u16* Bnx = &Bs[cb][0];
#pragma unroll
      for (int c = 0; c < 4; ++c) {
        gload_lds16(gA + (size_t)(c * 32) * K + kto, Anx + c * 2048 + dwave);
        gload_lds16(gB + (size_t)(c * 32) * K + kto, Bnx + c * 2048 + dwave);
      }
      asm volatile("s_waitcnt vmcnt(8)" ::: "memory");
    } else if (t + 1 < nk) {
      asm volatile("s_waitcnt vmcnt(0)" ::: "memory");
    }
    __builtin_amdgcn_s_barrier();
    __builtin_amdgcn_sched_barrier(0);
  }

  const int z = (int)blockIdx.z;
#pragma unroll
  for (int m = 0; m < 4; ++m) {
    const int rowb = m0 + wr * 64 + m * 16 + ((lane >> 4) << 2);
#pragma unroll
    for (int n = 0; n < 4; ++n) {
      const int col = n0 + wc * 64 + n * 16 + (lane & 15);
#pragma unroll
      for (int j = 0; j < 4; ++j) {
        const int r = rowb + j;
        float v = acc[m][n][j];
        if (EPI == 0) {
          float* outp = (float*)C0 + (size_t)z * (2048u * 1024u);
          outp[(size_t)r * N + col] = v;
        } else if (EPI == 1) {
          const int which = col >> 10;
          const int ci = col & 1023;
          u16* outp = (u16*)((which == 0) ? C0 : (which == 1) ? C1 : C2);
          outp[((size_t)(ci >> 6) * SEQ + r) * 64 + (ci & 63)] = f2b(v);
        } else {
          float xx = v + bias[col];
          float ge = 0.5f * xx * (1.0f + erff(xx * 0.70710678118654752f));
          ((u16*)C0)[(size_t)r * N + col] = f2b(ge);
        }
      }
    }
  }
}

// ---------------------------------------------------------------------------
// Fallback logits GEMM (fp32 B, BK=32) if emb_bf16 doesn't fit ws.
// ---------------------------------------------------------------------------
__global__ __launch_bounds__(256) void gemm_f32b(
    const u16* __restrict__ A, const float* __restrict__ Bt,
    float* __restrict__ C0, int N, int K)
{
  __shared__ u16 As[128 * 32];
  __shared__ u16 Bs[128 * 32];
  const int tid = threadIdx.x;
  const int lane = tid & 63;
  const int w = tid >> 6;
  const int wr = w >> 1;
  const int wc = w & 1;

  const int T = (int)gridDim.x;
  const int bid = (int)blockIdx.x;
  const int q8 = T >> 3, r8 = T & 7;
  const int xcd = bid & 7, base = bid >> 3;
  int swz = (xcd < r8 ? xcd * (q8 + 1) : r8 * (q8 + 1) + (xcd - r8) * q8) + base;
  const int m0 = (swz & 15) * 128;
  const int n0 = (swz >> 4) * 128;

  f32x4 acc[4][4] = {};
  const u16* ga0 = A + (size_t)(m0 + w * 32 + (lane >> 2)) * K + (lane & 3) * 8;
  u16* la = &As[(w * 32) * 32];
  const float* gb32 = Bt + (size_t)(n0 + (tid >> 1)) * K + (tid & 1) * 16;
  u16* lbw = &Bs[(tid >> 1) * 32 + (tid & 1) * 16];

  for (int kt = 0; kt < K; kt += 32) {
    __syncthreads();
    gload_lds16(ga0 + kt, la);
    gload_lds16(ga0 + kt + 16 * K, la + 16 * 32);
    {
      const float4 f0 = *(const float4*)(gb32 + kt);
      const float4 f1 = *(const float4*)(gb32 + kt + 4);
      const float4 f2 = *(const float4*)(gb32 + kt + 8);
      const float4 f3 = *(const float4*)(gb32 + kt + 12);
      union { bf16x8 b; u16x8 u; } lo, hi;
      lo.b[0] = (__bf16)f0.x; lo.b[1] = (__bf16)f0.y;
      lo.b[2] = (__bf16)f0.z; lo.b[3] = (__bf16)f0.w;
      lo.b[4] = (__bf16)f1.x; lo.b[5] = (__bf16)f1.y;
      lo.b[6] = (__bf16)f1.z; lo.b[7] = (__bf16)f1.w;
      hi.b[0] = (__bf16)f2.x; hi.b[1] = (__bf16)f2.y;
      hi.b[2] = (__bf16)f2.z; hi.b[3] = (__bf16)f2.w;
      hi.b[4] = (__bf16)f3.x; hi.b[5] = (__bf16)f3.y;
      hi.b[6] = (__bf16)f3.z; hi.b[7] = (__bf16)f3.w;
      *(u16x8*)lbw = lo.u;
      *(u16x8*)(lbw + 8) = hi.u;
    }
    asm volatile("s_waitcnt vmcnt(0)" ::: "memory");
    __syncthreads();
    bf16x8 af[4], bfr[4];
#pragma unroll
    for (int m = 0; m < 4; ++m)
      af[m] = *(const bf16x8*)&As[(wr * 64 + m * 16 + (lane & 15)) * 32 + (lane >> 4) * 8];
#pragma unroll
    for (int n = 0; n < 4; ++n)
      bfr[n] = *(const bf16x8*)&Bs[(wc * 64 + n * 16 + (lane & 15)) * 32 + (lane >> 4) * 8];
#pragma unroll
    for (int m = 0; m < 4; ++m)
#pragma unroll
      for (int n = 0; n < 4; ++n)
        acc[m][n] = __builtin_amdgcn_mfma_f32_16x16x32_bf16(af[m], bfr[n], acc[m][n], 0, 0, 0);
  }

#pragma unroll
  for (int m = 0; m < 4; ++m) {
    const int rowb = m0 + wr * 64 + m * 16 + ((lane >> 4) << 2);
#pragma unroll
    for (int n = 0; n < 4; ++n) {
      const int col = n0 + wc * 64 + n * 16 + (lane & 15);
#pragma unroll
      for (int j = 0; j < 4; ++j)
        C0[(size_t)(rowb + j) * N + col] = acc[m][n][j];
    }
  }
}

// ---------------------------------------------------------------------------
// LayerNorm (plain): fp32 x[row][1024] -> bf16 h
// ---------------------------------------------------------------------------
__global__ __launch_bounds__(256) void ln_kernel(const float* __restrict__ x,
    const float* __restrict__ g, const float* __restrict__ b, u16* __restrict__ out)
{
  const int row = blockIdx.x;
  const int tid = threadIdx.x;
  const float4 v = ((const float4*)(x + (size_t)row * 1024))[tid];
  float s = v.x + v.y + v.z + v.w;
  float sq = v.x * v.x + v.y * v.y + v.z * v.z + v.w * v.w;
#pragma unroll
  for (int o = 1; o < 64; o <<= 1) { s += __shfl_xor(s, o); sq += __shfl_xor(sq, o); }
  __shared__ float ss[4], ssq[4];
  if ((tid & 63) == 0) { ss[tid >> 6] = s; ssq[tid >> 6] = sq; }
  __syncthreads();
  s = ss[0] + ss[1] + ss[2] + ss[3];
  sq = ssq[0] + ssq[1] + ssq[2] + ssq[3];
  const float mean = s * (1.0f / 1024.0f);
  const float var = sq * (1.0f / 1024.0f) - mean * mean;
  const float rstd = rsqrtf(var + 1e-5f);
  const int c = tid * 4;
  u16* o4 = out + (size_t)row * 1024 + c;
  const float4 gg = ((const float4*)g)[tid];
  const float4 bb = ((const float4*)b)[tid];
  o4[0] = f2b((v.x - mean) * rstd * gg.x + bb.x);
  o4[1] = f2b((v.y - mean) * rstd * gg.y + bb.y);
  o4[2] = f2b((v.z - mean) * rstd * gg.z + bb.z);
  o4[3] = f2b((v.w - mean) * rstd * gg.w + bb.w);
}

// ---------------------------------------------------------------------------
// Fused residual + LayerNorm, 4 split-K partials:
// x_new = x + P[0]+P[1]+P[2]+P[3] (+bias); writes x_new (fp32) and
// h = ln(x_new)*g + b (bf16).
// ---------------------------------------------------------------------------
__global__ __launch_bounds__(256) void ln_res4(float* __restrict__ x,
    const float* __restrict__ P, const float* __restrict__ bias,
    const float* __restrict__ g, const float* __restrict__ b,
    u16* __restrict__ out)
{
  const int row = blockIdx.x;
  const int tid = threadIdx.x;
  const size_t off = (size_t)row * 1024;
  float4 v = ((const float4*)(x + off))[tid];
#pragma unroll
  for (int j = 0; j < 4; ++j) {
    const float4 a = ((const float4*)(P + (size_t)j * 2048 * 1024 + off))[tid];
    v.x += a.x; v.y += a.y; v.z += a.z; v.w += a.w;
  }
  if (bias != nullptr) {
    const float4 bi = ((const float4*)bias)[tid];
    v.x += bi.x; v.y += bi.y; v.z += bi.z; v.w += bi.w;
  }
  ((float4*)(x + off))[tid] = v;
  float s = v.x + v.y + v.z + v.w;
  float sq = v.x * v.x + v.y * v.y + v.z * v.z + v.w * v.w;
#pragma unroll
  for (int o = 1; o < 64; o <<= 1) { s += __shfl_xor(s, o); sq += __shfl_xor(sq, o); }
  __shared__ float ss[4], ssq[4];
  if ((tid & 63) == 0) { ss[tid >> 6] = s; ssq[tid >> 6] = sq; }
  __syncthreads();
  s = ss[0] + ss[1] + ss[2] + ss[3];
  sq = ssq[0] + ssq[1] + ssq[2] + ssq[3];
  const float mean = s * (1.0f / 1024.0f);
  const float var = sq * (1.0f / 1024.0f) - mean * mean;
  const float rstd = rsqrtf(var + 1e-5f);
  const int c = tid * 4;
  u16* o4 = out + off + c;
  const float4 gg = ((const float4*)g)[tid];
  const float4 bb = ((const float4*)b)[tid];
  o4[0] = f2b((v.x - mean) * rstd * gg.x + bb.x);
  o4[1] = f2b((v.y - mean) * rstd * gg.y + bb.y);
  o4[2] = f2b((v.z - mean) * rstd * gg.z + bb.z);
  o4[3] = f2b((v.w - mean) * rstd * gg.w + bb.w);
}

// ---------------------------------------------------------------------------
// Embedding gather: x[s][d] = emb_fp32[ids[s]][d]
// ---------------------------------------------------------------------------
__global__ __launch_bounds__(256) void gather_kernel(const int* __restrict__ ids,
    const float* __restrict__ emb, float* __restrict__ x)
{
  const int srow = blockIdx.x;
  const int tid = threadIdx.x;
  const int id = ids[srow];
  ((float4*)(x + (size_t)srow * 1024))[tid] =
      ((const float4*)(emb + (size_t)id * 1024))[tid];
}

// ---------------------------------------------------------------------------
// Flash attention w/ ALiBi + causal. K-LDS granule^row&3 XOR swizzle
// (pre-swizzled global source + same XOR on read, linear gload_lds dest).
// ---------------------------------------------------------------------------
__global__ __launch_bounds__(256) void attn_kernel(
    const u16* __restrict__ q, const u16* __restrict__ k, const u16* __restrict__ v,
    const float* __restrict__ slopes, u16* __restrict__ out)
{
  const int bid = (int)blockIdx.x;
  const int swz = (bid & 7) * 32 + (bid >> 3);
  const int h = swz >> 4;
  const int q0 = (swz & 15) * 128;
  const int tid = threadIdx.x;
  const int lane = tid & 63;
  const int w = tid >> 6;
  const float slope = slopes[h];

  __shared__ u16 Ks[2][64 * 32];
  __shared__ u16 Vt[64][72];
  __shared__ u16 Pl[4][32][72];

  const u16* qb = q + ((size_t)h * SEQ + q0 + w * 32) * 64;
  bf16x8 qf[2][2];
#pragma unroll
  for (int m = 0; m < 2; ++m)
#pragma unroll
    for (int kk = 0; kk < 2; ++kk)
      qf[m][kk] = *(const bf16x8*)(qb + (m * 16 + (lane & 15)) * 64 + kk * 32 + (lane >> 4) * 8);

  f32x4 o_acc[2][4] = {};
  float mrun[2][4], lrun[2][4];
#pragma unroll
  for (int m = 0; m < 2; ++m)
#pragma unroll
    for (int j = 0; j < 4; ++j) { mrun[m][j] = -1e30f; lrun[m][j] = 0.0f; }

  const int ntiles = (q0 >> 6) + 2;
  const int wmaxrow = q0 + w * 32 + 31;

  const int kkp = w >> 1, halfp = w & 1;
  // K staging: lane -> row halfp*32+(lane>>2), dest slot lane&3;
  // pre-swizzled source granule = (lane&3) ^ ((lane>>2)&3)
  const int ksl = (lane & 3) ^ ((lane >> 2) & 3);
  const u16* gk0 = k + ((size_t)h * SEQ + halfp * 32 + (lane >> 2)) * 64 + kkp * 32 + ksl * 8;
  u16* lk = &Ks[kkp][(halfp * 32) * 32];
  const u16* gv0 = v + ((size_t)h * SEQ + lane) * 64 + w * 16;
  // K read: row n*16+(lane&15), want granule lane>>4 -> slot (lane>>4)^(lane&3)
  const int krd = ((lane >> 4) ^ (lane & 3)) * 8;

  for (int t = 0; t < ntiles; ++t) {
    const int j0 = t << 6;
    __syncthreads();
    gload_lds16(gk0 + (size_t)j0 * 64, lk);
    gload_lds16(gk0 + (size_t)(j0 + 16) * 64, lk + 16 * 32);
    {
      const u16* gvp = gv0 + (size_t)j0 * 64;
      u16x8 v0 = *(const u16x8*)gvp;
      u16x8 v1 = *(const u16x8*)(gvp + 8);
      const int d0 = w * 16;
#pragma unroll
      for (int i = 0; i < 8; ++i) Vt[d0 + i][lane] = v0[i];
#pragma unroll
      for (int i = 0; i < 8; ++i) Vt[d0 + 8 + i][lane] = v1[i];
    }
    asm volatile("s_waitcnt vmcnt(0)" ::: "memory");
    __syncthreads();

    if (wmaxrow >= j0) {
      f32x4 s[2][4] = {};
      __builtin_amdgcn_s_setprio(1);
#pragma unroll
      for (int kk = 0; kk < 2; ++kk) {
        bf16x8 kf[4];
#pragma unroll
        for (int n = 0; n < 4; ++n)
          kf[n] = *(const bf16x8*)&Ks[kk][(n * 16 + (lane & 15)) * 32 + krd];
#pragma unroll
        for (int m = 0; m < 2; ++m)
#pragma unroll
          for (int n = 0; n < 4; ++n)
            s[m][n] = __builtin_amdgcn_mfma_f32_16x16x32_bf16(qf[m][kk], kf[n], s[m][n], 0, 0, 0);
      }
      __builtin_amdgcn_s_setprio(0);
      const int rq = q0 + w * 32 + ((lane >> 4) << 2);
      const int ck = j0 + (lane & 15);
#pragma unroll
      for (int m = 0; m < 2; ++m) {
#pragma unroll
        for (int j = 0; j < 4; ++j) {
          const int qi = rq + m * 16 + j;
          float mx = -1e30f;
#pragma unroll
          for (int n = 0; n < 4; ++n) {
            const int kj = ck + n * 16;
            float val = s[m][n][j] * 0.125f - slope * (float)(kj - qi);
            val = (kj <= qi) ? val : -1e30f;
            s[m][n][j] = val;
            mx = fmaxf(mx, val);
          }
#pragma unroll
          for (int o = 1; o < 16; o <<= 1) mx = fmaxf(mx, __shfl_xor(mx, o));
          const float mnew = fmaxf(mrun[m][j], mx);
          const float alpha = __expf(mrun[m][j] - mnew);
          mrun[m][j] = mnew;
          float rs = 0.0f;
          const int prow = m * 16 + ((lane >> 4) << 2) + j;
#pragma unroll
          for (int n = 0; n < 4; ++n) {
            const float p = __expf(s[m][n][j] - mnew);
            rs += p;
            Pl[w][prow][n * 16 + (lane & 15)] = f2b(p);
          }
#pragma unroll
          for (int o = 1; o < 16; o <<= 1) rs += __shfl_xor(rs, o);
          lrun[m][j] = lrun[m][j] * alpha + rs;
#pragma unroll
          for (int n = 0; n < 4; ++n) o_acc[m][n][j] *= alpha;
        }
      }
      __builtin_amdgcn_s_setprio(1);
#pragma unroll
      for (int kk = 0; kk < 2; ++kk) {
        bf16x8 pf[2], vf[4];
#pragma unroll
        for (int m = 0; m < 2; ++m)
          pf[m] = *(const bf16x8*)&Pl[w][m * 16 + (lane & 15)][kk * 32 + (lane >> 4) * 8];
#pragma unroll
        for (int n = 0; n < 4; ++n)
          vf[n] = *(const bf16x8*)&Vt[n * 16 + (lane & 15)][kk * 32 + (lane >> 4) * 8];
#pragma unroll
        for (int m = 0; m < 2; ++m)
#pragma unroll
          for (int n = 0; n < 4; ++n)
            o_acc[m][n] = __builtin_amdgcn_mfma_f32_16x16x32_bf16(pf[m], vf[n], o_acc[m][n], 0, 0, 0);
      }
      __builtin_amdgcn_s_setprio(0);
    }
  }

#pragma unroll
  for (int m = 0; m < 2; ++m) {
    const int sbase = q0 + w * 32 + m * 16 + ((lane >> 4) << 2);
#pragma unroll
    for (int n = 0; n < 4; ++n) {
      const int d = h * 64 + n * 16 + (lane & 15);
#pragma unroll
      for (int j = 0; j < 4; ++j)
        out[(size_t)(sbase + j) * 1024 + d] = f2b(o_acc[m][n][j] / lrun[m][j]);
    }
  }
}

// ---------------------------------------------------------------------------
extern "C" void kernel_launch(void* const* d_in, const int* in_sizes, int n_in,
                              void* d_out, int out_size, void* d_ws, size_t ws_size,
                              hipStream_t stream)
{
  (void)in_sizes; (void)n_in; (void)out_size;
  const int* ids = (const int*)d_in[0];
  const float* emb = (const float*)d_in[1];
  const float* slopes = (const float*)d_in[2];
  const float* Wq = (const float*)d_in[3];
  const float* Wk = (const float*)d_in[4];
  const float* Wv = (const float*)d_in[5];
  const float* Wo = (const float*)d_in[6];
  const float* W1 = (const float*)d_in[7];
  const float* b1 = (const float*)d_in[8];
  const float* W2 = (const float*)d_in[9];
  const float* b2 = (const float*)d_in[10];
  const float* g1 = (const float*)d_in[11];
  const float* be1 = (const float*)d_in[12];
  const float* g2 = (const float*)d_in[13];
  const float* be2 = (const float*)d_in[14];
  const float* gf = (const float*)d_in[15];
  const float* bfin = (const float*)d_in[16];

  char* ob = (char*)d_out;
  float* x    = (float*)ob;                          // 8 MB fp32 residual
  u16* qb     = (u16*)(ob + (size_t)( 8u << 20));    // 4 MB
  u16* kb     = (u16*)(ob + (size_t)(12u << 20));    // 4 MB
  u16* vb     = (u16*)(ob + (size_t)(16u << 20));    // 4 MB
  u16* attn   = (u16*)(ob + (size_t)(20u << 20));    // 4 MB
  u16* ff     = (u16*)(ob + (size_t)(24u << 20));    // 16 MB
  u16* Wqkv_b = (u16*)(ob + (size_t)( 40u << 20));   // 24 MB  [4][3072][1024]
  u16* Wo_b   = (u16*)(ob + (size_t)( 64u << 20));   // 8 MB
  u16* W1_b   = (u16*)(ob + (size_t)( 72u << 20));   // 32 MB
  u16* W2_b   = (u16*)(ob + (size_t)(104u << 20));   // 32 MB
  float* P    = (float*)(ob + (size_t)(136u << 20)); // 32 MB: 4 split-K partials
  u16* h      = (u16*)d_ws;                          // 4 MB
  const size_t emb_b_need = (size_t)(4u << 20) + (size_t)32000 * 1024 * 2;
  const bool emb_fits = ws_size >= emb_b_need;
  u16* emb_b = (u16*)((char*)d_ws + (4u << 20));
  float* logits = (float*)d_out;

  {
    CvtArgs a;
    const u32 wsz = 4 * 1024 * 1024 / 8;
    const u32 fsz = 16 * 1024 * 1024 / 8;
    const u32 esz = 32000 * 1024 / 8;
    a.src[0] = Wq; a.dst[0] = Wqkv_b;
    a.src[1] = Wk; a.dst[1] = Wqkv_b + 1024 * 1024;
    a.src[2] = Wv; a.dst[2] = Wqkv_b + 2 * 1024 * 1024;
    a.src[3] = Wo; a.dst[3] = Wo_b;
    a.src[4] = W1; a.dst[4] = W1_b;
    a.src[5] = W2; a.dst[5] = W2_b;
    a.src[6] = emb; a.dst[6] = emb_b;
    a.beg[0] = 0;
    a.beg[1] = wsz;      a.beg[2] = 2 * wsz;  a.beg[3] = 3 * wsz;
    a.beg[4] = 4 * wsz;  a.beg[5] = 4 * wsz + fsz;  a.beg[6] = 4 * wsz + 2 * fsz;
    a.beg[7] = a.beg[6] + esz;
    a.total = emb_fits ? a.beg[7] : a.beg[6];
    cvt_all<<<2048, 256, 0, stream>>>(a);
  }

  gather_kernel<<<2048, 256, 0, stream>>>(ids, emb, x);
  ln_kernel<<<2048, 256, 0, stream>>>(x, g1, be1, h);

  for (int l = 0; l < 4; ++l) {
    const size_t wqkv = (size_t)l * 3072 * 1024;
    const size_t wo = (size_t)l * 1024 * 1024;
    const size_t wf = (size_t)l * 4096 * 1024;
    // QKV (concat, N=3072): 16 M x 24 N = 384 blocks
    gemm128p<1><<<dim3(384, 1, 1), 256, 0, stream>>>(h, Wqkv_b + wqkv,
        qb, kb, vb, nullptr, 3072, 1024);
    attn_kernel<<<dim3(256, 1, 1), 256, 0, stream>>>(qb, kb, vb, slopes, attn);
    // O-proj: N=1024, split-K z=4 -> fp32 partials P[0..3]
    gemm128p<0><<<dim3(128, 1, 4), 256, 0, stream>>>(attn, Wo_b + wo,
        P, nullptr, nullptr, nullptr, 1024, 1024);
    ln_res4<<<2048, 256, 0, stream>>>(x, P, nullptr,
        g2 + l * 1024, be2 + l * 1024, h);
    // FFN1: N=4096 -> 512 blocks, gelu+bias epilogue
    gemm128p<2><<<dim3(512, 1, 1), 256, 0, stream>>>(h, W1_b + wf,
        ff, nullptr, nullptr, b1 + l * 4096, 4096, 1024);
    // FFN2: N=1024, K=4096, split-K z=4 -> partials (kchunk=1024, nk=16)
    gemm128p<0><<<dim3(128, 1, 4), 256, 0, stream>>>(ff, W2_b + wf,
        P, nullptr, nullptr, nullptr, 1024, 4096);
    if (l < 3) {
      ln_res4<<<2048, 256, 0, stream>>>(x, P, b2 + l * 1024,
          g1 + (l + 1) * 1024, be1 + (l + 1) * 1024, h);
    } else {
      ln_res4<<<2048, 256, 0, stream>>>(x, P, b2 + l * 1024, gf, bfin, h);
    }
  }

  if (emb_fits) {
    gemm256<<<dim3(1000, 1, 1), 512, 0, stream>>>(h, emb_b, logits, 32000, 1024);
  } else {
    gemm_f32b<<<dim3(4000, 1, 1), 256, 0, stream>>>(h, emb, logits, 32000, 1024);
  }
}

// Round 11
// 1231.772 us; speedup vs baseline: 1.1247x; 1.0023x over previous
//
#include <hip/hip_runtime.h>
#include <hip/hip_bf16.h>

typedef unsigned int u32;
typedef unsigned short u16;
typedef __attribute__((ext_vector_type(8))) __bf16 bf16x8;
typedef __attribute__((ext_vector_type(8))) unsigned short u16x8;
typedef __attribute__((ext_vector_type(4))) float f32x4;

#define SEQ 2048

__device__ __forceinline__ float b2f(u16 u) {
  union { u32 i; float f; } x; x.i = ((u32)u) << 16; return x.f;
}
__device__ __forceinline__ u16 f2b(float f) {
  u32 u = __float_as_uint(f);
  u = (u + 0x7fffu + ((u >> 16) & 1u)) >> 16;
  return (u16)u;
}
__device__ __forceinline__ void gload_lds16(const void* g, void* l) {
  __builtin_amdgcn_global_load_lds((const __attribute__((address_space(1))) u32*)g,
                                   (__attribute__((address_space(3))) u32*)l, 16, 0, 0);
}

// ---------------------------------------------------------------------------
// Fused fp32 -> bf16 bulk convert. Segments 0-2 (Wq/Wk/Wv) are remapped into
// a concatenated [L][3072][1024] layout.
// ---------------------------------------------------------------------------
struct CvtArgs {
  const float* src[7];
  u16* dst[7];
  u32 beg[8];
  u32 total;
};

__global__ __launch_bounds__(256) void cvt_all(CvtArgs a)
{
  for (u32 i = blockIdx.x * 256 + threadIdx.x; i < a.total; i += gridDim.x * 256) {
    int s = 0;
#pragma unroll
    for (int k = 1; k < 7; ++k) s += (i >= a.beg[k]);
    const u32 li = i - a.beg[s];
    const float* in = a.src[s];
    const float4 f0 = ((const float4*)in)[(size_t)li * 2];
    const float4 f1 = ((const float4*)in)[(size_t)li * 2 + 1];
    union { bf16x8 b; u16x8 u; } r;
    r.b[0] = (__bf16)f0.x; r.b[1] = (__bf16)f0.y;
    r.b[2] = (__bf16)f0.z; r.b[3] = (__bf16)f0.w;
    r.b[4] = (__bf16)f1.x; r.b[5] = (__bf16)f1.y;
    r.b[6] = (__bf16)f1.z; r.b[7] = (__bf16)f1.w;
    u16* d;
    if (s < 3) {
      const u32 layer = li >> 17;
      const u32 rem = li & 131071u;
      d = a.dst[s] + ((size_t)layer * 393216u + rem) * 8;
    } else {
      d = a.dst[s] + (size_t)li * 8;
    }
    *(u16x8*)d = r.u;
  }
}

// ---------------------------------------------------------------------------
// 256x256 pipelined GEMM (logits) — R8-proven. raw s_barrier + counted vmcnt.
// ---------------------------------------------------------------------------
__global__ __launch_bounds__(512, 2) void gemm256(
    const u16* __restrict__ A, const u16* __restrict__ Bt,
    float* __restrict__ C, int N, int K)
{
  __shared__ u16 As[2][256 * 64];
  __shared__ u16 Bs[2][256 * 64];
  const int tid = threadIdx.x;
  const int lane = tid & 63;
  const int wid = tid >> 6;
  const int wr = wid >> 2;
  const int wc = wid & 3;

  const int T = (int)gridDim.x;
  const int bid = (int)blockIdx.x;
  const int q8 = T >> 3, r8 = T & 7;
  const int xcd = bid & 7, base = bid >> 3;
  const int swz = (xcd < r8 ? xcd * (q8 + 1) : r8 * (q8 + 1) + (xcd - r8) * q8) + base;
  const int m0 = (swz & 7) * 256;
  const int n0 = (swz >> 3) * 256;

  f32x4 acc[8][4] = {};

  const int srow = tid >> 3;
  const int sgr = (tid & 7) ^ (srow & 7);
  const u16* gA = A + (size_t)(m0 + srow) * K + sgr * 8;
  const u16* gB = Bt + (size_t)(n0 + srow) * K + sgr * 8;
  const int dwave = wid * 512;

  const int co0 = (((lane >> 4)) ^ (lane & 7)) * 8;
  const int co1 = (((lane >> 4) + 4) ^ (lane & 7)) * 8;
  const int raA = (wr * 128 + (lane & 15)) * 64;
  const int raB = (wc * 64 + (lane & 15)) * 64;

  const int nk = K >> 6;

#pragma unroll
  for (int c = 0; c < 4; ++c) {
    gload_lds16(gA + (size_t)(c * 64) * K, &As[0][c * 4096 + dwave]);
    gload_lds16(gB + (size_t)(c * 64) * K, &Bs[0][c * 4096 + dwave]);
  }
#pragma unroll
  for (int c = 0; c < 4; ++c) {
    gload_lds16(gA + (size_t)(c * 64) * K + 64, &As[1][c * 4096 + dwave]);
    gload_lds16(gB + (size_t)(c * 64) * K + 64, &Bs[1][c * 4096 + dwave]);
  }
  asm volatile("s_waitcnt vmcnt(8)" ::: "memory");
  __builtin_amdgcn_s_barrier();
  __builtin_amdgcn_sched_barrier(0);

#pragma unroll 2
  for (int t = 0; t < nk; ++t) {
    const int cb = t & 1;
    const u16* Acur = &As[cb][0];
    const u16* Bcur = &Bs[cb][0];

    bf16x8 bf[4][2];
#pragma unroll
    for (int n = 0; n < 4; ++n) {
      const int ro = raB + n * 16 * 64;
      bf[n][0] = *(const bf16x8*)&Bcur[ro + co0];
      bf[n][1] = *(const bf16x8*)&Bcur[ro + co1];
    }
#pragma unroll
    for (int p = 0; p < 4; ++p) {
      bf16x8 af[2][2];
#pragma unroll
      for (int mm = 0; mm < 2; ++mm) {
        const int ro = raA + (p * 32 + mm * 16) * 64;
        af[mm][0] = *(const bf16x8*)&Acur[ro + co0];
        af[mm][1] = *(const bf16x8*)&Acur[ro + co1];
      }
      __builtin_amdgcn_s_setprio(1);
#pragma unroll
      for (int mm = 0; mm < 2; ++mm)
#pragma unroll
        for (int n = 0; n < 4; ++n) {
          acc[p * 2 + mm][n] = __builtin_amdgcn_mfma_f32_16x16x32_bf16(af[mm][0], bf[n][0], acc[p * 2 + mm][n], 0, 0, 0);
          acc[p * 2 + mm][n] = __builtin_amdgcn_mfma_f32_16x16x32_bf16(af[mm][1], bf[n][1], acc[p * 2 + mm][n], 0, 0, 0);
        }
      __builtin_amdgcn_s_setprio(0);
    }

    __builtin_amdgcn_s_barrier();
    if (t + 2 < nk) {
      const size_t kto = (size_t)(t + 2) * 64;
      u16* Anx = &As[cb][0];
      u16* Bnx = &Bs[cb][0];
#pragma unroll
      for (int c = 0; c < 4; ++c) {
        gload_lds16(gA + (size_t)(c * 64) * K + kto, Anx + c * 4096 + dwave);
        gload_lds16(gB + (size_t)(c * 64) * K + kto, Bnx + c * 4096 + dwave);
      }
      asm volatile("s_waitcnt vmcnt(8)" ::: "memory");
    } else if (t + 1 < nk) {
      asm volatile("s_waitcnt vmcnt(0)" ::: "memory");
    }
    __builtin_amdgcn_s_barrier();
    __builtin_amdgcn_sched_barrier(0);
  }

  const int crow = m0 + wr * 128 + ((lane >> 4) << 2);
  const int ccol = n0 + wc * 64 + (lane & 15);
#pragma unroll
  for (int m = 0; m < 8; ++m)
#pragma unroll
    for (int n = 0; n < 4; ++n)
#pragma unroll
      for (int j = 0; j < 4; ++j)
        C[(size_t)(crow + m * 16 + j) * N + ccol + n * 16] = acc[m][n][j];
}

// ---------------------------------------------------------------------------
// 128x128 pipelined layer GEMM (R9 structure, generalized split-K partials).
// EPI 0: fp32 partial store to P + blockIdx.z * (2048*1024)
// EPI 1: QKV head-major bf16 from concat [3072][1024] weights
// EPI 2: bf16 gelu(acc + bias[col])
// ---------------------------------------------------------------------------
template <int EPI>
__global__ __launch_bounds__(256, 2) void gemm128p(
    const u16* __restrict__ A, const u16* __restrict__ Bt,
    void* __restrict__ C0, void* __restrict__ C1, void* __restrict__ C2,
    const float* __restrict__ bias, int N, int K)
{
  __shared__ u16 As[2][128 * 64];
  __shared__ u16 Bs[2][128 * 64];
  const int tid = threadIdx.x;
  const int lane = tid & 63;
  const int wid = tid >> 6;
  const int wr = wid >> 1;
  const int wc = wid & 1;

  const int T = (int)gridDim.x;
  const int bid = (int)blockIdx.x;
  const int q8 = T >> 3, r8 = T & 7;
  const int xcd = bid & 7, base = bid >> 3;
  const int swz = (xcd < r8 ? xcd * (q8 + 1) : r8 * (q8 + 1) + (xcd - r8) * q8) + base;
  const int m0 = (swz & 15) * 128;
  const int n0 = (swz >> 4) * 128;

  const int kchunk = K / (int)gridDim.z;
  const int kbeg = (int)blockIdx.z * kchunk;
  const int nk = kchunk >> 6;

  f32x4 acc[4][4] = {};

  const int srow = tid >> 3;
  const int sgr = (tid & 7) ^ (srow & 7);
  const u16* gA = A + (size_t)(m0 + srow) * K + kbeg + sgr * 8;
  const u16* gB = Bt + (size_t)(n0 + srow) * K + kbeg + sgr * 8;
  const int dwave = wid * 512;

  const int co0 = (((lane >> 4)) ^ (lane & 7)) * 8;
  const int co1 = (((lane >> 4) + 4) ^ (lane & 7)) * 8;
  const int raA = (wr * 64 + (lane & 15)) * 64;
  const int raB = (wc * 64 + (lane & 15)) * 64;

#pragma unroll
  for (int c = 0; c < 4; ++c) {
    gload_lds16(gA + (size_t)(c * 32) * K, &As[0][c * 2048 + dwave]);
    gload_lds16(gB + (size_t)(c * 32) * K, &Bs[0][c * 2048 + dwave]);
  }
#pragma unroll
  for (int c = 0; c < 4; ++c) {
    gload_lds16(gA + (size_t)(c * 32) * K + 64, &As[1][c * 2048 + dwave]);
    gload_lds16(gB + (size_t)(c * 32) * K + 64, &Bs[1][c * 2048 + dwave]);
  }
  asm volatile("s_waitcnt vmcnt(8)" ::: "memory");
  __builtin_amdgcn_s_barrier();
  __builtin_amdgcn_sched_barrier(0);

#pragma unroll 2
  for (int t = 0; t < nk; ++t) {
    const int cb = t & 1;
    const u16* Acur = &As[cb][0];
    const u16* Bcur = &Bs[cb][0];

    bf16x8 bf[4][2];
#pragma unroll
    for (int n = 0; n < 4; ++n) {
      const int ro = raB + n * 16 * 64;
      bf[n][0] = *(const bf16x8*)&Bcur[ro + co0];
      bf[n][1] = *(const bf16x8*)&Bcur[ro + co1];
    }
#pragma unroll
    for (int p = 0; p < 4; ++p) {
      bf16x8 af[2];
      {
        const int ro = raA + p * 16 * 64;
        af[0] = *(const bf16x8*)&Acur[ro + co0];
        af[1] = *(const bf16x8*)&Acur[ro + co1];
      }
      __builtin_amdgcn_s_setprio(1);
#pragma unroll
      for (int n = 0; n < 4; ++n) {
        acc[p][n] = __builtin_amdgcn_mfma_f32_16x16x32_bf16(af[0], bf[n][0], acc[p][n], 0, 0, 0);
        acc[p][n] = __builtin_amdgcn_mfma_f32_16x16x32_bf16(af[1], bf[n][1], acc[p][n], 0, 0, 0);
      }
      __builtin_amdgcn_s_setprio(0);
    }

    __builtin_amdgcn_s_barrier();
    if (t + 2 < nk) {
      const size_t kto = (size_t)(t + 2) * 64;
      u16* Anx = &As[cb][0];
      u16* Bnx = &Bs[cb][0];
#pragma unroll
      for (int c = 0; c < 4; ++c) {
        gload_lds16(gA + (size_t)(c * 32) * K + kto, Anx + c * 2048 + dwave);
        gload_lds16(gB + (size_t)(c * 32) * K + kto, Bnx + c * 2048 + dwave);
      }
      asm volatile("s_waitcnt vmcnt(8)" ::: "memory");
    } else if (t + 1 < nk) {
      asm volatile("s_waitcnt vmcnt(0)" ::: "memory");
    }
    __builtin_amdgcn_s_barrier();
    __builtin_amdgcn_sched_barrier(0);
  }

  const int z = (int)blockIdx.z;
#pragma unroll
  for (int m = 0; m < 4; ++m) {
    const int rowb = m0 + wr * 64 + m * 16 + ((lane >> 4) << 2);
#pragma unroll
    for (int n = 0; n < 4; ++n) {
      const int col = n0 + wc * 64 + n * 16 + (lane & 15);
#pragma unroll
      for (int j = 0; j < 4; ++j) {
        const int r = rowb + j;
        float v = acc[m][n][j];
        if (EPI == 0) {
          float* outp = (float*)C0 + (size_t)z * (2048u * 1024u);
          outp[(size_t)r * N + col] = v;
        } else if (EPI == 1) {
          const int which = col >> 10;
          const int ci = col & 1023;
          u16* outp = (u16*)((which == 0) ? C0 : (which == 1) ? C1 : C2);
          outp[((size_t)(ci >> 6) * SEQ + r) * 64 + (ci & 63)] = f2b(v);
        } else {
          float xx = v + bias[col];
          float ge = 0.5f * xx * (1.0f + erff(xx * 0.70710678118654752f));
          ((u16*)C0)[(size_t)r * N + col] = f2b(ge);
        }
      }
    }
  }
}

// ---------------------------------------------------------------------------
// Fallback logits GEMM (fp32 B, BK=32) if emb_bf16 doesn't fit ws.
// ---------------------------------------------------------------------------
__global__ __launch_bounds__(256) void gemm_f32b(
    const u16* __restrict__ A, const float* __restrict__ Bt,
    float* __restrict__ C0, int N, int K)
{
  __shared__ u16 As[128 * 32];
  __shared__ u16 Bs[128 * 32];
  const int tid = threadIdx.x;
  const int lane = tid & 63;
  const int w = tid >> 6;
  const int wr = w >> 1;
  const int wc = w & 1;

  const int T = (int)gridDim.x;
  const int bid = (int)blockIdx.x;
  const int q8 = T >> 3, r8 = T & 7;
  const int xcd = bid & 7, base = bid >> 3;
  int swz = (xcd < r8 ? xcd * (q8 + 1) : r8 * (q8 + 1) + (xcd - r8) * q8) + base;
  const int m0 = (swz & 15) * 128;
  const int n0 = (swz >> 4) * 128;

  f32x4 acc[4][4] = {};
  const u16* ga0 = A + (size_t)(m0 + w * 32 + (lane >> 2)) * K + (lane & 3) * 8;
  u16* la = &As[(w * 32) * 32];
  const float* gb32 = Bt + (size_t)(n0 + (tid >> 1)) * K + (tid & 1) * 16;
  u16* lbw = &Bs[(tid >> 1) * 32 + (tid & 1) * 16];

  for (int kt = 0; kt < K; kt += 32) {
    __syncthreads();
    gload_lds16(ga0 + kt, la);
    gload_lds16(ga0 + kt + 16 * K, la + 16 * 32);
    {
      const float4 f0 = *(const float4*)(gb32 + kt);
      const float4 f1 = *(const float4*)(gb32 + kt + 4);
      const float4 f2 = *(const float4*)(gb32 + kt + 8);
      const float4 f3 = *(const float4*)(gb32 + kt + 12);
      union { bf16x8 b; u16x8 u; } lo, hi;
      lo.b[0] = (__bf16)f0.x; lo.b[1] = (__bf16)f0.y;
      lo.b[2] = (__bf16)f0.z; lo.b[3] = (__bf16)f0.w;
      lo.b[4] = (__bf16)f1.x; lo.b[5] = (__bf16)f1.y;
      lo.b[6] = (__bf16)f1.z; lo.b[7] = (__bf16)f1.w;
      hi.b[0] = (__bf16)f2.x; hi.b[1] = (__bf16)f2.y;
      hi.b[2] = (__bf16)f2.z; hi.b[3] = (__bf16)f2.w;
      hi.b[4] = (__bf16)f3.x; hi.b[5] = (__bf16)f3.y;
      hi.b[6] = (__bf16)f3.z; hi.b[7] = (__bf16)f3.w;
      *(u16x8*)lbw = lo.u;
      *(u16x8*)(lbw + 8) = hi.u;
    }
    asm volatile("s_waitcnt vmcnt(0)" ::: "memory");
    __syncthreads();
    bf16x8 af[4], bfr[4];
#pragma unroll
    for (int m = 0; m < 4; ++m)
      af[m] = *(const bf16x8*)&As[(wr * 64 + m * 16 + (lane & 15)) * 32 + (lane >> 4) * 8];
#pragma unroll
    for (int n = 0; n < 4; ++n)
      bfr[n] = *(const bf16x8*)&Bs[(wc * 64 + n * 16 + (lane & 15)) * 32 + (lane >> 4) * 8];
#pragma unroll
    for (int m = 0; m < 4; ++m)
#pragma unroll
      for (int n = 0; n < 4; ++n)
        acc[m][n] = __builtin_amdgcn_mfma_f32_16x16x32_bf16(af[m], bfr[n], acc[m][n], 0, 0, 0);
  }

#pragma unroll
  for (int m = 0; m < 4; ++m) {
    const int rowb = m0 + wr * 64 + m * 16 + ((lane >> 4) << 2);
#pragma unroll
    for (int n = 0; n < 4; ++n) {
      const int col = n0 + wc * 64 + n * 16 + (lane & 15);
#pragma unroll
      for (int j = 0; j < 4; ++j)
        C0[(size_t)(rowb + j) * N + col] = acc[m][n][j];
    }
  }
}

// ---------------------------------------------------------------------------
// LayerNorm (plain): fp32 x[row][1024] -> bf16 h
// ---------------------------------------------------------------------------
__global__ __launch_bounds__(256) void ln_kernel(const float* __restrict__ x,
    const float* __restrict__ g, const float* __restrict__ b, u16* __restrict__ out)
{
  const int row = blockIdx.x;
  const int tid = threadIdx.x;
  const float4 v = ((const float4*)(x + (size_t)row * 1024))[tid];
  float s = v.x + v.y + v.z + v.w;
  float sq = v.x * v.x + v.y * v.y + v.z * v.z + v.w * v.w;
#pragma unroll
  for (int o = 1; o < 64; o <<= 1) { s += __shfl_xor(s, o); sq += __shfl_xor(sq, o); }
  __shared__ float ss[4], ssq[4];
  if ((tid & 63) == 0) { ss[tid >> 6] = s; ssq[tid >> 6] = sq; }
  __syncthreads();
  s = ss[0] + ss[1] + ss[2] + ss[3];
  sq = ssq[0] + ssq[1] + ssq[2] + ssq[3];
  const float mean = s * (1.0f / 1024.0f);
  const float var = sq * (1.0f / 1024.0f) - mean * mean;
  const float rstd = rsqrtf(var + 1e-5f);
  const int c = tid * 4;
  u16* o4 = out + (size_t)row * 1024 + c;
  const float4 gg = ((const float4*)g)[tid];
  const float4 bb = ((const float4*)b)[tid];
  o4[0] = f2b((v.x - mean) * rstd * gg.x + bb.x);
  o4[1] = f2b((v.y - mean) * rstd * gg.y + bb.y);
  o4[2] = f2b((v.z - mean) * rstd * gg.z + bb.z);
  o4[3] = f2b((v.w - mean) * rstd * gg.w + bb.w);
}

// ---------------------------------------------------------------------------
// Fused residual + LayerNorm, 4 split-K partials.
// ---------------------------------------------------------------------------
__global__ __launch_bounds__(256) void ln_res4(float* __restrict__ x,
    const float* __restrict__ P, const float* __restrict__ bias,
    const float* __restrict__ g, const float* __restrict__ b,
    u16* __restrict__ out)
{
  const int row = blockIdx.x;
  const int tid = threadIdx.x;
  const size_t off = (size_t)row * 1024;
  float4 v = ((const float4*)(x + off))[tid];
#pragma unroll
  for (int j = 0; j < 4; ++j) {
    const float4 a = ((const float4*)(P + (size_t)j * 2048 * 1024 + off))[tid];
    v.x += a.x; v.y += a.y; v.z += a.z; v.w += a.w;
  }
  if (bias != nullptr) {
    const float4 bi = ((const float4*)bias)[tid];
    v.x += bi.x; v.y += bi.y; v.z += bi.z; v.w += bi.w;
  }
  ((float4*)(x + off))[tid] = v;
  float s = v.x + v.y + v.z + v.w;
  float sq = v.x * v.x + v.y * v.y + v.z * v.z + v.w * v.w;
#pragma unroll
  for (int o = 1; o < 64; o <<= 1) { s += __shfl_xor(s, o); sq += __shfl_xor(sq, o); }
  __shared__ float ss[4], ssq[4];
  if ((tid & 63) == 0) { ss[tid >> 6] = s; ssq[tid >> 6] = sq; }
  __syncthreads();
  s = ss[0] + ss[1] + ss[2] + ss[3];
  sq = ssq[0] + ssq[1] + ssq[2] + ssq[3];
  const float mean = s * (1.0f / 1024.0f);
  const float var = sq * (1.0f / 1024.0f) - mean * mean;
  const float rstd = rsqrtf(var + 1e-5f);
  const int c = tid * 4;
  u16* o4 = out + off + c;
  const float4 gg = ((const float4*)g)[tid];
  const float4 bb = ((const float4*)b)[tid];
  o4[0] = f2b((v.x - mean) * rstd * gg.x + bb.x);
  o4[1] = f2b((v.y - mean) * rstd * gg.y + bb.y);
  o4[2] = f2b((v.z - mean) * rstd * gg.z + bb.z);
  o4[3] = f2b((v.w - mean) * rstd * gg.w + bb.w);
}

// ---------------------------------------------------------------------------
// Embedding gather: x[s][d] = emb_fp32[ids[s]][d]
// ---------------------------------------------------------------------------
__global__ __launch_bounds__(256) void gather_kernel(const int* __restrict__ ids,
    const float* __restrict__ emb, float* __restrict__ x)
{
  const int srow = blockIdx.x;
  const int tid = threadIdx.x;
  const int id = ids[srow];
  ((float4*)(x + (size_t)srow * 1024))[tid] =
      ((const float4*)(emb + (size_t)id * 1024))[tid];
}

// ---------------------------------------------------------------------------
// Flash attention w/ ALiBi + causal — rebalanced: 512 blocks x 128 threads,
// QBLK=64 (2 waves x 32 q-rows), longest-first dispatch (qi = 31 - bid>>4),
// same-head blocks pinned to one XCD (h = bid&15 -> xcd = h%8).
// K-LDS granule^row&3 XOR swizzle (pre-swizzled source, linear gload dest).
// ---------------------------------------------------------------------------
__global__ __launch_bounds__(128) void attn_kernel(
    const u16* __restrict__ q, const u16* __restrict__ k, const u16* __restrict__ v,
    const float* __restrict__ slopes, u16* __restrict__ out)
{
  const int bid = (int)blockIdx.x;
  const int h = bid & 15;
  const int qi = 31 - (bid >> 4);        // longest blocks first
  const int q0 = qi * 64;
  const int tid = threadIdx.x;
  const int lane = tid & 63;
  const int w = tid >> 6;                // 0..1
  const float slope = slopes[h];

  __shared__ u16 Ks[2][64 * 32];         // [dim-half kk][key row][32 dims]
  __shared__ u16 Vt[64][72];             // V transposed [dim][key]
  __shared__ u16 Pl[2][32][72];          // per-wave P

  const u16* qb = q + ((size_t)h * SEQ + q0 + w * 32) * 64;
  bf16x8 qf[2][2];
#pragma unroll
  for (int m = 0; m < 2; ++m)
#pragma unroll
    for (int kk = 0; kk < 2; ++kk)
      qf[m][kk] = *(const bf16x8*)(qb + (m * 16 + (lane & 15)) * 64 + kk * 32 + (lane >> 4) * 8);

  f32x4 o_acc[2][4] = {};
  float mrun[2][4], lrun[2][4];
#pragma unroll
  for (int m = 0; m < 2; ++m)
#pragma unroll
    for (int j = 0; j < 4; ++j) { mrun[m][j] = -1e30f; lrun[m][j] = 0.0f; }

  const int ntiles = qi + 1;
  const int wmaxrow = q0 + w * 32 + 31;

  // K staging: wave w stages Ks[w] (64 key rows x 32 dims), 4 calls x 16 rows.
  // lane -> row (lane>>2), dest slot lane&3; source granule pre-swizzled.
  const int ksl = (lane & 3) ^ ((lane >> 2) & 3);
  const u16* gk0 = k + ((size_t)h * SEQ + (lane >> 2)) * 64 + w * 32 + ksl * 8;
  u16* lk = &Ks[w][0];
  // V staging: wave w covers dims w*32..w*32+31 for all 64 keys (lane = key).
  const u16* gv0 = v + ((size_t)h * SEQ + lane) * 64 + w * 32;
  // K read slot: row n*16+(lane&15) -> (lane>>4)^(lane&3)
  const int krd = ((lane >> 4) ^ (lane & 3)) * 8;

  for (int t = 0; t < ntiles; ++t) {
    const int j0 = t << 6;
    __syncthreads();
#pragma unroll
    for (int r = 0; r < 4; ++r)
      gload_lds16(gk0 + (size_t)(j0 + r * 16) * 64, lk + r * 16 * 32);
    {
      const u16* gvp = gv0 + (size_t)j0 * 64;
      u16x8 v0 = *(const u16x8*)gvp;
      u16x8 v1 = *(const u16x8*)(gvp + 8);
      u16x8 v2 = *(const u16x8*)(gvp + 16);
      u16x8 v3 = *(const u16x8*)(gvp + 24);
      const int d0 = w * 32;
#pragma unroll
      for (int i = 0; i < 8; ++i) Vt[d0 + i][lane] = v0[i];
#pragma unroll
      for (int i = 0; i < 8; ++i) Vt[d0 + 8 + i][lane] = v1[i];
#pragma unroll
      for (int i = 0; i < 8; ++i) Vt[d0 + 16 + i][lane] = v2[i];
#pragma unroll
      for (int i = 0; i < 8; ++i) Vt[d0 + 24 + i][lane] = v3[i];
    }
    asm volatile("s_waitcnt vmcnt(0)" ::: "memory");
    __syncthreads();

    if (wmaxrow >= j0) {
      f32x4 s[2][4] = {};
      __builtin_amdgcn_s_setprio(1);
#pragma unroll
      for (int kk = 0; kk < 2; ++kk) {
        bf16x8 kf[4];
#pragma unroll
        for (int n = 0; n < 4; ++n)
          kf[n] = *(const bf16x8*)&Ks[kk][(n * 16 + (lane & 15)) * 32 + krd];
#pragma unroll
        for (int m = 0; m < 2; ++m)
#pragma unroll
          for (int n = 0; n < 4; ++n)
            s[m][n] = __builtin_amdgcn_mfma_f32_16x16x32_bf16(qf[m][kk], kf[n], s[m][n], 0, 0, 0);
      }
      __builtin_amdgcn_s_setprio(0);
      const int rq = q0 + w * 32 + ((lane >> 4) << 2);
      const int ck = j0 + (lane & 15);
#pragma unroll
      for (int m = 0; m < 2; ++m) {
#pragma unroll
        for (int j = 0; j < 4; ++j) {
          const int qi2 = rq + m * 16 + j;
          float mx = -1e30f;
#pragma unroll
          for (int n = 0; n < 4; ++n) {
            const int kj = ck + n * 16;
            float val = s[m][n][j] * 0.125f - slope * (float)(kj - qi2);
            val = (kj <= qi2) ? val : -1e30f;
            s[m][n][j] = val;
            mx = fmaxf(mx, val);
          }
#pragma unroll
          for (int o = 1; o < 16; o <<= 1) mx = fmaxf(mx, __shfl_xor(mx, o));
          const float mnew = fmaxf(mrun[m][j], mx);
          const float alpha = __expf(mrun[m][j] - mnew);
          mrun[m][j] = mnew;
          float rs = 0.0f;
          const int prow = m * 16 + ((lane >> 4) << 2) + j;
#pragma unroll
          for (int n = 0; n < 4; ++n) {
            const float p = __expf(s[m][n][j] - mnew);
            rs += p;
            Pl[w][prow][n * 16 + (lane & 15)] = f2b(p);
          }
#pragma unroll
          for (int o = 1; o < 16; o <<= 1) rs += __shfl_xor(rs, o);
          lrun[m][j] = lrun[m][j] * alpha + rs;
#pragma unroll
          for (int n = 0; n < 4; ++n) o_acc[m][n][j] *= alpha;
        }
      }
      __builtin_amdgcn_s_setprio(1);
#pragma unroll
      for (int kk = 0; kk < 2; ++kk) {
        bf16x8 pf[2], vf[4];
#pragma unroll
        for (int m = 0; m < 2; ++m)
          pf[m] = *(const bf16x8*)&Pl[w][m * 16 + (lane & 15)][kk * 32 + (lane >> 4) * 8];
#pragma unroll
        for (int n = 0; n < 4; ++n)
          vf[n] = *(const bf16x8*)&Vt[n * 16 + (lane & 15)][kk * 32 + (lane >> 4) * 8];
#pragma unroll
        for (int m = 0; m < 2; ++m)
#pragma unroll
          for (int n = 0; n < 4; ++n)
            o_acc[m][n] = __builtin_amdgcn_mfma_f32_16x16x32_bf16(pf[m], vf[n], o_acc[m][n], 0, 0, 0);
      }
      __builtin_amdgcn_s_setprio(0);
    }
  }

#pragma unroll
  for (int m = 0; m < 2; ++m) {
    const int sbase = q0 + w * 32 + m * 16 + ((lane >> 4) << 2);
#pragma unroll
    for (int n = 0; n < 4; ++n) {
      const int d = h * 64 + n * 16 + (lane & 15);
#pragma unroll
      for (int j = 0; j < 4; ++j)
        out[(size_t)(sbase + j) * 1024 + d] = f2b(o_acc[m][n][j] / lrun[m][j]);
    }
  }
}

// ---------------------------------------------------------------------------
extern "C" void kernel_launch(void* const* d_in, const int* in_sizes, int n_in,
                              void* d_out, int out_size, void* d_ws, size_t ws_size,
                              hipStream_t stream)
{
  (void)in_sizes; (void)n_in; (void)out_size;
  const int* ids = (const int*)d_in[0];
  const float* emb = (const float*)d_in[1];
  const float* slopes = (const float*)d_in[2];
  const float* Wq = (const float*)d_in[3];
  const float* Wk = (const float*)d_in[4];
  const float* Wv = (const float*)d_in[5];
  const float* Wo = (const float*)d_in[6];
  const float* W1 = (const float*)d_in[7];
  const float* b1 = (const float*)d_in[8];
  const float* W2 = (const float*)d_in[9];
  const float* b2 = (const float*)d_in[10];
  const float* g1 = (const float*)d_in[11];
  const float* be1 = (const float*)d_in[12];
  const float* g2 = (const float*)d_in[13];
  const float* be2 = (const float*)d_in[14];
  const float* gf = (const float*)d_in[15];
  const float* bfin = (const float*)d_in[16];

  char* ob = (char*)d_out;
  float* x    = (float*)ob;                          // 8 MB fp32 residual
  u16* qb     = (u16*)(ob + (size_t)( 8u << 20));    // 4 MB
  u16* kb     = (u16*)(ob + (size_t)(12u << 20));    // 4 MB
  u16* vb     = (u16*)(ob + (size_t)(16u << 20));    // 4 MB
  u16* attn   = (u16*)(ob + (size_t)(20u << 20));    // 4 MB
  u16* ff     = (u16*)(ob + (size_t)(24u << 20));    // 16 MB
  u16* Wqkv_b = (u16*)(ob + (size_t)( 40u << 20));   // 24 MB  [4][3072][1024]
  u16* Wo_b   = (u16*)(ob + (size_t)( 64u << 20));   // 8 MB
  u16* W1_b   = (u16*)(ob + (size_t)( 72u << 20));   // 32 MB
  u16* W2_b   = (u16*)(ob + (size_t)(104u << 20));   // 32 MB
  float* P    = (float*)(ob + (size_t)(136u << 20)); // 32 MB: 4 split-K partials
  u16* h      = (u16*)d_ws;                          // 4 MB
  const size_t emb_b_need = (size_t)(4u << 20) + (size_t)32000 * 1024 * 2;
  const bool emb_fits = ws_size >= emb_b_need;
  u16* emb_b = (u16*)((char*)d_ws + (4u << 20));
  float* logits = (float*)d_out;

  {
    CvtArgs a;
    const u32 wsz = 4 * 1024 * 1024 / 8;
    const u32 fsz = 16 * 1024 * 1024 / 8;
    const u32 esz = 32000 * 1024 / 8;
    a.src[0] = Wq; a.dst[0] = Wqkv_b;
    a.src[1] = Wk; a.dst[1] = Wqkv_b + 1024 * 1024;
    a.src[2] = Wv; a.dst[2] = Wqkv_b + 2 * 1024 * 1024;
    a.src[3] = Wo; a.dst[3] = Wo_b;
    a.src[4] = W1; a.dst[4] = W1_b;
    a.src[5] = W2; a.dst[5] = W2_b;
    a.src[6] = emb; a.dst[6] = emb_b;
    a.beg[0] = 0;
    a.beg[1] = wsz;      a.beg[2] = 2 * wsz;  a.beg[3] = 3 * wsz;
    a.beg[4] = 4 * wsz;  a.beg[5] = 4 * wsz + fsz;  a.beg[6] = 4 * wsz + 2 * fsz;
    a.beg[7] = a.beg[6] + esz;
    a.total = emb_fits ? a.beg[7] : a.beg[6];
    cvt_all<<<2048, 256, 0, stream>>>(a);
  }

  gather_kernel<<<2048, 256, 0, stream>>>(ids, emb, x);
  ln_kernel<<<2048, 256, 0, stream>>>(x, g1, be1, h);

  for (int l = 0; l < 4; ++l) {
    const size_t wqkv = (size_t)l * 3072 * 1024;
    const size_t wo = (size_t)l * 1024 * 1024;
    const size_t wf = (size_t)l * 4096 * 1024;
    gemm128p<1><<<dim3(384, 1, 1), 256, 0, stream>>>(h, Wqkv_b + wqkv,
        qb, kb, vb, nullptr, 3072, 1024);
    attn_kernel<<<dim3(512, 1, 1), 128, 0, stream>>>(qb, kb, vb, slopes, attn);
    gemm128p<0><<<dim3(128, 1, 4), 256, 0, stream>>>(attn, Wo_b + wo,
        P, nullptr, nullptr, nullptr, 1024, 1024);
    ln_res4<<<2048, 256, 0, stream>>>(x, P, nullptr,
        g2 + l * 1024, be2 + l * 1024, h);
    gemm128p<2><<<dim3(512, 1, 1), 256, 0, stream>>>(h, W1_b + wf,
        ff, nullptr, nullptr, b1 + l * 4096, 4096, 1024);
    gemm128p<0><<<dim3(128, 1, 4), 256, 0, stream>>>(ff, W2_b + wf,
        P, nullptr, nullptr, nullptr, 1024, 4096);
    if (l < 3) {
      ln_res4<<<2048, 256, 0, stream>>>(x, P, b2 + l * 1024,
          g1 + (l + 1) * 1024, be1 + (l + 1) * 1024, h);
    } else {
      ln_res4<<<2048, 256, 0, stream>>>(x, P, b2 + l * 1024, gf, bfin, h);
    }
  }

  if (emb_fits) {
    gemm256<<<dim3(1000, 1, 1), 512, 0, stream>>>(h, emb_b, logits, 32000, 1024);
  } else {
    gemm_f32b<<<dim3(4000, 1, 1), 256, 0, stream>>>(h, emb, logits, 32000, 1024);
  }
}

// Round 12
// 1182.649 us; speedup vs baseline: 1.1714x; 1.0415x over previous
//
#include <hip/hip_runtime.h>
#include <hip/hip_bf16.h>

typedef unsigned int u32;
typedef unsigned short u16;
typedef __attribute__((ext_vector_type(8))) __bf16 bf16x8;
typedef __attribute__((ext_vector_type(8))) unsigned short u16x8;
typedef __attribute__((ext_vector_type(4))) float f32x4;

#define SEQ 2048

__device__ __forceinline__ float b2f(u16 u) {
  union { u32 i; float f; } x; x.i = ((u32)u) << 16; return x.f;
}
__device__ __forceinline__ u16 f2b(float f) {
  u32 u = __float_as_uint(f);
  u = (u + 0x7fffu + ((u >> 16) & 1u)) >> 16;
  return (u16)u;
}
__device__ __forceinline__ void gload_lds16(const void* g, void* l) {
  __builtin_amdgcn_global_load_lds((const __attribute__((address_space(1))) u32*)g,
                                   (__attribute__((address_space(3))) u32*)l, 16, 0, 0);
}

// ---------------------------------------------------------------------------
// Fused fp32 -> bf16 bulk convert. Segments 0-2 (Wq/Wk/Wv) are remapped into
// a concatenated [L][3072][1024] layout.
// ---------------------------------------------------------------------------
struct CvtArgs {
  const float* src[7];
  u16* dst[7];
  u32 beg[8];
  u32 total;
};

__global__ __launch_bounds__(256) void cvt_all(CvtArgs a)
{
  for (u32 i = blockIdx.x * 256 + threadIdx.x; i < a.total; i += gridDim.x * 256) {
    int s = 0;
#pragma unroll
    for (int k = 1; k < 7; ++k) s += (i >= a.beg[k]);
    const u32 li = i - a.beg[s];
    const float* in = a.src[s];
    const float4 f0 = ((const float4*)in)[(size_t)li * 2];
    const float4 f1 = ((const float4*)in)[(size_t)li * 2 + 1];
    union { bf16x8 b; u16x8 u; } r;
    r.b[0] = (__bf16)f0.x; r.b[1] = (__bf16)f0.y;
    r.b[2] = (__bf16)f0.z; r.b[3] = (__bf16)f0.w;
    r.b[4] = (__bf16)f1.x; r.b[5] = (__bf16)f1.y;
    r.b[6] = (__bf16)f1.z; r.b[7] = (__bf16)f1.w;
    u16* d;
    if (s < 3) {
      const u32 layer = li >> 17;
      const u32 rem = li & 131071u;
      d = a.dst[s] + ((size_t)layer * 393216u + rem) * 8;
    } else {
      d = a.dst[s] + (size_t)li * 8;
    }
    *(u16x8*)d = r.u;
  }
}

// ---------------------------------------------------------------------------
// 256x256 pipelined GEMM (logits). R12: drain-after-MFMA restructure.
// Per K-step: {read B + A(p01) | MFMA p01 | read A(p23) | lgkmcnt(0) |
//   barrier(1: buf[cb] read done) | stage t+2 -> buf[cb] | MFMA p23 |
//   vmcnt(8) | barrier(2: publish buf[cb^1]) | sched_barrier}.
// Cover for tile t+1's loads ~= 2 K-steps of compute.
// ---------------------------------------------------------------------------
__global__ __launch_bounds__(512, 2) void gemm256(
    const u16* __restrict__ A, const u16* __restrict__ Bt,
    float* __restrict__ C, int N, int K)
{
  __shared__ u16 As[2][256 * 64];
  __shared__ u16 Bs[2][256 * 64];
  const int tid = threadIdx.x;
  const int lane = tid & 63;
  const int wid = tid >> 6;
  const int wr = wid >> 2;
  const int wc = wid & 3;

  const int T = (int)gridDim.x;
  const int bid = (int)blockIdx.x;
  const int q8 = T >> 3, r8 = T & 7;
  const int xcd = bid & 7, base = bid >> 3;
  const int swz = (xcd < r8 ? xcd * (q8 + 1) : r8 * (q8 + 1) + (xcd - r8) * q8) + base;
  const int m0 = (swz & 7) * 256;
  const int n0 = (swz >> 3) * 256;

  f32x4 acc[8][4] = {};

  const int srow = tid >> 3;
  const int sgr = (tid & 7) ^ (srow & 7);
  const u16* gA = A + (size_t)(m0 + srow) * K + sgr * 8;
  const u16* gB = Bt + (size_t)(n0 + srow) * K + sgr * 8;
  const int dwave = wid * 512;

  const int co0 = (((lane >> 4)) ^ (lane & 7)) * 8;
  const int co1 = (((lane >> 4) + 4) ^ (lane & 7)) * 8;
  const int raA = (wr * 128 + (lane & 15)) * 64;
  const int raB = (wc * 64 + (lane & 15)) * 64;

  const int nk = K >> 6;

#pragma unroll
  for (int c = 0; c < 4; ++c) {
    gload_lds16(gA + (size_t)(c * 64) * K, &As[0][c * 4096 + dwave]);
    gload_lds16(gB + (size_t)(c * 64) * K, &Bs[0][c * 4096 + dwave]);
  }
#pragma unroll
  for (int c = 0; c < 4; ++c) {
    gload_lds16(gA + (size_t)(c * 64) * K + 64, &As[1][c * 4096 + dwave]);
    gload_lds16(gB + (size_t)(c * 64) * K + 64, &Bs[1][c * 4096 + dwave]);
  }
  asm volatile("s_waitcnt vmcnt(8)" ::: "memory");
  __builtin_amdgcn_s_barrier();
  __builtin_amdgcn_sched_barrier(0);

#pragma unroll 2
  for (int t = 0; t < nk; ++t) {
    const int cb = t & 1;
    const u16* Acur = &As[cb][0];
    const u16* Bcur = &Bs[cb][0];

    // --- reads: B frags + A frags for phases 0,1 ---
    bf16x8 bf[4][2];
#pragma unroll
    for (int n = 0; n < 4; ++n) {
      const int ro = raB + n * 16 * 64;
      bf[n][0] = *(const bf16x8*)&Bcur[ro + co0];
      bf[n][1] = *(const bf16x8*)&Bcur[ro + co1];
    }
    bf16x8 af01[2][2][2];
#pragma unroll
    for (int p = 0; p < 2; ++p)
#pragma unroll
      for (int mm = 0; mm < 2; ++mm) {
        const int ro = raA + (p * 32 + mm * 16) * 64;
        af01[p][mm][0] = *(const bf16x8*)&Acur[ro + co0];
        af01[p][mm][1] = *(const bf16x8*)&Acur[ro + co1];
      }
    // --- MFMA half 1 (phases 0,1) ---
    __builtin_amdgcn_s_setprio(1);
#pragma unroll
    for (int p = 0; p < 2; ++p)
#pragma unroll
      for (int mm = 0; mm < 2; ++mm)
#pragma unroll
        for (int n = 0; n < 4; ++n) {
          acc[p * 2 + mm][n] = __builtin_amdgcn_mfma_f32_16x16x32_bf16(af01[p][mm][0], bf[n][0], acc[p * 2 + mm][n], 0, 0, 0);
          acc[p * 2 + mm][n] = __builtin_amdgcn_mfma_f32_16x16x32_bf16(af01[p][mm][1], bf[n][1], acc[p * 2 + mm][n], 0, 0, 0);
        }
    __builtin_amdgcn_s_setprio(0);
    // --- reads: A frags for phases 2,3 ---
    bf16x8 af23[2][2][2];
#pragma unroll
    for (int p = 0; p < 2; ++p)
#pragma unroll
      for (int mm = 0; mm < 2; ++mm) {
        const int ro = raA + ((p + 2) * 32 + mm * 16) * 64;
        af23[p][mm][0] = *(const bf16x8*)&Acur[ro + co0];
        af23[p][mm][1] = *(const bf16x8*)&Acur[ro + co1];
      }
    asm volatile("s_waitcnt lgkmcnt(0)" ::: "memory");
    __builtin_amdgcn_s_barrier();          // (1) all reads of buf[cb] retired
    if (t + 2 < nk) {
      const size_t kto = (size_t)(t + 2) * 64;
#pragma unroll
      for (int c = 0; c < 4; ++c) {
        gload_lds16(gA + (size_t)(c * 64) * K + kto, &As[cb][c * 4096 + dwave]);
        gload_lds16(gB + (size_t)(c * 64) * K + kto, &Bs[cb][c * 4096 + dwave]);
      }
    }
    // --- MFMA half 2 (phases 2,3) ---
    __builtin_amdgcn_s_setprio(1);
#pragma unroll
    for (int p = 0; p < 2; ++p)
#pragma unroll
      for (int mm = 0; mm < 2; ++mm)
#pragma unroll
        for (int n = 0; n < 4; ++n) {
          acc[(p + 2) * 2 + mm][n] = __builtin_amdgcn_mfma_f32_16x16x32_bf16(af23[p][mm][0], bf[n][0], acc[(p + 2) * 2 + mm][n], 0, 0, 0);
          acc[(p + 2) * 2 + mm][n] = __builtin_amdgcn_mfma_f32_16x16x32_bf16(af23[p][mm][1], bf[n][1], acc[(p + 2) * 2 + mm][n], 0, 0, 0);
        }
    __builtin_amdgcn_s_setprio(0);
    if (t + 2 < nk) {
      asm volatile("s_waitcnt vmcnt(8)" ::: "memory");   // drain tile t+1
    } else if (t + 1 < nk) {
      asm volatile("s_waitcnt vmcnt(0)" ::: "memory");
    }
    __builtin_amdgcn_s_barrier();          // (2) publish buf[cb^1]
    __builtin_amdgcn_sched_barrier(0);
  }

  const int crow = m0 + wr * 128 + ((lane >> 4) << 2);
  const int ccol = n0 + wc * 64 + (lane & 15);
#pragma unroll
  for (int m = 0; m < 8; ++m)
#pragma unroll
    for (int n = 0; n < 4; ++n)
#pragma unroll
      for (int j = 0; j < 4; ++j)
        C[(size_t)(crow + m * 16 + j) * N + ccol + n * 16] = acc[m][n][j];
}

// ---------------------------------------------------------------------------
// 128x128 pipelined layer GEMM — same R12 drain-after-MFMA restructure.
// EPI 0: fp32 partial store to P + blockIdx.z * (2048*1024)
// EPI 1: QKV head-major bf16 from concat [3072][1024] weights
// EPI 2: bf16 gelu(acc + bias[col])
// ---------------------------------------------------------------------------
template <int EPI>
__global__ __launch_bounds__(256, 2) void gemm128p(
    const u16* __restrict__ A, const u16* __restrict__ Bt,
    void* __restrict__ C0, void* __restrict__ C1, void* __restrict__ C2,
    const float* __restrict__ bias, int N, int K)
{
  __shared__ u16 As[2][128 * 64];
  __shared__ u16 Bs[2][128 * 64];
  const int tid = threadIdx.x;
  const int lane = tid & 63;
  const int wid = tid >> 6;
  const int wr = wid >> 1;
  const int wc = wid & 1;

  const int T = (int)gridDim.x;
  const int bid = (int)blockIdx.x;
  const int q8 = T >> 3, r8 = T & 7;
  const int xcd = bid & 7, base = bid >> 3;
  const int swz = (xcd < r8 ? xcd * (q8 + 1) : r8 * (q8 + 1) + (xcd - r8) * q8) + base;
  const int m0 = (swz & 15) * 128;
  const int n0 = (swz >> 4) * 128;

  const int kchunk = K / (int)gridDim.z;
  const int kbeg = (int)blockIdx.z * kchunk;
  const int nk = kchunk >> 6;

  f32x4 acc[4][4] = {};

  const int srow = tid >> 3;
  const int sgr = (tid & 7) ^ (srow & 7);
  const u16* gA = A + (size_t)(m0 + srow) * K + kbeg + sgr * 8;
  const u16* gB = Bt + (size_t)(n0 + srow) * K + kbeg + sgr * 8;
  const int dwave = wid * 512;

  const int co0 = (((lane >> 4)) ^ (lane & 7)) * 8;
  const int co1 = (((lane >> 4) + 4) ^ (lane & 7)) * 8;
  const int raA = (wr * 64 + (lane & 15)) * 64;
  const int raB = (wc * 64 + (lane & 15)) * 64;

#pragma unroll
  for (int c = 0; c < 4; ++c) {
    gload_lds16(gA + (size_t)(c * 32) * K, &As[0][c * 2048 + dwave]);
    gload_lds16(gB + (size_t)(c * 32) * K, &Bs[0][c * 2048 + dwave]);
  }
#pragma unroll
  for (int c = 0; c < 4; ++c) {
    gload_lds16(gA + (size_t)(c * 32) * K + 64, &As[1][c * 2048 + dwave]);
    gload_lds16(gB + (size_t)(c * 32) * K + 64, &Bs[1][c * 2048 + dwave]);
  }
  asm volatile("s_waitcnt vmcnt(8)" ::: "memory");
  __builtin_amdgcn_s_barrier();
  __builtin_amdgcn_sched_barrier(0);

#pragma unroll 2
  for (int t = 0; t < nk; ++t) {
    const int cb = t & 1;
    const u16* Acur = &As[cb][0];
    const u16* Bcur = &Bs[cb][0];

    bf16x8 bf[4][2];
#pragma unroll
    for (int n = 0; n < 4; ++n) {
      const int ro = raB + n * 16 * 64;
      bf[n][0] = *(const bf16x8*)&Bcur[ro + co0];
      bf[n][1] = *(const bf16x8*)&Bcur[ro + co1];
    }
    bf16x8 af01[2][2];
#pragma unroll
    for (int p = 0; p < 2; ++p) {
      const int ro = raA + p * 16 * 64;
      af01[p][0] = *(const bf16x8*)&Acur[ro + co0];
      af01[p][1] = *(const bf16x8*)&Acur[ro + co1];
    }
    __builtin_amdgcn_s_setprio(1);
#pragma unroll
    for (int p = 0; p < 2; ++p)
#pragma unroll
      for (int n = 0; n < 4; ++n) {
        acc[p][n] = __builtin_amdgcn_mfma_f32_16x16x32_bf16(af01[p][0], bf[n][0], acc[p][n], 0, 0, 0);
        acc[p][n] = __builtin_amdgcn_mfma_f32_16x16x32_bf16(af01[p][1], bf[n][1], acc[p][n], 0, 0, 0);
      }
    __builtin_amdgcn_s_setprio(0);
    bf16x8 af23[2][2];
#pragma unroll
    for (int p = 0; p < 2; ++p) {
      const int ro = raA + (p + 2) * 16 * 64;
      af23[p][0] = *(const bf16x8*)&Acur[ro + co0];
      af23[p][1] = *(const bf16x8*)&Acur[ro + co1];
    }
    asm volatile("s_waitcnt lgkmcnt(0)" ::: "memory");
    __builtin_amdgcn_s_barrier();          // (1) all reads of buf[cb] retired
    if (t + 2 < nk) {
      const size_t kto = (size_t)(t + 2) * 64;
#pragma unroll
      for (int c = 0; c < 4; ++c) {
        gload_lds16(gA + (size_t)(c * 32) * K + kto, &As[cb][c * 2048 + dwave]);
        gload_lds16(gB + (size_t)(c * 32) * K + kto, &Bs[cb][c * 2048 + dwave]);
      }
    }
    __builtin_amdgcn_s_setprio(1);
#pragma unroll
    for (int p = 0; p < 2; ++p)
#pragma unroll
      for (int n = 0; n < 4; ++n) {
        acc[p + 2][n] = __builtin_amdgcn_mfma_f32_16x16x32_bf16(af23[p][0], bf[n][0], acc[p + 2][n], 0, 0, 0);
        acc[p + 2][n] = __builtin_amdgcn_mfma_f32_16x16x32_bf16(af23[p][1], bf[n][1], acc[p + 2][n], 0, 0, 0);
      }
    __builtin_amdgcn_s_setprio(0);
    if (t + 2 < nk) {
      asm volatile("s_waitcnt vmcnt(8)" ::: "memory");
    } else if (t + 1 < nk) {
      asm volatile("s_waitcnt vmcnt(0)" ::: "memory");
    }
    __builtin_amdgcn_s_barrier();          // (2) publish buf[cb^1]
    __builtin_amdgcn_sched_barrier(0);
  }

  const int z = (int)blockIdx.z;
#pragma unroll
  for (int m = 0; m < 4; ++m) {
    const int rowb = m0 + wr * 64 + m * 16 + ((lane >> 4) << 2);
#pragma unroll
    for (int n = 0; n < 4; ++n) {
      const int col = n0 + wc * 64 + n * 16 + (lane & 15);
#pragma unroll
      for (int j = 0; j < 4; ++j) {
        const int r = rowb + j;
        float v = acc[m][n][j];
        if (EPI == 0) {
          float* outp = (float*)C0 + (size_t)z * (2048u * 1024u);
          outp[(size_t)r * N + col] = v;
        } else if (EPI == 1) {
          const int which = col >> 10;
          const int ci = col & 1023;
          u16* outp = (u16*)((which == 0) ? C0 : (which == 1) ? C1 : C2);
          outp[((size_t)(ci >> 6) * SEQ + r) * 64 + (ci & 63)] = f2b(v);
        } else {
          float xx = v + bias[col];
          float ge = 0.5f * xx * (1.0f + erff(xx * 0.70710678118654752f));
          ((u16*)C0)[(size_t)r * N + col] = f2b(ge);
        }
      }
    }
  }
}

// ---------------------------------------------------------------------------
// Fallback logits GEMM (fp32 B, BK=32) if emb_bf16 doesn't fit ws.
// ---------------------------------------------------------------------------
__global__ __launch_bounds__(256) void gemm_f32b(
    const u16* __restrict__ A, const float* __restrict__ Bt,
    float* __restrict__ C0, int N, int K)
{
  __shared__ u16 As[128 * 32];
  __shared__ u16 Bs[128 * 32];
  const int tid = threadIdx.x;
  const int lane = tid & 63;
  const int w = tid >> 6;
  const int wr = w >> 1;
  const int wc = w & 1;

  const int T = (int)gridDim.x;
  const int bid = (int)blockIdx.x;
  const int q8 = T >> 3, r8 = T & 7;
  const int xcd = bid & 7, base = bid >> 3;
  int swz = (xcd < r8 ? xcd * (q8 + 1) : r8 * (q8 + 1) + (xcd - r8) * q8) + base;
  const int m0 = (swz & 15) * 128;
  const int n0 = (swz >> 4) * 128;

  f32x4 acc[4][4] = {};
  const u16* ga0 = A + (size_t)(m0 + w * 32 + (lane >> 2)) * K + (lane & 3) * 8;
  u16* la = &As[(w * 32) * 32];
  const float* gb32 = Bt + (size_t)(n0 + (tid >> 1)) * K + (tid & 1) * 16;
  u16* lbw = &Bs[(tid >> 1) * 32 + (tid & 1) * 16];

  for (int kt = 0; kt < K; kt += 32) {
    __syncthreads();
    gload_lds16(ga0 + kt, la);
    gload_lds16(ga0 + kt + 16 * K, la + 16 * 32);
    {
      const float4 f0 = *(const float4*)(gb32 + kt);
      const float4 f1 = *(const float4*)(gb32 + kt + 4);
      const float4 f2 = *(const float4*)(gb32 + kt + 8);
      const float4 f3 = *(const float4*)(gb32 + kt + 12);
      union { bf16x8 b; u16x8 u; } lo, hi;
      lo.b[0] = (__bf16)f0.x; lo.b[1] = (__bf16)f0.y;
      lo.b[2] = (__bf16)f0.z; lo.b[3] = (__bf16)f0.w;
      lo.b[4] = (__bf16)f1.x; lo.b[5] = (__bf16)f1.y;
      lo.b[6] = (__bf16)f1.z; lo.b[7] = (__bf16)f1.w;
      hi.b[0] = (__bf16)f2.x; hi.b[1] = (__bf16)f2.y;
      hi.b[2] = (__bf16)f2.z; hi.b[3] = (__bf16)f2.w;
      hi.b[4] = (__bf16)f3.x; hi.b[5] = (__bf16)f3.y;
      hi.b[6] = (__bf16)f3.z; hi.b[7] = (__bf16)f3.w;
      *(u16x8*)lbw = lo.u;
      *(u16x8*)(lbw + 8) = hi.u;
    }
    asm volatile("s_waitcnt vmcnt(0)" ::: "memory");
    __syncthreads();
    bf16x8 af[4], bfr[4];
#pragma unroll
    for (int m = 0; m < 4; ++m)
      af[m] = *(const bf16x8*)&As[(wr * 64 + m * 16 + (lane & 15)) * 32 + (lane >> 4) * 8];
#pragma unroll
    for (int n = 0; n < 4; ++n)
      bfr[n] = *(const bf16x8*)&Bs[(wc * 64 + n * 16 + (lane & 15)) * 32 + (lane >> 4) * 8];
#pragma unroll
    for (int m = 0; m < 4; ++m)
#pragma unroll
      for (int n = 0; n < 4; ++n)
        acc[m][n] = __builtin_amdgcn_mfma_f32_16x16x32_bf16(af[m], bfr[n], acc[m][n], 0, 0, 0);
  }

#pragma unroll
  for (int m = 0; m < 4; ++m) {
    const int rowb = m0 + wr * 64 + m * 16 + ((lane >> 4) << 2);
#pragma unroll
    for (int n = 0; n < 4; ++n) {
      const int col = n0 + wc * 64 + n * 16 + (lane & 15);
#pragma unroll
      for (int j = 0; j < 4; ++j)
        C0[(size_t)(rowb + j) * N + col] = acc[m][n][j];
    }
  }
}

// ---------------------------------------------------------------------------
// LayerNorm (plain): fp32 x[row][1024] -> bf16 h
// ---------------------------------------------------------------------------
__global__ __launch_bounds__(256) void ln_kernel(const float* __restrict__ x,
    const float* __restrict__ g, const float* __restrict__ b, u16* __restrict__ out)
{
  const int row = blockIdx.x;
  const int tid = threadIdx.x;
  const float4 v = ((const float4*)(x + (size_t)row * 1024))[tid];
  float s = v.x + v.y + v.z + v.w;
  float sq = v.x * v.x + v.y * v.y + v.z * v.z + v.w * v.w;
#pragma unroll
  for (int o = 1; o < 64; o <<= 1) { s += __shfl_xor(s, o); sq += __shfl_xor(sq, o); }
  __shared__ float ss[4], ssq[4];
  if ((tid & 63) == 0) { ss[tid >> 6] = s; ssq[tid >> 6] = sq; }
  __syncthreads();
  s = ss[0] + ss[1] + ss[2] + ss[3];
  sq = ssq[0] + ssq[1] + ssq[2] + ssq[3];
  const float mean = s * (1.0f / 1024.0f);
  const float var = sq * (1.0f / 1024.0f) - mean * mean;
  const float rstd = rsqrtf(var + 1e-5f);
  const int c = tid * 4;
  u16* o4 = out + (size_t)row * 1024 + c;
  const float4 gg = ((const float4*)g)[tid];
  const float4 bb = ((const float4*)b)[tid];
  o4[0] = f2b((v.x - mean) * rstd * gg.x + bb.x);
  o4[1] = f2b((v.y - mean) * rstd * gg.y + bb.y);
  o4[2] = f2b((v.z - mean) * rstd * gg.z + bb.z);
  o4[3] = f2b((v.w - mean) * rstd * gg.w + bb.w);
}

// ---------------------------------------------------------------------------
// Fused residual + LayerNorm, 4 split-K partials.
// ---------------------------------------------------------------------------
__global__ __launch_bounds__(256) void ln_res4(float* __restrict__ x,
    const float* __restrict__ P, const float* __restrict__ bias,
    const float* __restrict__ g, const float* __restrict__ b,
    u16* __restrict__ out)
{
  const int row = blockIdx.x;
  const int tid = threadIdx.x;
  const size_t off = (size_t)row * 1024;
  float4 v = ((const float4*)(x + off))[tid];
#pragma unroll
  for (int j = 0; j < 4; ++j) {
    const float4 a = ((const float4*)(P + (size_t)j * 2048 * 1024 + off))[tid];
    v.x += a.x; v.y += a.y; v.z += a.z; v.w += a.w;
  }
  if (bias != nullptr) {
    const float4 bi = ((const float4*)bias)[tid];
    v.x += bi.x; v.y += bi.y; v.z += bi.z; v.w += bi.w;
  }
  ((float4*)(x + off))[tid] = v;
  float s = v.x + v.y + v.z + v.w;
  float sq = v.x * v.x + v.y * v.y + v.z * v.z + v.w * v.w;
#pragma unroll
  for (int o = 1; o < 64; o <<= 1) { s += __shfl_xor(s, o); sq += __shfl_xor(sq, o); }
  __shared__ float ss[4], ssq[4];
  if ((tid & 63) == 0) { ss[tid >> 6] = s; ssq[tid >> 6] = sq; }
  __syncthreads();
  s = ss[0] + ss[1] + ss[2] + ss[3];
  sq = ssq[0] + ssq[1] + ssq[2] + ssq[3];
  const float mean = s * (1.0f / 1024.0f);
  const float var = sq * (1.0f / 1024.0f) - mean * mean;
  const float rstd = rsqrtf(var + 1e-5f);
  const int c = tid * 4;
  u16* o4 = out + off + c;
  const float4 gg = ((const float4*)g)[tid];
  const float4 bb = ((const float4*)b)[tid];
  o4[0] = f2b((v.x - mean) * rstd * gg.x + bb.x);
  o4[1] = f2b((v.y - mean) * rstd * gg.y + bb.y);
  o4[2] = f2b((v.z - mean) * rstd * gg.z + bb.z);
  o4[3] = f2b((v.w - mean) * rstd * gg.w + bb.w);
}

// ---------------------------------------------------------------------------
// Embedding gather: x[s][d] = emb_fp32[ids[s]][d]
// ---------------------------------------------------------------------------
__global__ __launch_bounds__(256) void gather_kernel(const int* __restrict__ ids,
    const float* __restrict__ emb, float* __restrict__ x)
{
  const int srow = blockIdx.x;
  const int tid = threadIdx.x;
  const int id = ids[srow];
  ((float4*)(x + (size_t)srow * 1024))[tid] =
      ((const float4*)(emb + (size_t)id * 1024))[tid];
}

// ---------------------------------------------------------------------------
// Flash attention w/ ALiBi + causal (R11 config: 512 blocks x 128 threads).
// ---------------------------------------------------------------------------
__global__ __launch_bounds__(128) void attn_kernel(
    const u16* __restrict__ q, const u16* __restrict__ k, const u16* __restrict__ v,
    const float* __restrict__ slopes, u16* __restrict__ out)
{
  const int bid = (int)blockIdx.x;
  const int h = bid & 15;
  const int qi = 31 - (bid >> 4);
  const int q0 = qi * 64;
  const int tid = threadIdx.x;
  const int lane = tid & 63;
  const int w = tid >> 6;
  const float slope = slopes[h];

  __shared__ u16 Ks[2][64 * 32];
  __shared__ u16 Vt[64][72];
  __shared__ u16 Pl[2][32][72];

  const u16* qb = q + ((size_t)h * SEQ + q0 + w * 32) * 64;
  bf16x8 qf[2][2];
#pragma unroll
  for (int m = 0; m < 2; ++m)
#pragma unroll
    for (int kk = 0; kk < 2; ++kk)
      qf[m][kk] = *(const bf16x8*)(qb + (m * 16 + (lane & 15)) * 64 + kk * 32 + (lane >> 4) * 8);

  f32x4 o_acc[2][4] = {};
  float mrun[2][4], lrun[2][4];
#pragma unroll
  for (int m = 0; m < 2; ++m)
#pragma unroll
    for (int j = 0; j < 4; ++j) { mrun[m][j] = -1e30f; lrun[m][j] = 0.0f; }

  const int ntiles = qi + 1;
  const int wmaxrow = q0 + w * 32 + 31;

  const int ksl = (lane & 3) ^ ((lane >> 2) & 3);
  const u16* gk0 = k + ((size_t)h * SEQ + (lane >> 2)) * 64 + w * 32 + ksl * 8;
  u16* lk = &Ks[w][0];
  const u16* gv0 = v + ((size_t)h * SEQ + lane) * 64 + w * 32;
  const int krd = ((lane >> 4) ^ (lane & 3)) * 8;

  for (int t = 0; t < ntiles; ++t) {
    const int j0 = t << 6;
    __syncthreads();
#pragma unroll
    for (int r = 0; r < 4; ++r)
      gload_lds16(gk0 + (size_t)(j0 + r * 16) * 64, lk + r * 16 * 32);
    {
      const u16* gvp = gv0 + (size_t)j0 * 64;
      u16x8 v0 = *(const u16x8*)gvp;
      u16x8 v1 = *(const u16x8*)(gvp + 8);
      u16x8 v2 = *(const u16x8*)(gvp + 16);
      u16x8 v3 = *(const u16x8*)(gvp + 24);
      const int d0 = w * 32;
#pragma unroll
      for (int i = 0; i < 8; ++i) Vt[d0 + i][lane] = v0[i];
#pragma unroll
      for (int i = 0; i < 8; ++i) Vt[d0 + 8 + i][lane] = v1[i];
#pragma unroll
      for (int i = 0; i < 8; ++i) Vt[d0 + 16 + i][lane] = v2[i];
#pragma unroll
      for (int i = 0; i < 8; ++i) Vt[d0 + 24 + i][lane] = v3[i];
    }
    asm volatile("s_waitcnt vmcnt(0)" ::: "memory");
    __syncthreads();

    if (wmaxrow >= j0) {
      f32x4 s[2][4] = {};
      __builtin_amdgcn_s_setprio(1);
#pragma unroll
      for (int kk = 0; kk < 2; ++kk) {
        bf16x8 kf[4];
#pragma unroll
        for (int n = 0; n < 4; ++n)
          kf[n] = *(const bf16x8*)&Ks[kk][(n * 16 + (lane & 15)) * 32 + krd];
#pragma unroll
        for (int m = 0; m < 2; ++m)
#pragma unroll
          for (int n = 0; n < 4; ++n)
            s[m][n] = __builtin_amdgcn_mfma_f32_16x16x32_bf16(qf[m][kk], kf[n], s[m][n], 0, 0, 0);
      }
      __builtin_amdgcn_s_setprio(0);
      const int rq = q0 + w * 32 + ((lane >> 4) << 2);
      const int ck = j0 + (lane & 15);
#pragma unroll
      for (int m = 0; m < 2; ++m) {
#pragma unroll
        for (int j = 0; j < 4; ++j) {
          const int qi2 = rq + m * 16 + j;
          float mx = -1e30f;
#pragma unroll
          for (int n = 0; n < 4; ++n) {
            const int kj = ck + n * 16;
            float val = s[m][n][j] * 0.125f - slope * (float)(kj - qi2);
            val = (kj <= qi2) ? val : -1e30f;
            s[m][n][j] = val;
            mx = fmaxf(mx, val);
          }
#pragma unroll
          for (int o = 1; o < 16; o <<= 1) mx = fmaxf(mx, __shfl_xor(mx, o));
          const float mnew = fmaxf(mrun[m][j], mx);
          const float alpha = __expf(mrun[m][j] - mnew);
          mrun[m][j] = mnew;
          float rs = 0.0f;
          const int prow = m * 16 + ((lane >> 4) << 2) + j;
#pragma unroll
          for (int n = 0; n < 4; ++n) {
            const float p = __expf(s[m][n][j] - mnew);
            rs += p;
            Pl[w][prow][n * 16 + (lane & 15)] = f2b(p);
          }
#pragma unroll
          for (int o = 1; o < 16; o <<= 1) rs += __shfl_xor(rs, o);
          lrun[m][j] = lrun[m][j] * alpha + rs;
#pragma unroll
          for (int n = 0; n < 4; ++n) o_acc[m][n][j] *= alpha;
        }
      }
      __builtin_amdgcn_s_setprio(1);
#pragma unroll
      for (int kk = 0; kk < 2; ++kk) {
        bf16x8 pf[2], vf[4];
#pragma unroll
        for (int m = 0; m < 2; ++m)
          pf[m] = *(const bf16x8*)&Pl[w][m * 16 + (lane & 15)][kk * 32 + (lane >> 4) * 8];
#pragma unroll
        for (int n = 0; n < 4; ++n)
          vf[n] = *(const bf16x8*)&Vt[n * 16 + (lane & 15)][kk * 32 + (lane >> 4) * 8];
#pragma unroll
        for (int m = 0; m < 2; ++m)
#pragma unroll
          for (int n = 0; n < 4; ++n)
            o_acc[m][n] = __builtin_amdgcn_mfma_f32_16x16x32_bf16(pf[m], vf[n], o_acc[m][n], 0, 0, 0);
      }
      __builtin_amdgcn_s_setprio(0);
    }
  }

#pragma unroll
  for (int m = 0; m < 2; ++m) {
    const int sbase = q0 + w * 32 + m * 16 + ((lane >> 4) << 2);
#pragma unroll
    for (int n = 0; n < 4; ++n) {
      const int d = h * 64 + n * 16 + (lane & 15);
#pragma unroll
      for (int j = 0; j < 4; ++j)
        out[(size_t)(sbase + j) * 1024 + d] = f2b(o_acc[m][n][j] / lrun[m][j]);
    }
  }
}

// ---------------------------------------------------------------------------
extern "C" void kernel_launch(void* const* d_in, const int* in_sizes, int n_in,
                              void* d_out, int out_size, void* d_ws, size_t ws_size,
                              hipStream_t stream)
{
  (void)in_sizes; (void)n_in; (void)out_size;
  const int* ids = (const int*)d_in[0];
  const float* emb = (const float*)d_in[1];
  const float* slopes = (const float*)d_in[2];
  const float* Wq = (const float*)d_in[3];
  const float* Wk = (const float*)d_in[4];
  const float* Wv = (const float*)d_in[5];
  const float* Wo = (const float*)d_in[6];
  const float* W1 = (const float*)d_in[7];
  const float* b1 = (const float*)d_in[8];
  const float* W2 = (const float*)d_in[9];
  const float* b2 = (const float*)d_in[10];
  const float* g1 = (const float*)d_in[11];
  const float* be1 = (const float*)d_in[12];
  const float* g2 = (const float*)d_in[13];
  const float* be2 = (const float*)d_in[14];
  const float* gf = (const float*)d_in[15];
  const float* bfin = (const float*)d_in[16];

  char* ob = (char*)d_out;
  float* x    = (float*)ob;                          // 8 MB fp32 residual
  u16* qb     = (u16*)(ob + (size_t)( 8u << 20));    // 4 MB
  u16* kb     = (u16*)(ob + (size_t)(12u << 20));    // 4 MB
  u16* vb     = (u16*)(ob + (size_t)(16u << 20));    // 4 MB
  u16* attn   = (u16*)(ob + (size_t)(20u << 20));    // 4 MB
  u16* ff     = (u16*)(ob + (size_t)(24u << 20));    // 16 MB
  u16* Wqkv_b = (u16*)(ob + (size_t)( 40u << 20));   // 24 MB  [4][3072][1024]
  u16* Wo_b   = (u16*)(ob + (size_t)( 64u << 20));   // 8 MB
  u16* W1_b   = (u16*)(ob + (size_t)( 72u << 20));   // 32 MB
  u16* W2_b   = (u16*)(ob + (size_t)(104u << 20));   // 32 MB
  float* P    = (float*)(ob + (size_t)(136u << 20)); // 32 MB: 4 split-K partials
  u16* h      = (u16*)d_ws;                          // 4 MB
  const size_t emb_b_need = (size_t)(4u << 20) + (size_t)32000 * 1024 * 2;
  const bool emb_fits = ws_size >= emb_b_need;
  u16* emb_b = (u16*)((char*)d_ws + (4u << 20));
  float* logits = (float*)d_out;

  {
    CvtArgs a;
    const u32 wsz = 4 * 1024 * 1024 / 8;
    const u32 fsz = 16 * 1024 * 1024 / 8;
    const u32 esz = 32000 * 1024 / 8;
    a.src[0] = Wq; a.dst[0] = Wqkv_b;
    a.src[1] = Wk; a.dst[1] = Wqkv_b + 1024 * 1024;
    a.src[2] = Wv; a.dst[2] = Wqkv_b + 2 * 1024 * 1024;
    a.src[3] = Wo; a.dst[3] = Wo_b;
    a.src[4] = W1; a.dst[4] = W1_b;
    a.src[5] = W2; a.dst[5] = W2_b;
    a.src[6] = emb; a.dst[6] = emb_b;
    a.beg[0] = 0;
    a.beg[1] = wsz;      a.beg[2] = 2 * wsz;  a.beg[3] = 3 * wsz;
    a.beg[4] = 4 * wsz;  a.beg[5] = 4 * wsz + fsz;  a.beg[6] = 4 * wsz + 2 * fsz;
    a.beg[7] = a.beg[6] + esz;
    a.total = emb_fits ? a.beg[7] : a.beg[6];
    cvt_all<<<2048, 256, 0, stream>>>(a);
  }

  gather_kernel<<<2048, 256, 0, stream>>>(ids, emb, x);
  ln_kernel<<<2048, 256, 0, stream>>>(x, g1, be1, h);

  for (int l = 0; l < 4; ++l) {
    const size_t wqkv = (size_t)l * 3072 * 1024;
    const size_t wo = (size_t)l * 1024 * 1024;
    const size_t wf = (size_t)l * 4096 * 1024;
    gemm128p<1><<<dim3(384, 1, 1), 256, 0, stream>>>(h, Wqkv_b + wqkv,
        qb, kb, vb, nullptr, 3072, 1024);
    attn_kernel<<<dim3(512, 1, 1), 128, 0, stream>>>(qb, kb, vb, slopes, attn);
    gemm128p<0><<<dim3(128, 1, 4), 256, 0, stream>>>(attn, Wo_b + wo,
        P, nullptr, nullptr, nullptr, 1024, 1024);
    ln_res4<<<2048, 256, 0, stream>>>(x, P, nullptr,
        g2 + l * 1024, be2 + l * 1024, h);
    gemm128p<2><<<dim3(512, 1, 1), 256, 0, stream>>>(h, W1_b + wf,
        ff, nullptr, nullptr, b1 + l * 4096, 4096, 1024);
    gemm128p<0><<<dim3(128, 1, 4), 256, 0, stream>>>(ff, W2_b + wf,
        P, nullptr, nullptr, nullptr, 1024, 4096);
    if (l < 3) {
      ln_res4<<<2048, 256, 0, stream>>>(x, P, b2 + l * 1024,
          g1 + (l + 1) * 1024, be1 + (l + 1) * 1024, h);
    } else {
      ln_res4<<<2048, 256, 0, stream>>>(x, P, b2 + l * 1024, gf, bfin, h);
    }
  }

  if (emb_fits) {
    gemm256<<<dim3(1000, 1, 1), 512, 0, stream>>>(h, emb_b, logits, 32000, 1024);
  } else {
    gemm_f32b<<<dim3(4000, 1, 1), 256, 0, stream>>>(h, emb, logits, 32000, 1024);
  }
}